// Round 13
// baseline (335.976 us; speedup 1.0000x reference)
//
#include <hip/hip_runtime.h>
#include <math.h>

#define N_GRID 65160
#define N_MESH 40962
#define N_TOT  106122
#define NE     521280
#define IN_CH  96
#define HID    256
#define OUT_CH 96

typedef __attribute__((ext_vector_type(8))) short bf16x8;   // 8 bf16 in 4 VGPRs (guide §3)
typedef __attribute__((ext_vector_type(4))) float f32x4;

__device__ __forceinline__ unsigned short f2bf(float f) {   // fp32 -> bf16 RNE
  unsigned u = __float_as_uint(f);
  return (unsigned short)((u + 0x7FFFu + ((u >> 16) & 1u)) >> 16);
}
__device__ __forceinline__ float bf2f(unsigned short s) {
  return __uint_as_float(((unsigned)s) << 16);
}
__device__ __forceinline__ float4 ldbf4(const unsigned short* p) {
  ushort4 u = *(const ushort4*)p;
  return make_float4(bf2f(u.x), bf2f(u.y), bf2f(u.z), bf2f(u.w));
}

// ---------------- concat + transpose: (96,N) fp32 channel-major -> (N,96) bf16 node-major ----------------
__global__ void k_concat_transpose(const float* __restrict__ xg, const float* __restrict__ xm,
                                   unsigned short* __restrict__ h) {
  __shared__ float tile[IN_CH][65];
  int base = blockIdx.x * 64;
  int t = threadIdx.x;
#pragma unroll
  for (int it = 0; it < 24; ++it) {
    int lin = t + it * 256;            // 0..6143 over 96x64
    int c  = lin >> 6;
    int n0 = lin & 63;
    int n = base + n0;
    float v = 0.f;
    if (n < N_TOT) {
      v = (n < N_GRID) ? xg[(size_t)c * N_GRID + n]
                       : xm[(size_t)c * N_MESH + (n - N_GRID)];
    }
    tile[c][n0] = v;
  }
  __syncthreads();
#pragma unroll
  for (int it = 0; it < 24; ++it) {
    int lin = t + it * 256;
    int c  = lin % 96;
    int n0 = lin / 96;
    int n = base + n0;
    if (n < N_TOT) h[(size_t)n * IN_CH + c] = f2bf(tile[c][n0]);
  }
}

// ---------------- final transpose: tb (N_GRID,96) fp32 node-major -> out (96,N_GRID) ----------------
__global__ void k_transpose_out(const float* __restrict__ tb, float* __restrict__ out) {
  __shared__ float tile[IN_CH][65];
  int base = blockIdx.x * 64;
  int t = threadIdx.x;
#pragma unroll
  for (int it = 0; it < 24; ++it) {
    int lin = t + it * 256;
    int c  = lin % 96;
    int n0 = lin / 96;
    int n = base + n0;
    if (n < N_GRID) tile[c][n0] = tb[(size_t)n * 96 + c];
  }
  __syncthreads();
#pragma unroll
  for (int it = 0; it < 24; ++it) {
    int lin = t + it * 256;
    int c  = lin >> 6;
    int n0 = lin & 63;
    int n = base + n0;
    if (n < N_GRID) out[(size_t)c * N_GRID + n] = tile[c][n0];
  }
}

// ---------------- CSR build ----------------
__global__ void k_zeroi(int* __restrict__ p, int n) {
  int i = blockIdx.x * 256 + threadIdx.x;
  if (i < n) p[i] = 0;
}
__global__ void k_seti(int* __restrict__ p, int v) { *p = v; }

__global__ void k_hist(const int* __restrict__ dst, int* __restrict__ deg) {
  int e = blockIdx.x * 256 + threadIdx.x;
  if (e < NE) atomicAdd(&deg[dst[e]], 1);
}

__global__ void k_blocksum(const int* __restrict__ deg, int* __restrict__ bsum, int n) {
  __shared__ int s[256];
  int i = blockIdx.x * 256 + threadIdx.x;
  s[threadIdx.x] = (i < n) ? deg[i] : 0;
  __syncthreads();
  for (int st = 128; st > 0; st >>= 1) {
    if (threadIdx.x < st) s[threadIdx.x] += s[threadIdx.x + st];
    __syncthreads();
  }
  if (threadIdx.x == 0) bsum[blockIdx.x] = s[0];
}

__global__ void k_scanbsum(int* __restrict__ bsum, int nb) {   // single block, 512 thr
  __shared__ int s[512];
  int t = threadIdx.x;
  int v = (t < nb) ? bsum[t] : 0;
  s[t] = v;
  __syncthreads();
  for (int off = 1; off < 512; off <<= 1) {
    int x = (t >= off) ? s[t - off] : 0;
    __syncthreads();
    s[t] += x;
    __syncthreads();
  }
  if (t < nb) bsum[t] = s[t] - v;   // exclusive
}

__global__ void k_offsets(const int* __restrict__ deg, const int* __restrict__ bsum,
                          int* __restrict__ off, int* __restrict__ cur, int n) {
  __shared__ int s[256];
  int i = blockIdx.x * 256 + threadIdx.x;
  int v = (i < n) ? deg[i] : 0;
  s[threadIdx.x] = v;
  __syncthreads();
  for (int o = 1; o < 256; o <<= 1) {
    int x = (threadIdx.x >= o) ? s[threadIdx.x - o] : 0;
    __syncthreads();
    s[threadIdx.x] += x;
    __syncthreads();
  }
  if (i < n) {
    int e = bsum[blockIdx.x] + s[threadIdx.x] - v;
    off[i] = e;
    cur[i] = e;
  }
}

__global__ void k_fillcsr(const int* __restrict__ src, const int* __restrict__ dst,
                          int* __restrict__ cur, int* __restrict__ csrc) {
  int e = blockIdx.x * 256 + threadIdx.x;
  if (e < NE) {
    int p = atomicAdd(&cur[dst[e]], 1);
    csrc[p] = src[e];
  }
}

__global__ void k_dinv(const int* __restrict__ deg, float* __restrict__ dinv, int n) {
  int i = blockIdx.x * 256 + threadIdx.x;
  if (i < n) dinv[i] = rsqrtf(1.0f + (float)deg[i]);
}

// gather over p (fp32, 96 ch) for grid nodes only, + combined bias bc, write tb node-major fp32
__global__ void k_gather96p(const int* __restrict__ off, const int* __restrict__ csrc,
                            const float* __restrict__ dinv, const float* __restrict__ p,
                            const float* __restrict__ bc, float* __restrict__ tb) {
  int i = blockIdx.x * 256 + threadIdx.x;
  if (i >= N_GRID * 24) return;
  int n = i / 24;
  int c4 = (i % 24) << 2;
  float di = dinv[n];
  float4 v = *(const float4*)(p + (size_t)n * 96 + c4);
  float w0 = di * di;
  float4 acc = make_float4(v.x * w0, v.y * w0, v.z * w0, v.w * w0);
  int e0 = off[n], e1 = off[n + 1];
  int e = e0;
  for (; e + 3 < e1; e += 4) {
    int s0 = csrc[e], s1 = csrc[e + 1], s2 = csrc[e + 2], s3 = csrc[e + 3];
    float wa = dinv[s0] * di, wb = dinv[s1] * di, wc = dinv[s2] * di, wd = dinv[s3] * di;
    float4 u0 = *(const float4*)(p + (size_t)s0 * 96 + c4);
    float4 u1 = *(const float4*)(p + (size_t)s1 * 96 + c4);
    float4 u2 = *(const float4*)(p + (size_t)s2 * 96 + c4);
    float4 u3 = *(const float4*)(p + (size_t)s3 * 96 + c4);
    acc.x += u0.x * wa + u1.x * wb + u2.x * wc + u3.x * wd;
    acc.y += u0.y * wa + u1.y * wb + u2.y * wc + u3.y * wd;
    acc.z += u0.z * wa + u1.z * wb + u2.z * wc + u3.z * wd;
    acc.w += u0.w * wa + u1.w * wb + u2.w * wc + u3.w * wd;
  }
  for (; e < e1; ++e) {
    int s = csrc[e];
    float w = dinv[s] * di;
    float4 u = *(const float4*)(p + (size_t)s * 96 + c4);
    acc.x += u.x * w; acc.y += u.y * w; acc.z += u.z * w; acc.w += u.w * w;
  }
  float4 b = *(const float4*)(bc + c4);
  acc.x += b.x; acc.y += b.y; acc.z += b.z; acc.w += b.w;
  *(float4*)(tb + (size_t)n * 96 + c4) = acc;
}

// ---------------- small-matrix weight GEMM: C(Mx96) = [A; bvec](MxK) @ B(Kx96) ----------------
__global__ __launch_bounds__(256, 2) void k_wgemm96(const float* __restrict__ A, const float* __restrict__ bvec,
                                                    const float* __restrict__ B, float* __restrict__ C,
                                                    int M, int K) {
  __shared__ float As[64][33];
  __shared__ float Bs[64][100];
  int t = threadIdx.x;
  int tx = t & 15, ty = t >> 4;
  int bm = blockIdx.x * 32;
  float acc[2][6] = {};
  for (int kc = 0; kc < K; kc += 64) {
#pragma unroll
    for (int it = 0; it < 2; ++it) {
      int idx = t + it * 256;
      int r = idx >> 4, k4 = (idx & 15) << 2;
      int gr = bm + r;
      float4 v = make_float4(0.f, 0.f, 0.f, 0.f);
      if (gr < M) {
        const float* src = (gr < M - 1) ? (A + (size_t)gr * K + kc + k4) : (bvec + kc + k4);
        v = *(const float4*)src;
      }
      As[k4 + 0][r] = v.x;
      As[k4 + 1][r] = v.y;
      As[k4 + 2][r] = v.z;
      As[k4 + 3][r] = v.w;
    }
#pragma unroll
    for (int it = 0; it < 6; ++it) {
      int idx = t + it * 256;
      int k = idx / 24, j4 = (idx % 24) << 2;
      float4 v = *(const float4*)(B + (size_t)(kc + k) * 96 + j4);
      *(float4*)&Bs[k][j4] = v;
    }
    __syncthreads();
#pragma unroll
    for (int k = 0; k < 64; ++k) {
      float a0 = As[k][ty * 2], a1 = As[k][ty * 2 + 1];
      float w[6];
      *(float2*)&w[0] = *(const float2*)&Bs[k][tx * 6];
      *(float2*)&w[2] = *(const float2*)&Bs[k][tx * 6 + 2];
      *(float2*)&w[4] = *(const float2*)&Bs[k][tx * 6 + 4];
#pragma unroll
      for (int j = 0; j < 6; ++j) { acc[0][j] += a0 * w[j]; acc[1][j] += a1 * w[j]; }
    }
    __syncthreads();
  }
#pragma unroll
  for (int i = 0; i < 2; ++i) {
    int gr = bm + ty * 2 + i;
    if (gr >= M) continue;
    float* row = C + (size_t)gr * 96 + tx * 6;
    row[0] = acc[i][0]; row[1] = acc[i][1]; row[2] = acc[i][2];
    row[3] = acc[i][3]; row[4] = acc[i][4]; row[5] = acc[i][5];
  }
}

// bc[j] = P1[256][j] + P2[256][j] + bl2[j]
__global__ void k_bc_final(const float* __restrict__ r1, const float* __restrict__ r2,
                           const float* __restrict__ bl2, float* __restrict__ bc) {
  int j = threadIdx.x;
  if (j < OUT_CH) bc[j] = r1[j] + r2[j] + bl2[j];
}

// ---------------- weight casts (fp32 -> bf16, transposed to col-major) ----------------
__global__ void k_cast_w1t(const float* __restrict__ W1, unsigned short* __restrict__ W1bt) {
  int idx = blockIdx.x * 256 + threadIdx.x;          // over [256 n][96 k]
  if (idx >= 256 * 96) return;
  int n = idx / 96, k = idx % 96;
  W1bt[idx] = f2bf(W1[(size_t)k * 256 + n]);
}
__global__ void k_cast_wct(const float* __restrict__ Wc, unsigned short* __restrict__ Wcbt) {
  int idx = blockIdx.x * 256 + threadIdx.x;          // over [96 n][256 k]
  if (idx >= 96 * 256) return;
  int n = idx / 256, k = idx % 256;
  Wcbt[idx] = f2bf(Wc[(size_t)k * 96 + n]);
}

// ---------------- FUSED node pipeline: gather + GEMM1 + gelu + GEMM2 ----------------
// Block = 64 rows, 4 waves x 16 rows; each wave's rows are self-contained end-to-end:
//   phase A: gather agg rows (bf16) -> As (wave-local rows; CSR random reads from hb/L3)
//   phase B: h1 = gelu(agg @ W1 + b1), 16 frags/wave, K=96, B-frags from L2-resident W1bt -> Hs (bf16)
//   phase C: p = h1 @ Wc, 6 frags/wave, K=256, B-frags from L2-resident Wcbt -> global fp32
// agg1b and h1b intermediates NEVER touch HBM (round-12 counters: their round-trips were ~150 MB).
// LDS 46 KB -> 3 blocks/CU. Frag maps identical to round-12 verified kernels (D: col=lane&15,
// row=(lane>>4)*4+reg). Hs stride 264 bf16 = 528 B: 16B-aligned b128 reads, 2-way banks (free, m136).
__global__ __launch_bounds__(256) void k_fused(const int* __restrict__ off, const int* __restrict__ csrc,
                                               const float* __restrict__ dinv,
                                               const unsigned short* __restrict__ hb,
                                               const unsigned short* __restrict__ W1bt,  // [256 n][96 k]
                                               const float* __restrict__ b1,
                                               const unsigned short* __restrict__ Wcbt,  // [96 n][256 k]
                                               float* __restrict__ P, int M) {
  __shared__ unsigned short As[64][104];   // gathered agg rows (bf16), 13.3 KB
  __shared__ unsigned short Hs[64][264];   // h1 rows (bf16), 33.8 KB
  int t = threadIdx.x;
  int wave = t >> 6, lane = t & 63;
  int l15 = lane & 15, lhi = lane >> 4;
  int bm = blockIdx.x * 64;

  // ---- phase A: gather 16 rows/wave x 24 c4-groups = 384 tasks / 64 lanes ----
#pragma unroll
  for (int it = 0; it < 6; ++it) {
    int task = lane + it * 64;             // 0..383
    int r = task / 24;                     // local row 0..15
    int c4 = (task % 24) << 2;
    int row = wave * 16 + r;
    int n = bm + row;
    float4 acc = make_float4(0.f, 0.f, 0.f, 0.f);
    if (n < M) {
      float di = dinv[n];
      float4 v = ldbf4(hb + (size_t)n * 96 + c4);
      float w0 = di * di;
      acc = make_float4(v.x * w0, v.y * w0, v.z * w0, v.w * w0);
      int e0 = off[n], e1 = off[n + 1];
      int e = e0;
      for (; e + 3 < e1; e += 4) {
        int s0 = csrc[e], s1 = csrc[e + 1], s2 = csrc[e + 2], s3 = csrc[e + 3];
        float wa = dinv[s0] * di, wb = dinv[s1] * di, wc = dinv[s2] * di, wd = dinv[s3] * di;
        float4 u0 = ldbf4(hb + (size_t)s0 * 96 + c4);
        float4 u1 = ldbf4(hb + (size_t)s1 * 96 + c4);
        float4 u2 = ldbf4(hb + (size_t)s2 * 96 + c4);
        float4 u3 = ldbf4(hb + (size_t)s3 * 96 + c4);
        acc.x += u0.x * wa + u1.x * wb + u2.x * wc + u3.x * wd;
        acc.y += u0.y * wa + u1.y * wb + u2.y * wc + u3.y * wd;
        acc.z += u0.z * wa + u1.z * wb + u2.z * wc + u3.z * wd;
        acc.w += u0.w * wa + u1.w * wb + u2.w * wc + u3.w * wd;
      }
      for (; e < e1; ++e) {
        int s = csrc[e];
        float w = dinv[s] * di;
        float4 u = ldbf4(hb + (size_t)s * 96 + c4);
        acc.x += u.x * w; acc.y += u.y * w; acc.z += u.z * w; acc.w += u.w * w;
      }
    }
    ushort4 o;
    o.x = f2bf(acc.x); o.y = f2bf(acc.y); o.z = f2bf(acc.z); o.w = f2bf(acc.w);
    *(ushort4*)&As[row][c4] = o;
  }
  __syncthreads();                          // cross-lane handoff As

  // ---- phase B: h1 = gelu(agg @ W1 + b1); 16 frags of 16x16, K=96 ----
  {
    f32x4 acc1[16];
#pragma unroll
    for (int f = 0; f < 16; ++f) acc1[f] = (f32x4){0.f, 0.f, 0.f, 0.f};
    int arow = wave * 16 + l15;
#pragma unroll
    for (int ks = 0; ks < 3; ++ks) {
      bf16x8 a = *(const bf16x8*)&As[arow][ks * 32 + lhi * 8];
#pragma unroll
      for (int f = 0; f < 16; ++f) {
        bf16x8 b = *(const bf16x8*)(W1bt + (size_t)(f * 16 + l15) * 96 + ks * 32 + lhi * 8);
        acc1[f] = __builtin_amdgcn_mfma_f32_16x16x32_bf16(a, b, acc1[f], 0, 0, 0);
      }
    }
#pragma unroll
    for (int f = 0; f < 16; ++f) {
      int col = f * 16 + l15;
      float bv = b1[col];
#pragma unroll
      for (int r = 0; r < 4; ++r) {
        float x = acc1[f][r] + bv;
        x = 0.5f * x * (1.0f + erff(x * 0.70710678118654752f));
        Hs[wave * 16 + lhi * 4 + r][col] = f2bf(x);
      }
    }
  }
  __syncthreads();                          // cross-lane handoff Hs

  // ---- phase C: p = h1 @ Wc; 6 frags, K=256 ----
  {
    f32x4 acc2[6];
#pragma unroll
    for (int f = 0; f < 6; ++f) acc2[f] = (f32x4){0.f, 0.f, 0.f, 0.f};
    int hrow = wave * 16 + l15;
#pragma unroll
    for (int ks = 0; ks < 8; ++ks) {
      bf16x8 a = *(const bf16x8*)&Hs[hrow][ks * 32 + lhi * 8];
#pragma unroll
      for (int f = 0; f < 6; ++f) {
        bf16x8 b = *(const bf16x8*)(Wcbt + (size_t)(f * 16 + l15) * 256 + ks * 32 + lhi * 8);
        acc2[f] = __builtin_amdgcn_mfma_f32_16x16x32_bf16(a, b, acc2[f], 0, 0, 0);
      }
    }
#pragma unroll
    for (int f = 0; f < 6; ++f) {
      int col = f * 16 + l15;
#pragma unroll
      for (int r = 0; r < 4; ++r) {
        int row = bm + wave * 16 + lhi * 4 + r;
        if (row < M) P[(size_t)row * 96 + col] = acc2[f][r];
      }
    }
  }
}

extern "C" void kernel_launch(void* const* d_in, const int* in_sizes, int n_in,
                              void* d_out, int out_size, void* d_ws, size_t ws_size,
                              hipStream_t stream) {
  const float* xm  = (const float*)d_in[0];
  const float* xg  = (const float*)d_in[1];
  const int*   ei  = (const int*)d_in[2];
  const float* W1  = (const float*)d_in[3];
  const float* b1  = (const float*)d_in[4];
  const float* W2  = (const float*)d_in[5];
  const float* b2  = (const float*)d_in[6];
  const float* Wl1 = (const float*)d_in[7];
  const float* bl1 = (const float*)d_in[8];
  const float* Wl2 = (const float*)d_in[9];
  const float* bl2 = (const float*)d_in[10];
  float* out = (float*)d_out;

  // ---- workspace layout (float units) ----
  // region0 [0, MB): p fp32 (t4-t5, 10.19M fl); tb fp32 [10.19M, 16.44M)
  // meta [MB, RH): CSR + P1/P2 + bc + W1bt/Wcbt bf16
  // [RH, ...): hb bf16 (t1-t4)
  float* W0 = (float*)d_ws;
  const size_t MB = (size_t)N_GRID * 256;          // 16,680,960
  int*   deg  = (int*)(W0 + MB);
  int*   off  = deg + N_TOT;                       // N_TOT+1
  int*   cur  = off + N_TOT + 1;
  int*   bsum = cur + N_TOT;                       // 512
  int*   csrc = bsum + 512;                        // NE
  float* dinv = (float*)(csrc + NE);               // N_TOT
  size_t p1off = ((size_t)(dinv + N_TOT - W0) + 3) & ~(size_t)3;   // 16B align
  float* P1 = W0 + p1off;                          // 257*96: [Wl1;bl1]@Wl2 (rows 0..255 = T1)
  float* P2 = P1 + 257 * 96;                       // 257*96: [W2;b2]@T1  (rows 0..255 = Wc)
  float* bc = P2 + 257 * 96;                       // 96
  size_t wboff = ((size_t)(bc + 96 - W0) + 3) & ~(size_t)3;        // 16B align
  unsigned short* W1bt = (unsigned short*)(W0 + wboff);            // 256x96 bf16
  unsigned short* Wcbt = W1bt + 256 * 96;                          // 96x256 bf16
  size_t RH = (wboff + 24576 + 3) & ~(size_t)3;    // past both bf16 arrays (24576 floats)
  unsigned short* hb = (unsigned short*)(W0 + RH); // N_TOT x 96 bf16
  float* p  = W0;
  float* tb = W0 + (size_t)N_TOT * 96;             // 10,187,712 .. 16,443,072 < MB

  const int* esrc = ei;
  const int* edst = ei + NE;
  dim3 b256(256);
  const int NB_N = (N_TOT + 255) / 256;

  // t1. node features (N_TOT, 96) bf16
  k_concat_transpose<<<dim3((N_TOT + 63) / 64), b256, 0, stream>>>(xg, xm, hb);

  // t2. CSR by dst + dinv; weight combine + casts (independent of node pipeline)
  k_zeroi<<<dim3(NB_N), b256, 0, stream>>>(deg, N_TOT);
  k_hist<<<dim3((NE + 255) / 256), b256, 0, stream>>>(edst, deg);
  k_blocksum<<<dim3(NB_N), b256, 0, stream>>>(deg, bsum, N_TOT);
  k_scanbsum<<<dim3(1), dim3(512), 0, stream>>>(bsum, NB_N);
  k_offsets<<<dim3(NB_N), b256, 0, stream>>>(deg, bsum, off, cur, N_TOT);
  k_seti<<<dim3(1), dim3(1), 0, stream>>>(off + N_TOT, NE);
  k_fillcsr<<<dim3((NE + 255) / 256), b256, 0, stream>>>(esrc, edst, cur, csrc);
  k_dinv<<<dim3(NB_N), b256, 0, stream>>>(deg, dinv, N_TOT);
  k_cast_w1t<<<dim3(96), b256, 0, stream>>>(W1, W1bt);
  k_wgemm96<<<dim3(9), b256, 0, stream>>>(Wl1, bl1, Wl2, P1, 257, HID);
  k_wgemm96<<<dim3(9), b256, 0, stream>>>(W2, b2, P1, P2, 257, HID);
  k_bc_final<<<dim3(1), dim3(96), 0, stream>>>(P1 + 256 * 96, P2 + 256 * 96, bl2, bc);
  k_cast_wct<<<dim3(96), b256, 0, stream>>>(P2, Wcbt);

  // t4. p = (S@hb waved through MLP) — fused gather+GEMM1+gelu+GEMM2
  k_fused<<<dim3((N_TOT + 63) / 64), b256, 0, stream>>>(off, csrc, dinv, hb, W1bt, b1, Wcbt, p, N_TOT);

  // t5. tb = S_grid @ p + bc   (96 ch, fp32 gather)
  k_gather96p<<<dim3((N_GRID * 24 + 255) / 256), b256, 0, stream>>>(off, csrc, dinv, p, bc, tb);

  // t6. out = tb^T   (96, N_GRID)
  k_transpose_out<<<dim3((N_GRID + 63) / 64), b256, 0, stream>>>(tb, out);
}

// Round 14
// 296.362 us; speedup vs baseline: 1.1337x; 1.1337x over previous
//
#include <hip/hip_runtime.h>
#include <math.h>

#define N_GRID 65160
#define N_MESH 40962
#define N_TOT  106122
#define NE     521280
#define IN_CH  96
#define HID    256
#define OUT_CH 96

typedef __attribute__((ext_vector_type(8))) short bf16x8;   // 8 bf16 in 4 VGPRs (guide §3)
typedef __attribute__((ext_vector_type(4))) float f32x4;

__device__ __forceinline__ unsigned short f2bf(float f) {   // fp32 -> bf16 RNE
  unsigned u = __float_as_uint(f);
  return (unsigned short)((u + 0x7FFFu + ((u >> 16) & 1u)) >> 16);
}
__device__ __forceinline__ float bf2f(unsigned short s) {
  return __uint_as_float(((unsigned)s) << 16);
}
__device__ __forceinline__ float4 ldbf4(const unsigned short* p) {
  ushort4 u = *(const ushort4*)p;
  return make_float4(bf2f(u.x), bf2f(u.y), bf2f(u.z), bf2f(u.w));
}

// ---------------- concat + transpose: (96,N) fp32 channel-major -> (N,96) bf16 node-major ----------------
__global__ void k_concat_transpose(const float* __restrict__ xg, const float* __restrict__ xm,
                                   unsigned short* __restrict__ h) {
  __shared__ float tile[IN_CH][65];
  int base = blockIdx.x * 64;
  int t = threadIdx.x;
#pragma unroll
  for (int it = 0; it < 24; ++it) {
    int lin = t + it * 256;            // 0..6143 over 96x64
    int c  = lin >> 6;
    int n0 = lin & 63;
    int n = base + n0;
    float v = 0.f;
    if (n < N_TOT) {
      v = (n < N_GRID) ? xg[(size_t)c * N_GRID + n]
                       : xm[(size_t)c * N_MESH + (n - N_GRID)];
    }
    tile[c][n0] = v;
  }
  __syncthreads();
#pragma unroll
  for (int it = 0; it < 24; ++it) {
    int lin = t + it * 256;
    int c  = lin % 96;
    int n0 = lin / 96;
    int n = base + n0;
    if (n < N_TOT) h[(size_t)n * IN_CH + c] = f2bf(tile[c][n0]);
  }
}

// ---------------- final transpose: tb (N_GRID,96) fp32 node-major -> out (96,N_GRID) ----------------
__global__ void k_transpose_out(const float* __restrict__ tb, float* __restrict__ out) {
  __shared__ float tile[IN_CH][65];
  int base = blockIdx.x * 64;
  int t = threadIdx.x;
#pragma unroll
  for (int it = 0; it < 24; ++it) {
    int lin = t + it * 256;
    int c  = lin % 96;
    int n0 = lin / 96;
    int n = base + n0;
    if (n < N_GRID) tile[c][n0] = tb[(size_t)n * 96 + c];
  }
  __syncthreads();
#pragma unroll
  for (int it = 0; it < 24; ++it) {
    int lin = t + it * 256;
    int c  = lin >> 6;
    int n0 = lin & 63;
    int n = base + n0;
    if (n < N_GRID) out[(size_t)c * N_GRID + n] = tile[c][n0];
  }
}

// ---------------- CSR build ----------------
__global__ void k_zeroi(int* __restrict__ p, int n) {
  int i = blockIdx.x * 256 + threadIdx.x;
  if (i < n) p[i] = 0;
}
__global__ void k_seti(int* __restrict__ p, int v) { *p = v; }

__global__ void k_hist(const int* __restrict__ dst, int* __restrict__ deg) {
  int e = blockIdx.x * 256 + threadIdx.x;
  if (e < NE) atomicAdd(&deg[dst[e]], 1);
}

__global__ void k_blocksum(const int* __restrict__ deg, int* __restrict__ bsum, int n) {
  __shared__ int s[256];
  int i = blockIdx.x * 256 + threadIdx.x;
  s[threadIdx.x] = (i < n) ? deg[i] : 0;
  __syncthreads();
  for (int st = 128; st > 0; st >>= 1) {
    if (threadIdx.x < st) s[threadIdx.x] += s[threadIdx.x + st];
    __syncthreads();
  }
  if (threadIdx.x == 0) bsum[blockIdx.x] = s[0];
}

__global__ void k_scanbsum(int* __restrict__ bsum, int nb) {   // single block, 512 thr
  __shared__ int s[512];
  int t = threadIdx.x;
  int v = (t < nb) ? bsum[t] : 0;
  s[t] = v;
  __syncthreads();
  for (int off = 1; off < 512; off <<= 1) {
    int x = (t >= off) ? s[t - off] : 0;
    __syncthreads();
    s[t] += x;
    __syncthreads();
  }
  if (t < nb) bsum[t] = s[t] - v;   // exclusive
}

__global__ void k_offsets(const int* __restrict__ deg, const int* __restrict__ bsum,
                          int* __restrict__ off, int* __restrict__ cur, int n) {
  __shared__ int s[256];
  int i = blockIdx.x * 256 + threadIdx.x;
  int v = (i < n) ? deg[i] : 0;
  s[threadIdx.x] = v;
  __syncthreads();
  for (int o = 1; o < 256; o <<= 1) {
    int x = (threadIdx.x >= o) ? s[threadIdx.x - o] : 0;
    __syncthreads();
    s[threadIdx.x] += x;
    __syncthreads();
  }
  if (i < n) {
    int e = bsum[blockIdx.x] + s[threadIdx.x] - v;
    off[i] = e;
    cur[i] = e;
  }
}

__global__ void k_fillcsr(const int* __restrict__ src, const int* __restrict__ dst,
                          int* __restrict__ cur, int* __restrict__ csrc) {
  int e = blockIdx.x * 256 + threadIdx.x;
  if (e < NE) {
    int p = atomicAdd(&cur[dst[e]], 1);
    csrc[p] = src[e];
  }
}

__global__ void k_dinv(const int* __restrict__ deg, float* __restrict__ dinv, int n) {
  int i = blockIdx.x * 256 + threadIdx.x;
  if (i < n) dinv[i] = rsqrtf(1.0f + (float)deg[i]);
}

// ---------------- gather over bf16 h (4-edge unrolled, fp32 accumulate, bf16 out) ----------------
// Standalone: trivial resource footprint -> near-max waves/CU. Round 13 proved this phase MUST NOT
// inherit a compute kernel's VGPR/LDS footprint (fused: 3x slower at 12 waves/CU).
__global__ void k_gather96(const int* __restrict__ off, const int* __restrict__ csrc,
                           const float* __restrict__ dinv, const unsigned short* __restrict__ h,
                           unsigned short* __restrict__ agg) {
  int i = blockIdx.x * 256 + threadIdx.x;
  if (i >= N_TOT * 24) return;
  int n = i / 24;
  int c4 = (i % 24) << 2;
  float di = dinv[n];
  float4 v = ldbf4(h + (size_t)n * 96 + c4);
  float w0 = di * di;
  float4 acc = make_float4(v.x * w0, v.y * w0, v.z * w0, v.w * w0);
  int e0 = off[n], e1 = off[n + 1];
  int e = e0;
  for (; e + 3 < e1; e += 4) {
    int s0 = csrc[e], s1 = csrc[e + 1], s2 = csrc[e + 2], s3 = csrc[e + 3];
    float wa = dinv[s0] * di, wb = dinv[s1] * di, wc = dinv[s2] * di, wd = dinv[s3] * di;
    float4 u0 = ldbf4(h + (size_t)s0 * 96 + c4);
    float4 u1 = ldbf4(h + (size_t)s1 * 96 + c4);
    float4 u2 = ldbf4(h + (size_t)s2 * 96 + c4);
    float4 u3 = ldbf4(h + (size_t)s3 * 96 + c4);
    acc.x += u0.x * wa + u1.x * wb + u2.x * wc + u3.x * wd;
    acc.y += u0.y * wa + u1.y * wb + u2.y * wc + u3.y * wd;
    acc.z += u0.z * wa + u1.z * wb + u2.z * wc + u3.z * wd;
    acc.w += u0.w * wa + u1.w * wb + u2.w * wc + u3.w * wd;
  }
  for (; e < e1; ++e) {
    int s = csrc[e];
    float w = dinv[s] * di;
    float4 u = ldbf4(h + (size_t)s * 96 + c4);
    acc.x += u.x * w; acc.y += u.y * w; acc.z += u.z * w; acc.w += u.w * w;
  }
  ushort4 o;
  o.x = f2bf(acc.x); o.y = f2bf(acc.y); o.z = f2bf(acc.z); o.w = f2bf(acc.w);
  *(ushort4*)(agg + (size_t)n * 96 + c4) = o;
}

// gather over p (fp32, 96 ch) for grid nodes only, + combined bias bc, write tb node-major fp32
__global__ void k_gather96p(const int* __restrict__ off, const int* __restrict__ csrc,
                            const float* __restrict__ dinv, const float* __restrict__ p,
                            const float* __restrict__ bc, float* __restrict__ tb) {
  int i = blockIdx.x * 256 + threadIdx.x;
  if (i >= N_GRID * 24) return;
  int n = i / 24;
  int c4 = (i % 24) << 2;
  float di = dinv[n];
  float4 v = *(const float4*)(p + (size_t)n * 96 + c4);
  float w0 = di * di;
  float4 acc = make_float4(v.x * w0, v.y * w0, v.z * w0, v.w * w0);
  int e0 = off[n], e1 = off[n + 1];
  int e = e0;
  for (; e + 3 < e1; e += 4) {
    int s0 = csrc[e], s1 = csrc[e + 1], s2 = csrc[e + 2], s3 = csrc[e + 3];
    float wa = dinv[s0] * di, wb = dinv[s1] * di, wc = dinv[s2] * di, wd = dinv[s3] * di;
    float4 u0 = *(const float4*)(p + (size_t)s0 * 96 + c4);
    float4 u1 = *(const float4*)(p + (size_t)s1 * 96 + c4);
    float4 u2 = *(const float4*)(p + (size_t)s2 * 96 + c4);
    float4 u3 = *(const float4*)(p + (size_t)s3 * 96 + c4);
    acc.x += u0.x * wa + u1.x * wb + u2.x * wc + u3.x * wd;
    acc.y += u0.y * wa + u1.y * wb + u2.y * wc + u3.y * wd;
    acc.z += u0.z * wa + u1.z * wb + u2.z * wc + u3.z * wd;
    acc.w += u0.w * wa + u1.w * wb + u2.w * wc + u3.w * wd;
  }
  for (; e < e1; ++e) {
    int s = csrc[e];
    float w = dinv[s] * di;
    float4 u = *(const float4*)(p + (size_t)s * 96 + c4);
    acc.x += u.x * w; acc.y += u.y * w; acc.z += u.z * w; acc.w += u.w * w;
  }
  float4 b = *(const float4*)(bc + c4);
  acc.x += b.x; acc.y += b.y; acc.z += b.z; acc.w += b.w;
  *(float4*)(tb + (size_t)n * 96 + c4) = acc;
}

// ---------------- small-matrix weight GEMM: C(Mx96) = [A; bvec](MxK) @ B(Kx96) ----------------
__global__ __launch_bounds__(256, 2) void k_wgemm96(const float* __restrict__ A, const float* __restrict__ bvec,
                                                    const float* __restrict__ B, float* __restrict__ C,
                                                    int M, int K) {
  __shared__ float As[64][33];
  __shared__ float Bs[64][100];
  int t = threadIdx.x;
  int tx = t & 15, ty = t >> 4;
  int bm = blockIdx.x * 32;
  float acc[2][6] = {};
  for (int kc = 0; kc < K; kc += 64) {
#pragma unroll
    for (int it = 0; it < 2; ++it) {
      int idx = t + it * 256;
      int r = idx >> 4, k4 = (idx & 15) << 2;
      int gr = bm + r;
      float4 v = make_float4(0.f, 0.f, 0.f, 0.f);
      if (gr < M) {
        const float* src = (gr < M - 1) ? (A + (size_t)gr * K + kc + k4) : (bvec + kc + k4);
        v = *(const float4*)src;
      }
      As[k4 + 0][r] = v.x;
      As[k4 + 1][r] = v.y;
      As[k4 + 2][r] = v.z;
      As[k4 + 3][r] = v.w;
    }
#pragma unroll
    for (int it = 0; it < 6; ++it) {
      int idx = t + it * 256;
      int k = idx / 24, j4 = (idx % 24) << 2;
      float4 v = *(const float4*)(B + (size_t)(kc + k) * 96 + j4);
      *(float4*)&Bs[k][j4] = v;
    }
    __syncthreads();
#pragma unroll
    for (int k = 0; k < 64; ++k) {
      float a0 = As[k][ty * 2], a1 = As[k][ty * 2 + 1];
      float w[6];
      *(float2*)&w[0] = *(const float2*)&Bs[k][tx * 6];
      *(float2*)&w[2] = *(const float2*)&Bs[k][tx * 6 + 2];
      *(float2*)&w[4] = *(const float2*)&Bs[k][tx * 6 + 4];
#pragma unroll
      for (int j = 0; j < 6; ++j) { acc[0][j] += a0 * w[j]; acc[1][j] += a1 * w[j]; }
    }
    __syncthreads();
  }
#pragma unroll
  for (int i = 0; i < 2; ++i) {
    int gr = bm + ty * 2 + i;
    if (gr >= M) continue;
    float* row = C + (size_t)gr * 96 + tx * 6;
    row[0] = acc[i][0]; row[1] = acc[i][1]; row[2] = acc[i][2];
    row[3] = acc[i][3]; row[4] = acc[i][4]; row[5] = acc[i][5];
  }
}

// bc[j] = P1[256][j] + P2[256][j] + bl2[j]
__global__ void k_bc_final(const float* __restrict__ r1, const float* __restrict__ r2,
                           const float* __restrict__ bl2, float* __restrict__ bc) {
  int j = threadIdx.x;
  if (j < OUT_CH) bc[j] = r1[j] + r2[j] + bl2[j];
}

// ---------------- weight casts (fp32 -> bf16, transposed to col-major) ----------------
__global__ void k_cast_w1t(const float* __restrict__ W1, unsigned short* __restrict__ W1bt) {
  int idx = blockIdx.x * 256 + threadIdx.x;          // over [256 n][96 k]
  if (idx >= 256 * 96) return;
  int n = idx / 96, k = idx % 96;
  W1bt[idx] = f2bf(W1[(size_t)k * 256 + n]);
}
__global__ void k_cast_wct(const float* __restrict__ Wc, unsigned short* __restrict__ Wcbt) {
  int idx = blockIdx.x * 256 + threadIdx.x;          // over [96 n][256 k]
  if (idx >= 96 * 256) return;
  int n = idx / 256, k = idx % 256;
  Wcbt[idx] = f2bf(Wc[(size_t)k * 96 + n]);
}

// ---------------- FUSED MLP: p = (gelu(agg @ W1 + b1)) @ Wc  — bf16 MFMA x2, h1 never leaves LDS ----
// Block = 64 rows, 4 waves x 16 rows, each wave's rows self-contained:
//   stage: coalesced load agg rows -> As (13.3 KB)
//   phase B: h1 = gelu(agg@W1+b1): 16 frags/wave, K=96, B-frags from L2-resident W1bt -> Hs (33.8 KB)
//   phase C: p = h1@Wc: 6 frags/wave, K=256, B-frags from L2-resident Wcbt -> global fp32
// Round-12 counters: h1b round-trip was 54 MB write + 54 MB read of HBM — eliminated here.
// Round-13 lesson applied: NO latency-bound gather inside this kernel (it runs standalone).
// LDS 47 KB -> 3 blocks/CU; 2 barriers total. Frag maps identical to verified round-12 kernels.
__global__ __launch_bounds__(256) void k_mlp(const unsigned short* __restrict__ A,
                                             const unsigned short* __restrict__ W1bt,  // [256 n][96 k]
                                             const float* __restrict__ b1,
                                             const unsigned short* __restrict__ Wcbt,  // [96 n][256 k]
                                             float* __restrict__ P, int M) {
  __shared__ unsigned short As[64][104];   // agg rows (bf16)
  __shared__ unsigned short Hs[64][264];   // h1 rows (bf16), stride 528 B: 16B-aligned, 2-way banks (free)
  int t = threadIdx.x;
  int wave = t >> 6, lane = t & 63;
  int l15 = lane & 15, lhi = lane >> 4;
  int bm = blockIdx.x * 64;

  // stage: 64 rows x 12 uint4-groups = 768 tasks, coalesced
#pragma unroll
  for (int it = 0; it < 3; ++it) {
    int idx = t + it * 256;
    int row = idx / 12, g = idx % 12;
    uint4 v = make_uint4(0u, 0u, 0u, 0u);
    if (bm + row < M) v = *(const uint4*)(A + (size_t)(bm + row) * 96 + g * 8);
    *(uint4*)&As[row][g * 8] = v;
  }
  __syncthreads();

  // phase B: h1 = gelu(agg @ W1 + b1); 16 frags of 16x16, K=96
  {
    f32x4 acc1[16];
#pragma unroll
    for (int f = 0; f < 16; ++f) acc1[f] = (f32x4){0.f, 0.f, 0.f, 0.f};
    int arow = wave * 16 + l15;
#pragma unroll
    for (int ks = 0; ks < 3; ++ks) {
      bf16x8 a = *(const bf16x8*)&As[arow][ks * 32 + lhi * 8];
#pragma unroll
      for (int f = 0; f < 16; ++f) {
        bf16x8 b = *(const bf16x8*)(W1bt + (size_t)(f * 16 + l15) * 96 + ks * 32 + lhi * 8);
        acc1[f] = __builtin_amdgcn_mfma_f32_16x16x32_bf16(a, b, acc1[f], 0, 0, 0);
      }
    }
#pragma unroll
    for (int f = 0; f < 16; ++f) {
      int col = f * 16 + l15;
      float bv = b1[col];
#pragma unroll
      for (int r = 0; r < 4; ++r) {
        float x = acc1[f][r] + bv;
        x = 0.5f * x * (1.0f + erff(x * 0.70710678118654752f));
        Hs[wave * 16 + lhi * 4 + r][col] = f2bf(x);
      }
    }
  }
  __syncthreads();

  // phase C: p = h1 @ Wc; 6 frags, K=256
  {
    f32x4 acc2[6];
#pragma unroll
    for (int f = 0; f < 6; ++f) acc2[f] = (f32x4){0.f, 0.f, 0.f, 0.f};
    int hrow = wave * 16 + l15;
#pragma unroll
    for (int ks = 0; ks < 8; ++ks) {
      bf16x8 a = *(const bf16x8*)&Hs[hrow][ks * 32 + lhi * 8];
#pragma unroll
      for (int f = 0; f < 6; ++f) {
        bf16x8 b = *(const bf16x8*)(Wcbt + (size_t)(f * 16 + l15) * 256 + ks * 32 + lhi * 8);
        acc2[f] = __builtin_amdgcn_mfma_f32_16x16x32_bf16(a, b, acc2[f], 0, 0, 0);
      }
    }
#pragma unroll
    for (int f = 0; f < 6; ++f) {
      int col = f * 16 + l15;
#pragma unroll
      for (int r = 0; r < 4; ++r) {
        int row = bm + wave * 16 + lhi * 4 + r;
        if (row < M) P[(size_t)row * 96 + col] = acc2[f][r];
      }
    }
  }
}

extern "C" void kernel_launch(void* const* d_in, const int* in_sizes, int n_in,
                              void* d_out, int out_size, void* d_ws, size_t ws_size,
                              hipStream_t stream) {
  const float* xm  = (const float*)d_in[0];
  const float* xg  = (const float*)d_in[1];
  const int*   ei  = (const int*)d_in[2];
  const float* W1  = (const float*)d_in[3];
  const float* b1  = (const float*)d_in[4];
  const float* W2  = (const float*)d_in[5];
  const float* b2  = (const float*)d_in[6];
  const float* Wl1 = (const float*)d_in[7];
  const float* bl1 = (const float*)d_in[8];
  const float* Wl2 = (const float*)d_in[9];
  const float* bl2 = (const float*)d_in[10];
  float* out = (float*)d_out;

  // ---- workspace layout (float units) ----
  // region0 [0, MB): agg1b bf16 (t3-t4) then p fp32 (t4-t5); tb fp32 [10.19M, 16.44M)
  // meta [MB, RH): CSR + P1/P2 + bc + W1bt/Wcbt bf16
  // [RH, ...): hb bf16 (t1-t4)
  float* W0 = (float*)d_ws;
  const size_t MB = (size_t)N_GRID * 256;          // 16,680,960
  int*   deg  = (int*)(W0 + MB);
  int*   off  = deg + N_TOT;                       // N_TOT+1
  int*   cur  = off + N_TOT + 1;
  int*   bsum = cur + N_TOT;                       // 512
  int*   csrc = bsum + 512;                        // NE
  float* dinv = (float*)(csrc + NE);               // N_TOT
  size_t p1off = ((size_t)(dinv + N_TOT - W0) + 3) & ~(size_t)3;   // 16B align
  float* P1 = W0 + p1off;                          // 257*96: [Wl1;bl1]@Wl2 (rows 0..255 = T1)
  float* P2 = P1 + 257 * 96;                       // 257*96: [W2;b2]@T1  (rows 0..255 = Wc)
  float* bc = P2 + 257 * 96;                       // 96
  size_t wboff = ((size_t)(bc + 96 - W0) + 3) & ~(size_t)3;        // 16B align
  unsigned short* W1bt = (unsigned short*)(W0 + wboff);            // 256x96 bf16
  unsigned short* Wcbt = W1bt + 256 * 96;                          // 96x256 bf16
  size_t RH = (wboff + 24576 + 3) & ~(size_t)3;    // past both bf16 arrays (24576 floats)
  unsigned short* hb = (unsigned short*)(W0 + RH); // N_TOT x 96 bf16
  unsigned short* agg1b = (unsigned short*)W0;     // N_TOT x 96 bf16 (t3-t4)
  // p overlaps agg1b's region — but k_mlp reads agg1b while writing p. Put p AFTER tb instead:
  float* tb = W0 + (size_t)N_TOT * 96;             // [10,187,712 , 16,443,072) — wait: tb needs N_GRID*96
  // NOTE: agg1b occupies [0, N_TOT*96 bf16 = 5.09M floats). p must not alias it during k_mlp.
  // Layout: agg1b [0, 5.1M fl) ; tb [5.1M, 11.35M fl) ; p [11.35M, 21.54M fl) — all < MB? MB=16.68M. NO.
  // p (10.19M fl) goes after RH+hb instead (hb is 5.09M fl; ws is ample).
  float* p = (float*)(hb + (size_t)N_TOT * 96 + 16);   // after hb, 16B-aligned region
  p = (float*)(((size_t)p + 15) & ~(size_t)15);
  tb = W0 + (size_t)6 * 1024 * 1024;               // [6M, 12.25M) floats — clear of agg1b (5.1M) and meta(>=MB)

  const int* esrc = ei;
  const int* edst = ei + NE;
  dim3 b256(256);
  const int NB_N = (N_TOT + 255) / 256;

  // t1. node features (N_TOT, 96) bf16
  k_concat_transpose<<<dim3((N_TOT + 63) / 64), b256, 0, stream>>>(xg, xm, hb);

  // t2. CSR by dst + dinv; weight combine + casts (independent of node pipeline)
  k_zeroi<<<dim3(NB_N), b256, 0, stream>>>(deg, N_TOT);
  k_hist<<<dim3((NE + 255) / 256), b256, 0, stream>>>(edst, deg);
  k_blocksum<<<dim3(NB_N), b256, 0, stream>>>(deg, bsum, N_TOT);
  k_scanbsum<<<dim3(1), dim3(512), 0, stream>>>(bsum, NB_N);
  k_offsets<<<dim3(NB_N), b256, 0, stream>>>(deg, bsum, off, cur, N_TOT);
  k_seti<<<dim3(1), dim3(1), 0, stream>>>(off + N_TOT, NE);
  k_fillcsr<<<dim3((NE + 255) / 256), b256, 0, stream>>>(esrc, edst, cur, csrc);
  k_dinv<<<dim3(NB_N), b256, 0, stream>>>(deg, dinv, N_TOT);
  k_cast_w1t<<<dim3(96), b256, 0, stream>>>(W1, W1bt);
  k_wgemm96<<<dim3(9), b256, 0, stream>>>(Wl1, bl1, Wl2, P1, 257, HID);
  k_wgemm96<<<dim3(9), b256, 0, stream>>>(W2, b2, P1, P2, 257, HID);
  k_bc_final<<<dim3(1), dim3(96), 0, stream>>>(P1 + 256 * 96, P2 + 256 * 96, bl2, bc);
  k_cast_wct<<<dim3(96), b256, 0, stream>>>(P2, Wcbt);

  // t3. agg1 = S @ h   (96 ch, gather, bf16) — standalone, high occupancy
  k_gather96<<<dim3((N_TOT * 24 + 255) / 256), b256, 0, stream>>>(off, csrc, dinv, hb, agg1b);

  // t4. p = gelu(agg1@W1+b1)@Wc  — fused MLP, h1 stays in LDS
  k_mlp<<<dim3((N_TOT + 63) / 64), b256, 0, stream>>>(agg1b, W1bt, b1, Wcbt, p, N_TOT);

  // t5. tb = S_grid @ p + bc   (96 ch, fp32 gather)
  k_gather96p<<<dim3((N_GRID * 24 + 255) / 256), b256, 0, stream>>>(off, csrc, dinv, p, bc, tb);

  // t6. out = tb^T   (96, N_GRID)
  k_transpose_out<<<dim3((N_GRID + 63) / 64), b256, 0, stream>>>(tb, out);
}

// Round 15
// 266.004 us; speedup vs baseline: 1.2630x; 1.1141x over previous
//
#include <hip/hip_runtime.h>
#include <math.h>

#define N_GRID 65160
#define N_MESH 40962
#define N_TOT  106122
#define NE     521280
#define IN_CH  96
#define HID    256
#define OUT_CH 96

typedef __attribute__((ext_vector_type(8))) short bf16x8;   // 8 bf16 in 4 VGPRs (guide §3)
typedef __attribute__((ext_vector_type(4))) float f32x4;

__device__ __forceinline__ unsigned short f2bf(float f) {   // fp32 -> bf16 RNE
  unsigned u = __float_as_uint(f);
  return (unsigned short)((u + 0x7FFFu + ((u >> 16) & 1u)) >> 16);
}
__device__ __forceinline__ float bf2f(unsigned short s) {
  return __uint_as_float(((unsigned)s) << 16);
}
__device__ __forceinline__ float4 ldbf4(const unsigned short* p) {
  ushort4 u = *(const ushort4*)p;
  return make_float4(bf2f(u.x), bf2f(u.y), bf2f(u.z), bf2f(u.w));
}

// ---------------- concat + transpose: (96,N) fp32 channel-major -> (N,96) bf16 node-major ----------------
__global__ void k_concat_transpose(const float* __restrict__ xg, const float* __restrict__ xm,
                                   unsigned short* __restrict__ h) {
  __shared__ float tile[IN_CH][65];
  int base = blockIdx.x * 64;
  int t = threadIdx.x;
#pragma unroll
  for (int it = 0; it < 24; ++it) {
    int lin = t + it * 256;            // 0..6143 over 96x64
    int c  = lin >> 6;
    int n0 = lin & 63;
    int n = base + n0;
    float v = 0.f;
    if (n < N_TOT) {
      v = (n < N_GRID) ? xg[(size_t)c * N_GRID + n]
                       : xm[(size_t)c * N_MESH + (n - N_GRID)];
    }
    tile[c][n0] = v;
  }
  __syncthreads();
#pragma unroll
  for (int it = 0; it < 24; ++it) {
    int lin = t + it * 256;
    int c  = lin % 96;
    int n0 = lin / 96;
    int n = base + n0;
    if (n < N_TOT) h[(size_t)n * IN_CH + c] = f2bf(tile[c][n0]);
  }
}

// ---------------- final transpose: tb (N_GRID,96) fp32 node-major -> out (96,N_GRID) ----------------
__global__ void k_transpose_out(const float* __restrict__ tb, float* __restrict__ out) {
  __shared__ float tile[IN_CH][65];
  int base = blockIdx.x * 64;
  int t = threadIdx.x;
#pragma unroll
  for (int it = 0; it < 24; ++it) {
    int lin = t + it * 256;
    int c  = lin % 96;
    int n0 = lin / 96;
    int n = base + n0;
    if (n < N_GRID) tile[c][n0] = tb[(size_t)n * 96 + c];
  }
  __syncthreads();
#pragma unroll
  for (int it = 0; it < 24; ++it) {
    int lin = t + it * 256;
    int c  = lin >> 6;
    int n0 = lin & 63;
    int n = base + n0;
    if (n < N_GRID) out[(size_t)c * N_GRID + n] = tile[c][n0];
  }
}

// ---------------- CSR build ----------------
__global__ void k_zeroi(int* __restrict__ p, int n) {
  int i = blockIdx.x * 256 + threadIdx.x;
  if (i < n) p[i] = 0;
}
__global__ void k_seti(int* __restrict__ p, int v) { *p = v; }

__global__ void k_hist(const int* __restrict__ dst, int* __restrict__ deg) {
  int e = blockIdx.x * 256 + threadIdx.x;
  if (e < NE) atomicAdd(&deg[dst[e]], 1);
}

__global__ void k_blocksum(const int* __restrict__ deg, int* __restrict__ bsum, int n) {
  __shared__ int s[256];
  int i = blockIdx.x * 256 + threadIdx.x;
  s[threadIdx.x] = (i < n) ? deg[i] : 0;
  __syncthreads();
  for (int st = 128; st > 0; st >>= 1) {
    if (threadIdx.x < st) s[threadIdx.x] += s[threadIdx.x + st];
    __syncthreads();
  }
  if (threadIdx.x == 0) bsum[blockIdx.x] = s[0];
}

__global__ void k_scanbsum(int* __restrict__ bsum, int nb) {   // single block, 512 thr
  __shared__ int s[512];
  int t = threadIdx.x;
  int v = (t < nb) ? bsum[t] : 0;
  s[t] = v;
  __syncthreads();
  for (int off = 1; off < 512; off <<= 1) {
    int x = (t >= off) ? s[t - off] : 0;
    __syncthreads();
    s[t] += x;
    __syncthreads();
  }
  if (t < nb) bsum[t] = s[t] - v;   // exclusive
}

__global__ void k_offsets(const int* __restrict__ deg, const int* __restrict__ bsum,
                          int* __restrict__ off, int* __restrict__ cur, int n) {
  __shared__ int s[256];
  int i = blockIdx.x * 256 + threadIdx.x;
  int v = (i < n) ? deg[i] : 0;
  s[threadIdx.x] = v;
  __syncthreads();
  for (int o = 1; o < 256; o <<= 1) {
    int x = (threadIdx.x >= o) ? s[threadIdx.x - o] : 0;
    __syncthreads();
    s[threadIdx.x] += x;
    __syncthreads();
  }
  if (i < n) {
    int e = bsum[blockIdx.x] + s[threadIdx.x] - v;
    off[i] = e;
    cur[i] = e;
  }
}

__global__ void k_fillcsr(const int* __restrict__ src, const int* __restrict__ dst,
                          int* __restrict__ cur, int* __restrict__ csrc) {
  int e = blockIdx.x * 256 + threadIdx.x;
  if (e < NE) {
    int p = atomicAdd(&cur[dst[e]], 1);
    csrc[p] = src[e];
  }
}

__global__ void k_dinv(const int* __restrict__ deg, float* __restrict__ dinv, int n) {
  int i = blockIdx.x * 256 + threadIdx.x;
  if (i < n) dinv[i] = rsqrtf(1.0f + (float)deg[i]);
}

// ---------------- gather over bf16 h (4-edge unrolled, fp32 accumulate, bf16 out) ----------------
// Standalone: trivial resource footprint -> near-max waves/CU (round-13 lesson: never fuse me).
__global__ void k_gather96(const int* __restrict__ off, const int* __restrict__ csrc,
                           const float* __restrict__ dinv, const unsigned short* __restrict__ h,
                           unsigned short* __restrict__ agg) {
  int i = blockIdx.x * 256 + threadIdx.x;
  if (i >= N_TOT * 24) return;
  int n = i / 24;
  int c4 = (i % 24) << 2;
  float di = dinv[n];
  float4 v = ldbf4(h + (size_t)n * 96 + c4);
  float w0 = di * di;
  float4 acc = make_float4(v.x * w0, v.y * w0, v.z * w0, v.w * w0);
  int e0 = off[n], e1 = off[n + 1];
  int e = e0;
  for (; e + 3 < e1; e += 4) {
    int s0 = csrc[e], s1 = csrc[e + 1], s2 = csrc[e + 2], s3 = csrc[e + 3];
    float wa = dinv[s0] * di, wb = dinv[s1] * di, wc = dinv[s2] * di, wd = dinv[s3] * di;
    float4 u0 = ldbf4(h + (size_t)s0 * 96 + c4);
    float4 u1 = ldbf4(h + (size_t)s1 * 96 + c4);
    float4 u2 = ldbf4(h + (size_t)s2 * 96 + c4);
    float4 u3 = ldbf4(h + (size_t)s3 * 96 + c4);
    acc.x += u0.x * wa + u1.x * wb + u2.x * wc + u3.x * wd;
    acc.y += u0.y * wa + u1.y * wb + u2.y * wc + u3.y * wd;
    acc.z += u0.z * wa + u1.z * wb + u2.z * wc + u3.z * wd;
    acc.w += u0.w * wa + u1.w * wb + u2.w * wc + u3.w * wd;
  }
  for (; e < e1; ++e) {
    int s = csrc[e];
    float w = dinv[s] * di;
    float4 u = ldbf4(h + (size_t)s * 96 + c4);
    acc.x += u.x * w; acc.y += u.y * w; acc.z += u.z * w; acc.w += u.w * w;
  }
  ushort4 o;
  o.x = f2bf(acc.x); o.y = f2bf(acc.y); o.z = f2bf(acc.z); o.w = f2bf(acc.w);
  *(ushort4*)(agg + (size_t)n * 96 + c4) = o;
}

// gather over p (bf16, 96 ch) for grid nodes only, + combined bias bc, write tb node-major fp32
__global__ void k_gather96p(const int* __restrict__ off, const int* __restrict__ csrc,
                            const float* __restrict__ dinv, const unsigned short* __restrict__ p,
                            const float* __restrict__ bc, float* __restrict__ tb) {
  int i = blockIdx.x * 256 + threadIdx.x;
  if (i >= N_GRID * 24) return;
  int n = i / 24;
  int c4 = (i % 24) << 2;
  float di = dinv[n];
  float4 v = ldbf4(p + (size_t)n * 96 + c4);
  float w0 = di * di;
  float4 acc = make_float4(v.x * w0, v.y * w0, v.z * w0, v.w * w0);
  int e0 = off[n], e1 = off[n + 1];
  int e = e0;
  for (; e + 3 < e1; e += 4) {
    int s0 = csrc[e], s1 = csrc[e + 1], s2 = csrc[e + 2], s3 = csrc[e + 3];
    float wa = dinv[s0] * di, wb = dinv[s1] * di, wc = dinv[s2] * di, wd = dinv[s3] * di;
    float4 u0 = ldbf4(p + (size_t)s0 * 96 + c4);
    float4 u1 = ldbf4(p + (size_t)s1 * 96 + c4);
    float4 u2 = ldbf4(p + (size_t)s2 * 96 + c4);
    float4 u3 = ldbf4(p + (size_t)s3 * 96 + c4);
    acc.x += u0.x * wa + u1.x * wb + u2.x * wc + u3.x * wd;
    acc.y += u0.y * wa + u1.y * wb + u2.y * wc + u3.y * wd;
    acc.z += u0.z * wa + u1.z * wb + u2.z * wc + u3.z * wd;
    acc.w += u0.w * wa + u1.w * wb + u2.w * wc + u3.w * wd;
  }
  for (; e < e1; ++e) {
    int s = csrc[e];
    float w = dinv[s] * di;
    float4 u = ldbf4(p + (size_t)s * 96 + c4);
    acc.x += u.x * w; acc.y += u.y * w; acc.z += u.z * w; acc.w += u.w * w;
  }
  float4 b = *(const float4*)(bc + c4);
  acc.x += b.x; acc.y += b.y; acc.z += b.z; acc.w += b.w;
  *(float4*)(tb + (size_t)n * 96 + c4) = acc;
}

// ---------------- small-matrix weight GEMM: C(Mx96) = [A; bvec](MxK) @ B(Kx96) ----------------
__global__ __launch_bounds__(256, 2) void k_wgemm96(const float* __restrict__ A, const float* __restrict__ bvec,
                                                    const float* __restrict__ B, float* __restrict__ C,
                                                    int M, int K) {
  __shared__ float As[64][33];
  __shared__ float Bs[64][100];
  int t = threadIdx.x;
  int tx = t & 15, ty = t >> 4;
  int bm = blockIdx.x * 32;
  float acc[2][6] = {};
  for (int kc = 0; kc < K; kc += 64) {
#pragma unroll
    for (int it = 0; it < 2; ++it) {
      int idx = t + it * 256;
      int r = idx >> 4, k4 = (idx & 15) << 2;
      int gr = bm + r;
      float4 v = make_float4(0.f, 0.f, 0.f, 0.f);
      if (gr < M) {
        const float* src = (gr < M - 1) ? (A + (size_t)gr * K + kc + k4) : (bvec + kc + k4);
        v = *(const float4*)src;
      }
      As[k4 + 0][r] = v.x;
      As[k4 + 1][r] = v.y;
      As[k4 + 2][r] = v.z;
      As[k4 + 3][r] = v.w;
    }
#pragma unroll
    for (int it = 0; it < 6; ++it) {
      int idx = t + it * 256;
      int k = idx / 24, j4 = (idx % 24) << 2;
      float4 v = *(const float4*)(B + (size_t)(kc + k) * 96 + j4);
      *(float4*)&Bs[k][j4] = v;
    }
    __syncthreads();
#pragma unroll
    for (int k = 0; k < 64; ++k) {
      float a0 = As[k][ty * 2], a1 = As[k][ty * 2 + 1];
      float w[6];
      *(float2*)&w[0] = *(const float2*)&Bs[k][tx * 6];
      *(float2*)&w[2] = *(const float2*)&Bs[k][tx * 6 + 2];
      *(float2*)&w[4] = *(const float2*)&Bs[k][tx * 6 + 4];
#pragma unroll
      for (int j = 0; j < 6; ++j) { acc[0][j] += a0 * w[j]; acc[1][j] += a1 * w[j]; }
    }
    __syncthreads();
  }
#pragma unroll
  for (int i = 0; i < 2; ++i) {
    int gr = bm + ty * 2 + i;
    if (gr >= M) continue;
    float* row = C + (size_t)gr * 96 + tx * 6;
    row[0] = acc[i][0]; row[1] = acc[i][1]; row[2] = acc[i][2];
    row[3] = acc[i][3]; row[4] = acc[i][4]; row[5] = acc[i][5];
  }
}

// bc[j] = P1[256][j] + P2[256][j] + bl2[j]
__global__ void k_bc_final(const float* __restrict__ r1, const float* __restrict__ r2,
                           const float* __restrict__ bl2, float* __restrict__ bc) {
  int j = threadIdx.x;
  if (j < OUT_CH) bc[j] = r1[j] + r2[j] + bl2[j];
}

// ---------------- weight casts (fp32 -> bf16, transposed to col-major) ----------------
__global__ void k_cast_w1t(const float* __restrict__ W1, unsigned short* __restrict__ W1bt) {
  int idx = blockIdx.x * 256 + threadIdx.x;          // over [256 n][96 k]
  if (idx >= 256 * 96) return;
  int n = idx / 96, k = idx % 96;
  W1bt[idx] = f2bf(W1[(size_t)k * 256 + n]);
}
__global__ void k_cast_wct(const float* __restrict__ Wc, unsigned short* __restrict__ Wcbt) {
  int idx = blockIdx.x * 256 + threadIdx.x;          // over [96 n][256 k]
  if (idx >= 96 * 256) return;
  int n = idx / 256, k = idx % 256;
  Wcbt[idx] = f2bf(Wc[(size_t)k * 96 + n]);
}

// ---------------- FUSED MLP v2: p = (gelu(agg @ W1 + b1)) @ Wc, f-major, load-pipelineable ----
// Round-14 failure diagnosed: acc1[16]=64 VGPRs left the compiler 8 regs -> every global B-frag
// load serialized behind its MFMA (VGPR_Count=72, MfmaUtil 4%, 525 GB/s). Fix: f-major loops.
//   phase B: hold 3 A-frags (12 VGPRs); per output-frag f: 3 b-loads + 3 chained MFMAs, 1 live acc.
//   phase C: hold 8 h1-frags (32 VGPRs); per f: 8 b-loads + 8 chained MFMAs.
// Live demand ~50-80 VGPRs under the (256,2) cap of 128 -> unrolled f-loop can keep 3-4 iterations
// of B-loads in flight. Output staged through dead As buffer for coalesced 16B stores; p is bf16.
__global__ __launch_bounds__(256, 2) void k_mlp(const unsigned short* __restrict__ A,
                                                const unsigned short* __restrict__ W1bt,  // [256 n][96 k]
                                                const float* __restrict__ bias1,
                                                const unsigned short* __restrict__ Wcbt,  // [96 n][256 k]
                                                unsigned short* __restrict__ P, int M) {
  __shared__ unsigned short As[64][104];   // agg rows (bf16), 13.3 KB; reused as p-out staging in phase C
  __shared__ unsigned short Hs[64][264];   // h1 rows (bf16), stride 528 B: 16B-aligned, 2-way banks
  int t = threadIdx.x;
  int wave = t >> 6, lane = t & 63;
  int l15 = lane & 15, lhi = lane >> 4;
  int bm = blockIdx.x * 64;

  // stage: 64 rows x 12 uint4-groups = 768 tasks, coalesced
#pragma unroll
  for (int it = 0; it < 3; ++it) {
    int idx = t + it * 256;
    int row = idx / 12, g = idx % 12;
    uint4 v = make_uint4(0u, 0u, 0u, 0u);
    if (bm + row < M) v = *(const uint4*)(A + (size_t)(bm + row) * 96 + g * 8);
    *(uint4*)&As[row][g * 8] = v;
  }
  __syncthreads();

  // phase B: h1 = gelu(agg @ W1 + b1); f-major, 16 output frags, K=96 (3 chained MFMAs each)
  {
    int arow = wave * 16 + l15;
    bf16x8 a0 = *(const bf16x8*)&As[arow][0  + lhi * 8];
    bf16x8 a1 = *(const bf16x8*)&As[arow][32 + lhi * 8];
    bf16x8 a2 = *(const bf16x8*)&As[arow][64 + lhi * 8];
    int hrow = wave * 16 + lhi * 4;
#pragma unroll
    for (int f = 0; f < 16; ++f) {
      const unsigned short* wp = W1bt + (size_t)(f * 16 + l15) * 96 + lhi * 8;
      bf16x8 w0_ = *(const bf16x8*)(wp);
      bf16x8 w1_ = *(const bf16x8*)(wp + 32);
      bf16x8 w2_ = *(const bf16x8*)(wp + 64);
      f32x4 acc = (f32x4){0.f, 0.f, 0.f, 0.f};
      acc = __builtin_amdgcn_mfma_f32_16x16x32_bf16(a0, w0_, acc, 0, 0, 0);
      acc = __builtin_amdgcn_mfma_f32_16x16x32_bf16(a1, w1_, acc, 0, 0, 0);
      acc = __builtin_amdgcn_mfma_f32_16x16x32_bf16(a2, w2_, acc, 0, 0, 0);
      int col = f * 16 + l15;
      float bv = bias1[col];
#pragma unroll
      for (int r = 0; r < 4; ++r) {
        float x = acc[r] + bv;
        x = 0.5f * x * (1.0f + erff(x * 0.70710678118654752f));
        Hs[hrow + r][col] = f2bf(x);
      }
    }
  }
  __syncthreads();

  // phase C: p = h1 @ Wc; f-major, 6 output frags, K=256 (8 chained MFMAs each); out via As staging
  {
    int hrow = wave * 16 + l15;
    bf16x8 ha[8];
#pragma unroll
    for (int ks = 0; ks < 8; ++ks) ha[ks] = *(const bf16x8*)&Hs[hrow][ks * 32 + lhi * 8];
    int orow = wave * 16 + lhi * 4;
#pragma unroll
    for (int f = 0; f < 6; ++f) {
      const unsigned short* wp = Wcbt + (size_t)(f * 16 + l15) * 256 + lhi * 8;
      f32x4 acc = (f32x4){0.f, 0.f, 0.f, 0.f};
#pragma unroll
      for (int ks = 0; ks < 8; ++ks) {
        bf16x8 wv = *(const bf16x8*)(wp + ks * 32);
        acc = __builtin_amdgcn_mfma_f32_16x16x32_bf16(ha[ks], wv, acc, 0, 0, 0);
      }
      int col = f * 16 + l15;
#pragma unroll
      for (int r = 0; r < 4; ++r) As[orow + r][col] = f2bf(acc[r]);
    }
  }
  __syncthreads();
  // coalesced p write: 64 rows x 12 uint4-groups
#pragma unroll
  for (int it = 0; it < 3; ++it) {
    int idx = t + it * 256;
    int row = idx / 12, g = idx % 12;
    if (bm + row < M) *(uint4*)(P + (size_t)(bm + row) * 96 + g * 8) = *(const uint4*)&As[row][g * 8];
  }
}

extern "C" void kernel_launch(void* const* d_in, const int* in_sizes, int n_in,
                              void* d_out, int out_size, void* d_ws, size_t ws_size,
                              hipStream_t stream) {
  const float* xm  = (const float*)d_in[0];
  const float* xg  = (const float*)d_in[1];
  const int*   ei  = (const int*)d_in[2];
  const float* W1  = (const float*)d_in[3];
  const float* b1  = (const float*)d_in[4];
  const float* W2  = (const float*)d_in[5];
  const float* b2  = (const float*)d_in[6];
  const float* Wl1 = (const float*)d_in[7];
  const float* bl1 = (const float*)d_in[8];
  const float* Wl2 = (const float*)d_in[9];
  const float* bl2 = (const float*)d_in[10];
  float* out = (float*)d_out;

  // ---- workspace layout (float units) ----
  float* W0 = (float*)d_ws;
  const size_t MB = (size_t)N_GRID * 256;          // 16,680,960
  int*   deg  = (int*)(W0 + MB);
  int*   off  = deg + N_TOT;                       // N_TOT+1
  int*   cur  = off + N_TOT + 1;
  int*   bsum = cur + N_TOT;                       // 512
  int*   csrc = bsum + 512;                        // NE
  float* dinv = (float*)(csrc + NE);               // N_TOT
  size_t p1off = ((size_t)(dinv + N_TOT - W0) + 3) & ~(size_t)3;   // 16B align
  float* P1 = W0 + p1off;                          // 257*96: [Wl1;bl1]@Wl2 (rows 0..255 = T1)
  float* P2 = P1 + 257 * 96;                       // 257*96: [W2;b2]@T1  (rows 0..255 = Wc)
  float* bc = P2 + 257 * 96;                       // 96
  size_t wboff = ((size_t)(bc + 96 - W0) + 3) & ~(size_t)3;        // 16B align
  unsigned short* W1bt = (unsigned short*)(W0 + wboff);            // 256x96 bf16
  unsigned short* Wcbt = W1bt + 256 * 96;                          // 96x256 bf16
  size_t RH = (wboff + 24576 + 3) & ~(size_t)3;    // past both bf16 arrays (24576 floats)
  unsigned short* hb = (unsigned short*)(W0 + RH); // N_TOT x 96 bf16 (5.09M fl)
  unsigned short* agg1b = (unsigned short*)W0;     // [0, 5.1M fl) bf16 (t3-t4)
  unsigned short* p = (unsigned short*)(hb + (size_t)N_TOT * 96 + 16);   // bf16, after hb
  p = (unsigned short*)(((size_t)p + 15) & ~(size_t)15);
  float* tb = W0 + (size_t)6 * 1024 * 1024;        // [6M, 12.25M) fl — clear of agg1b and meta

  const int* esrc = ei;
  const int* edst = ei + NE;
  dim3 b256(256);
  const int NB_N = (N_TOT + 255) / 256;

  // t1. node features (N_TOT, 96) bf16
  k_concat_transpose<<<dim3((N_TOT + 63) / 64), b256, 0, stream>>>(xg, xm, hb);

  // t2. CSR by dst + dinv; weight combine + casts (independent of node pipeline)
  k_zeroi<<<dim3(NB_N), b256, 0, stream>>>(deg, N_TOT);
  k_hist<<<dim3((NE + 255) / 256), b256, 0, stream>>>(edst, deg);
  k_blocksum<<<dim3(NB_N), b256, 0, stream>>>(deg, bsum, N_TOT);
  k_scanbsum<<<dim3(1), dim3(512), 0, stream>>>(bsum, NB_N);
  k_offsets<<<dim3(NB_N), b256, 0, stream>>>(deg, bsum, off, cur, N_TOT);
  k_seti<<<dim3(1), dim3(1), 0, stream>>>(off + N_TOT, NE);
  k_fillcsr<<<dim3((NE + 255) / 256), b256, 0, stream>>>(esrc, edst, cur, csrc);
  k_dinv<<<dim3(NB_N), b256, 0, stream>>>(deg, dinv, N_TOT);
  k_cast_w1t<<<dim3(96), b256, 0, stream>>>(W1, W1bt);
  k_wgemm96<<<dim3(9), b256, 0, stream>>>(Wl1, bl1, Wl2, P1, 257, HID);
  k_wgemm96<<<dim3(9), b256, 0, stream>>>(W2, b2, P1, P2, 257, HID);
  k_bc_final<<<dim3(1), dim3(96), 0, stream>>>(P1 + 256 * 96, P2 + 256 * 96, bl2, bc);
  k_cast_wct<<<dim3(96), b256, 0, stream>>>(P2, Wcbt);

  // t3. agg1 = S @ h   (96 ch, gather, bf16) — standalone, high occupancy
  k_gather96<<<dim3((N_TOT * 24 + 255) / 256), b256, 0, stream>>>(off, csrc, dinv, hb, agg1b);

  // t4. p = gelu(agg1@W1+b1)@Wc  — fused MLP v2 (f-major), h1 stays in LDS, p bf16
  k_mlp<<<dim3((N_TOT + 63) / 64), b256, 0, stream>>>(agg1b, W1bt, b1, Wcbt, p, N_TOT);

  // t5. tb = S_grid @ p + bc   (96 ch, bf16 reads, fp32 accumulate)
  k_gather96p<<<dim3((N_GRID * 24 + 255) / 256), b256, 0, stream>>>(off, csrc, dinv, p, bc, tb);

  // t6. out = tb^T   (96, N_GRID)
  k_transpose_out<<<dim3((N_GRID + 63) / 64), b256, 0, stream>>>(tb, out);
}

// Round 16
// 249.050 us; speedup vs baseline: 1.3490x; 1.0681x over previous
//
#include <hip/hip_runtime.h>
#include <math.h>

#define N_GRID 65160
#define N_MESH 40962
#define N_TOT  106122
#define NE     521280
#define IN_CH  96
#define HID    256
#define OUT_CH 96

typedef __attribute__((ext_vector_type(8))) short bf16x8;   // 8 bf16 in 4 VGPRs (guide §3)
typedef __attribute__((ext_vector_type(4))) float f32x4;

__device__ __forceinline__ unsigned short f2bf(float f) {   // fp32 -> bf16 RNE
  unsigned u = __float_as_uint(f);
  return (unsigned short)((u + 0x7FFFu + ((u >> 16) & 1u)) >> 16);
}
__device__ __forceinline__ float bf2f(unsigned short s) {
  return __uint_as_float(((unsigned)s) << 16);
}
__device__ __forceinline__ float4 ldbf4(const unsigned short* p) {
  ushort4 u = *(const ushort4*)p;
  return make_float4(bf2f(u.x), bf2f(u.y), bf2f(u.z), bf2f(u.w));
}

// ---------------- concat + transpose: (96,N) fp32 channel-major -> (N,96) bf16 node-major ----------------
__global__ void k_concat_transpose(const float* __restrict__ xg, const float* __restrict__ xm,
                                   unsigned short* __restrict__ h) {
  __shared__ float tile[IN_CH][65];
  int base = blockIdx.x * 64;
  int t = threadIdx.x;
#pragma unroll
  for (int it = 0; it < 24; ++it) {
    int lin = t + it * 256;            // 0..6143 over 96x64
    int c  = lin >> 6;
    int n0 = lin & 63;
    int n = base + n0;
    float v = 0.f;
    if (n < N_TOT) {
      v = (n < N_GRID) ? xg[(size_t)c * N_GRID + n]
                       : xm[(size_t)c * N_MESH + (n - N_GRID)];
    }
    tile[c][n0] = v;
  }
  __syncthreads();
#pragma unroll
  for (int it = 0; it < 24; ++it) {
    int lin = t + it * 256;
    int c  = lin % 96;
    int n0 = lin / 96;
    int n = base + n0;
    if (n < N_TOT) h[(size_t)n * IN_CH + c] = f2bf(tile[c][n0]);
  }
}

// ---------------- final transpose: tb (N_GRID,96) fp32 node-major -> out (96,N_GRID) ----------------
__global__ void k_transpose_out(const float* __restrict__ tb, float* __restrict__ out) {
  __shared__ float tile[IN_CH][65];
  int base = blockIdx.x * 64;
  int t = threadIdx.x;
#pragma unroll
  for (int it = 0; it < 24; ++it) {
    int lin = t + it * 256;
    int c  = lin % 96;
    int n0 = lin / 96;
    int n = base + n0;
    if (n < N_GRID) tile[c][n0] = tb[(size_t)n * 96 + c];
  }
  __syncthreads();
#pragma unroll
  for (int it = 0; it < 24; ++it) {
    int lin = t + it * 256;
    int c  = lin >> 6;
    int n0 = lin & 63;
    int n = base + n0;
    if (n < N_GRID) out[(size_t)c * N_GRID + n] = tile[c][n0];
  }
}

// ---------------- CSR build ----------------
__global__ void k_zeroi(int* __restrict__ p, int n) {
  int i = blockIdx.x * 256 + threadIdx.x;
  if (i < n) p[i] = 0;
}
__global__ void k_seti(int* __restrict__ p, int v) { *p = v; }

__global__ void k_hist(const int* __restrict__ dst, int* __restrict__ deg) {
  int e = blockIdx.x * 256 + threadIdx.x;
  if (e < NE) atomicAdd(&deg[dst[e]], 1);
}

__global__ void k_blocksum(const int* __restrict__ deg, int* __restrict__ bsum, int n) {
  __shared__ int s[256];
  int i = blockIdx.x * 256 + threadIdx.x;
  s[threadIdx.x] = (i < n) ? deg[i] : 0;
  __syncthreads();
  for (int st = 128; st > 0; st >>= 1) {
    if (threadIdx.x < st) s[threadIdx.x] += s[threadIdx.x + st];
    __syncthreads();
  }
  if (threadIdx.x == 0) bsum[blockIdx.x] = s[0];
}

__global__ void k_scanbsum(int* __restrict__ bsum, int nb) {   // single block, 512 thr
  __shared__ int s[512];
  int t = threadIdx.x;
  int v = (t < nb) ? bsum[t] : 0;
  s[t] = v;
  __syncthreads();
  for (int off = 1; off < 512; off <<= 1) {
    int x = (t >= off) ? s[t - off] : 0;
    __syncthreads();
    s[t] += x;
    __syncthreads();
  }
  if (t < nb) bsum[t] = s[t] - v;   // exclusive
}

__global__ void k_offsets(const int* __restrict__ deg, const int* __restrict__ bsum,
                          int* __restrict__ off, int* __restrict__ cur, int n) {
  __shared__ int s[256];
  int i = blockIdx.x * 256 + threadIdx.x;
  int v = (i < n) ? deg[i] : 0;
  s[threadIdx.x] = v;
  __syncthreads();
  for (int o = 1; o < 256; o <<= 1) {
    int x = (threadIdx.x >= o) ? s[threadIdx.x - o] : 0;
    __syncthreads();
    s[threadIdx.x] += x;
    __syncthreads();
  }
  if (i < n) {
    int e = bsum[blockIdx.x] + s[threadIdx.x] - v;
    off[i] = e;
    cur[i] = e;
  }
}

__global__ void k_fillcsr(const int* __restrict__ src, const int* __restrict__ dst,
                          int* __restrict__ cur, int* __restrict__ csrc) {
  int e = blockIdx.x * 256 + threadIdx.x;
  if (e < NE) {
    int p = atomicAdd(&cur[dst[e]], 1);
    csrc[p] = src[e];
  }
}

__global__ void k_dinv(const int* __restrict__ deg, float* __restrict__ dinv, int n) {
  int i = blockIdx.x * 256 + threadIdx.x;
  if (i < n) dinv[i] = rsqrtf(1.0f + (float)deg[i]);
}

// ---------------- gather over bf16 h (4-edge unrolled, fp32 accumulate, bf16 out) ----------------
// Standalone: trivial resource footprint -> near-max waves/CU (round-13 lesson: never fuse me).
__global__ void k_gather96(const int* __restrict__ off, const int* __restrict__ csrc,
                           const float* __restrict__ dinv, const unsigned short* __restrict__ h,
                           unsigned short* __restrict__ agg) {
  int i = blockIdx.x * 256 + threadIdx.x;
  if (i >= N_TOT * 24) return;
  int n = i / 24;
  int c4 = (i % 24) << 2;
  float di = dinv[n];
  float4 v = ldbf4(h + (size_t)n * 96 + c4);
  float w0 = di * di;
  float4 acc = make_float4(v.x * w0, v.y * w0, v.z * w0, v.w * w0);
  int e0 = off[n], e1 = off[n + 1];
  int e = e0;
  for (; e + 3 < e1; e += 4) {
    int s0 = csrc[e], s1 = csrc[e + 1], s2 = csrc[e + 2], s3 = csrc[e + 3];
    float wa = dinv[s0] * di, wb = dinv[s1] * di, wc = dinv[s2] * di, wd = dinv[s3] * di;
    float4 u0 = ldbf4(h + (size_t)s0 * 96 + c4);
    float4 u1 = ldbf4(h + (size_t)s1 * 96 + c4);
    float4 u2 = ldbf4(h + (size_t)s2 * 96 + c4);
    float4 u3 = ldbf4(h + (size_t)s3 * 96 + c4);
    acc.x += u0.x * wa + u1.x * wb + u2.x * wc + u3.x * wd;
    acc.y += u0.y * wa + u1.y * wb + u2.y * wc + u3.y * wd;
    acc.z += u0.z * wa + u1.z * wb + u2.z * wc + u3.z * wd;
    acc.w += u0.w * wa + u1.w * wb + u2.w * wc + u3.w * wd;
  }
  for (; e < e1; ++e) {
    int s = csrc[e];
    float w = dinv[s] * di;
    float4 u = ldbf4(h + (size_t)s * 96 + c4);
    acc.x += u.x * w; acc.y += u.y * w; acc.z += u.z * w; acc.w += u.w * w;
  }
  ushort4 o;
  o.x = f2bf(acc.x); o.y = f2bf(acc.y); o.z = f2bf(acc.z); o.w = f2bf(acc.w);
  *(ushort4*)(agg + (size_t)n * 96 + c4) = o;
}

// gather over p (bf16, 96 ch) for grid nodes only, + combined bias bc, write tb node-major fp32
__global__ void k_gather96p(const int* __restrict__ off, const int* __restrict__ csrc,
                            const float* __restrict__ dinv, const unsigned short* __restrict__ p,
                            const float* __restrict__ bc, float* __restrict__ tb) {
  int i = blockIdx.x * 256 + threadIdx.x;
  if (i >= N_GRID * 24) return;
  int n = i / 24;
  int c4 = (i % 24) << 2;
  float di = dinv[n];
  float4 v = ldbf4(p + (size_t)n * 96 + c4);
  float w0 = di * di;
  float4 acc = make_float4(v.x * w0, v.y * w0, v.z * w0, v.w * w0);
  int e0 = off[n], e1 = off[n + 1];
  int e = e0;
  for (; e + 3 < e1; e += 4) {
    int s0 = csrc[e], s1 = csrc[e + 1], s2 = csrc[e + 2], s3 = csrc[e + 3];
    float wa = dinv[s0] * di, wb = dinv[s1] * di, wc = dinv[s2] * di, wd = dinv[s3] * di;
    float4 u0 = ldbf4(p + (size_t)s0 * 96 + c4);
    float4 u1 = ldbf4(p + (size_t)s1 * 96 + c4);
    float4 u2 = ldbf4(p + (size_t)s2 * 96 + c4);
    float4 u3 = ldbf4(p + (size_t)s3 * 96 + c4);
    acc.x += u0.x * wa + u1.x * wb + u2.x * wc + u3.x * wd;
    acc.y += u0.y * wa + u1.y * wb + u2.y * wc + u3.y * wd;
    acc.z += u0.z * wa + u1.z * wb + u2.z * wc + u3.z * wd;
    acc.w += u0.w * wa + u1.w * wb + u2.w * wc + u3.w * wd;
  }
  for (; e < e1; ++e) {
    int s = csrc[e];
    float w = dinv[s] * di;
    float4 u = ldbf4(p + (size_t)s * 96 + c4);
    acc.x += u.x * w; acc.y += u.y * w; acc.z += u.z * w; acc.w += u.w * w;
  }
  float4 b = *(const float4*)(bc + c4);
  acc.x += b.x; acc.y += b.y; acc.z += b.z; acc.w += b.w;
  *(float4*)(tb + (size_t)n * 96 + c4) = acc;
}

// ---------------- small-matrix weight GEMM: C(Mx96) = [A; bvec](MxK) @ B(Kx96) ----------------
__global__ __launch_bounds__(256, 2) void k_wgemm96(const float* __restrict__ A, const float* __restrict__ bvec,
                                                    const float* __restrict__ B, float* __restrict__ C,
                                                    int M, int K) {
  __shared__ float As[64][33];
  __shared__ float Bs[64][100];
  int t = threadIdx.x;
  int tx = t & 15, ty = t >> 4;
  int bm = blockIdx.x * 32;
  float acc[2][6] = {};
  for (int kc = 0; kc < K; kc += 64) {
#pragma unroll
    for (int it = 0; it < 2; ++it) {
      int idx = t + it * 256;
      int r = idx >> 4, k4 = (idx & 15) << 2;
      int gr = bm + r;
      float4 v = make_float4(0.f, 0.f, 0.f, 0.f);
      if (gr < M) {
        const float* src = (gr < M - 1) ? (A + (size_t)gr * K + kc + k4) : (bvec + kc + k4);
        v = *(const float4*)src;
      }
      As[k4 + 0][r] = v.x;
      As[k4 + 1][r] = v.y;
      As[k4 + 2][r] = v.z;
      As[k4 + 3][r] = v.w;
    }
#pragma unroll
    for (int it = 0; it < 6; ++it) {
      int idx = t + it * 256;
      int k = idx / 24, j4 = (idx % 24) << 2;
      float4 v = *(const float4*)(B + (size_t)(kc + k) * 96 + j4);
      *(float4*)&Bs[k][j4] = v;
    }
    __syncthreads();
#pragma unroll
    for (int k = 0; k < 64; ++k) {
      float a0 = As[k][ty * 2], a1 = As[k][ty * 2 + 1];
      float w[6];
      *(float2*)&w[0] = *(const float2*)&Bs[k][tx * 6];
      *(float2*)&w[2] = *(const float2*)&Bs[k][tx * 6 + 2];
      *(float2*)&w[4] = *(const float2*)&Bs[k][tx * 6 + 4];
#pragma unroll
      for (int j = 0; j < 6; ++j) { acc[0][j] += a0 * w[j]; acc[1][j] += a1 * w[j]; }
    }
    __syncthreads();
  }
#pragma unroll
  for (int i = 0; i < 2; ++i) {
    int gr = bm + ty * 2 + i;
    if (gr >= M) continue;
    float* row = C + (size_t)gr * 96 + tx * 6;
    row[0] = acc[i][0]; row[1] = acc[i][1]; row[2] = acc[i][2];
    row[3] = acc[i][3]; row[4] = acc[i][4]; row[5] = acc[i][5];
  }
}

// bc[j] = P1[256][j] + P2[256][j] + bl2[j]
__global__ void k_bc_final(const float* __restrict__ r1, const float* __restrict__ r2,
                           const float* __restrict__ bl2, float* __restrict__ bc) {
  int j = threadIdx.x;
  if (j < OUT_CH) bc[j] = r1[j] + r2[j] + bl2[j];
}

// ---------------- weight casts (fp32 -> bf16, transposed to col-major) ----------------
__global__ void k_cast_w1t(const float* __restrict__ W1, unsigned short* __restrict__ W1bt) {
  int idx = blockIdx.x * 256 + threadIdx.x;          // over [256 n][96 k]
  if (idx >= 256 * 96) return;
  int n = idx / 96, k = idx % 96;
  W1bt[idx] = f2bf(W1[(size_t)k * 256 + n]);
}
__global__ void k_cast_wct(const float* __restrict__ Wc, unsigned short* __restrict__ Wcbt) {
  int idx = blockIdx.x * 256 + threadIdx.x;          // over [96 n][256 k]
  if (idx >= 96 * 256) return;
  int n = idx / 256, k = idx % 256;
  Wcbt[idx] = f2bf(Wc[(size_t)k * 96 + n]);
}

// ---------------- FUSED MLP v3: p = (gelu(agg @ W1 + b1)) @ Wc, LDS weight-chunk staging ----
// Round-15 diagnosis: per-wave global B-frag reads = 384 KB L2/block (637 MB total) in scattered
// 16B/lane loads -> latency/L2-bound at MfmaUtil 5%. Fix (round-12's trick, fused): cooperatively
// stage weight chunks into a 13 KB LDS buffer; B-frags read from LDS (2-way banks, free).
// Per-block weight L2 traffic 384 KB -> 96 KB.
//   phase B: 4 chunks x (4 f = 64 rows of W1bt, 12 KB);  A-frags in regs (loaded once from As).
//   phase C: 4 chunks x (3 f x 128 k, 12.8 KB); per-f accs persist across the two K-halves.
// LDS: As 13.3 + Hs 33.8 + Ws 13.3 = 60.4 KB -> 2 blocks/CU. Hs stays wave-private (no sync needed
// for it); barriers protect only the shared Ws buffer. h1 never touches HBM; p bf16 out via As.
__global__ __launch_bounds__(256, 2) void k_mlp(const unsigned short* __restrict__ A,
                                                const unsigned short* __restrict__ W1bt,  // [256 n][96 k]
                                                const float* __restrict__ bias1,
                                                const unsigned short* __restrict__ Wcbt,  // [96 n][256 k]
                                                unsigned short* __restrict__ P, int M) {
  __shared__ unsigned short As[64][104];   // agg rows; later p-out staging (cols < 104 ✓)
  __shared__ unsigned short Hs[64][264];   // h1 rows, wave-private (each wave writes/reads own 16 rows)
  __shared__ unsigned short Ws[6656];      // weight chunk: B: [64][104]; C: [48][136]
  int t = threadIdx.x;
  int wave = t >> 6, lane = t & 63;
  int l15 = lane & 15, lhi = lane >> 4;
  int bm = blockIdx.x * 64;

  // stage As: 64 rows x 12 uint4-groups, coalesced
#pragma unroll
  for (int it = 0; it < 3; ++it) {
    int idx = t + it * 256;
    int row = idx / 12, g = idx % 12;
    uint4 v = make_uint4(0u, 0u, 0u, 0u);
    if (bm + row < M) v = *(const uint4*)(A + (size_t)(bm + row) * 96 + g * 8);
    *(uint4*)&As[row][g * 8] = v;
  }
  __syncthreads();

  // A-frags to registers (As content then dead -> reusable for output staging)
  int arow = wave * 16 + l15;
  bf16x8 a0 = *(const bf16x8*)&As[arow][0  + lhi * 8];
  bf16x8 a1 = *(const bf16x8*)&As[arow][32 + lhi * 8];
  bf16x8 a2 = *(const bf16x8*)&As[arow][64 + lhi * 8];
  int hrow = wave * 16 + lhi * 4;

  // ---- phase B: h1 = gelu(agg @ W1 + b1); 4 chunks of 4 f ----
  for (int c = 0; c < 4; ++c) {
    __syncthreads();                       // Ws free (prev chunk consumed / As handoff done)
#pragma unroll
    for (int it = 0; it < 3; ++it) {       // stage 64 rows x 96 bf16 of W1bt, coalesced
      int idx = t + it * 256;
      int row = idx / 12, g = idx % 12;
      *(uint4*)&Ws[row * 104 + g * 8] = *(const uint4*)(W1bt + (size_t)(c * 64 + row) * 96 + g * 8);
    }
    __syncthreads();
#pragma unroll
    for (int fl = 0; fl < 4; ++fl) {
      int f = c * 4 + fl;
      const unsigned short* wp = &Ws[(fl * 16 + l15) * 104 + lhi * 8];
      bf16x8 w0_ = *(const bf16x8*)(wp);
      bf16x8 w1_ = *(const bf16x8*)(wp + 32);
      bf16x8 w2_ = *(const bf16x8*)(wp + 64);
      f32x4 acc = (f32x4){0.f, 0.f, 0.f, 0.f};
      acc = __builtin_amdgcn_mfma_f32_16x16x32_bf16(a0, w0_, acc, 0, 0, 0);
      acc = __builtin_amdgcn_mfma_f32_16x16x32_bf16(a1, w1_, acc, 0, 0, 0);
      acc = __builtin_amdgcn_mfma_f32_16x16x32_bf16(a2, w2_, acc, 0, 0, 0);
      int col = f * 16 + l15;
      float bv = bias1[col];
#pragma unroll
      for (int r = 0; r < 4; ++r) {
        float x = acc[r] + bv;
        x = 0.5f * x * (1.0f + erff(x * 0.70710678118654752f));
        Hs[hrow + r][col] = f2bf(x);
      }
    }
  }

  // ---- phase C: p = h1 @ Wc; 2 f-triples x 2 K-halves; accs persist across K-halves ----
  int orow = wave * 16 + lhi * 4;
  for (int tf = 0; tf < 2; ++tf) {
    f32x4 accC[3];
#pragma unroll
    for (int fl = 0; fl < 3; ++fl) accC[fl] = (f32x4){0.f, 0.f, 0.f, 0.f};
    for (int kh = 0; kh < 2; ++kh) {
      __syncthreads();                     // Ws free
#pragma unroll
      for (int it = 0; it < 3; ++it) {     // stage 48 rows x 128 bf16 of Wcbt, coalesced
        int idx = t + it * 256;
        int row = idx >> 4, g = idx & 15;
        *(uint4*)&Ws[row * 136 + g * 8] =
            *(const uint4*)(Wcbt + (size_t)(tf * 48 + row) * 256 + kh * 128 + g * 8);
      }
      __syncthreads();
#pragma unroll
      for (int fl = 0; fl < 3; ++fl) {
        const unsigned short* wp = &Ws[(fl * 16 + l15) * 136 + lhi * 8];
        // this K-half holds k-slots kh*4 .. kh*4+3 of Hs
#pragma unroll
        for (int ks = 0; ks < 4; ++ks) {
          bf16x8 av = *(const bf16x8*)&Hs[wave * 16 + l15][(kh * 4 + ks) * 32 + lhi * 8];
          bf16x8 wv = *(const bf16x8*)(wp + ks * 32);
          accC[fl] = __builtin_amdgcn_mfma_f32_16x16x32_bf16(av, wv, accC[fl], 0, 0, 0);
        }
      }
    }
#pragma unroll
    for (int fl = 0; fl < 3; ++fl) {
      int col = (tf * 3 + fl) * 16 + l15;
#pragma unroll
      for (int r = 0; r < 4; ++r) As[orow + r][col] = f2bf(accC[fl][r]);
    }
  }
  __syncthreads();
  // coalesced p write: 64 rows x 12 uint4-groups
#pragma unroll
  for (int it = 0; it < 3; ++it) {
    int idx = t + it * 256;
    int row = idx / 12, g = idx % 12;
    if (bm + row < M) *(uint4*)(P + (size_t)(bm + row) * 96 + g * 8) = *(const uint4*)&As[row][g * 8];
  }
}

extern "C" void kernel_launch(void* const* d_in, const int* in_sizes, int n_in,
                              void* d_out, int out_size, void* d_ws, size_t ws_size,
                              hipStream_t stream) {
  const float* xm  = (const float*)d_in[0];
  const float* xg  = (const float*)d_in[1];
  const int*   ei  = (const int*)d_in[2];
  const float* W1  = (const float*)d_in[3];
  const float* b1  = (const float*)d_in[4];
  const float* W2  = (const float*)d_in[5];
  const float* b2  = (const float*)d_in[6];
  const float* Wl1 = (const float*)d_in[7];
  const float* bl1 = (const float*)d_in[8];
  const float* Wl2 = (const float*)d_in[9];
  const float* bl2 = (const float*)d_in[10];
  float* out = (float*)d_out;

  // ---- workspace layout (float units) ----
  float* W0 = (float*)d_ws;
  const size_t MB = (size_t)N_GRID * 256;          // 16,680,960
  int*   deg  = (int*)(W0 + MB);
  int*   off  = deg + N_TOT;                       // N_TOT+1
  int*   cur  = off + N_TOT + 1;
  int*   bsum = cur + N_TOT;                       // 512
  int*   csrc = bsum + 512;                        // NE
  float* dinv = (float*)(csrc + NE);               // N_TOT
  size_t p1off = ((size_t)(dinv + N_TOT - W0) + 3) & ~(size_t)3;   // 16B align
  float* P1 = W0 + p1off;                          // 257*96: [Wl1;bl1]@Wl2 (rows 0..255 = T1)
  float* P2 = P1 + 257 * 96;                       // 257*96: [W2;b2]@T1  (rows 0..255 = Wc)
  float* bc = P2 + 257 * 96;                       // 96
  size_t wboff = ((size_t)(bc + 96 - W0) + 3) & ~(size_t)3;        // 16B align
  unsigned short* W1bt = (unsigned short*)(W0 + wboff);            // 256x96 bf16
  unsigned short* Wcbt = W1bt + 256 * 96;                          // 96x256 bf16
  size_t RH = (wboff + 24576 + 3) & ~(size_t)3;    // past both bf16 arrays (24576 floats)
  unsigned short* hb = (unsigned short*)(W0 + RH); // N_TOT x 96 bf16 (5.09M fl)
  unsigned short* agg1b = (unsigned short*)W0;     // [0, 5.1M fl) bf16 (t3-t4)
  unsigned short* p = (unsigned short*)(hb + (size_t)N_TOT * 96 + 16);   // bf16, after hb
  p = (unsigned short*)(((size_t)p + 15) & ~(size_t)15);
  float* tb = W0 + (size_t)6 * 1024 * 1024;        // [6M, 12.25M) fl — clear of agg1b and meta

  const int* esrc = ei;
  const int* edst = ei + NE;
  dim3 b256(256);
  const int NB_N = (N_TOT + 255) / 256;

  // t1. node features (N_TOT, 96) bf16
  k_concat_transpose<<<dim3((N_TOT + 63) / 64), b256, 0, stream>>>(xg, xm, hb);

  // t2. CSR by dst + dinv; weight combine + casts (independent of node pipeline)
  k_zeroi<<<dim3(NB_N), b256, 0, stream>>>(deg, N_TOT);
  k_hist<<<dim3((NE + 255) / 256), b256, 0, stream>>>(edst, deg);
  k_blocksum<<<dim3(NB_N), b256, 0, stream>>>(deg, bsum, N_TOT);
  k_scanbsum<<<dim3(1), dim3(512), 0, stream>>>(bsum, NB_N);
  k_offsets<<<dim3(NB_N), b256, 0, stream>>>(deg, bsum, off, cur, N_TOT);
  k_seti<<<dim3(1), dim3(1), 0, stream>>>(off + N_TOT, NE);
  k_fillcsr<<<dim3((NE + 255) / 256), b256, 0, stream>>>(esrc, edst, cur, csrc);
  k_dinv<<<dim3(NB_N), b256, 0, stream>>>(deg, dinv, N_TOT);
  k_cast_w1t<<<dim3(96), b256, 0, stream>>>(W1, W1bt);
  k_wgemm96<<<dim3(9), b256, 0, stream>>>(Wl1, bl1, Wl2, P1, 257, HID);
  k_wgemm96<<<dim3(9), b256, 0, stream>>>(W2, b2, P1, P2, 257, HID);
  k_bc_final<<<dim3(1), dim3(96), 0, stream>>>(P1 + 256 * 96, P2 + 256 * 96, bl2, bc);
  k_cast_wct<<<dim3(96), b256, 0, stream>>>(P2, Wcbt);

  // t3. agg1 = S @ h   (96 ch, gather, bf16) — standalone, high occupancy
  k_gather96<<<dim3((N_TOT * 24 + 255) / 256), b256, 0, stream>>>(off, csrc, dinv, hb, agg1b);

  // t4. p = gelu(agg1@W1+b1)@Wc  — fused MLP v3 (LDS weight chunks), h1 stays in LDS, p bf16
  k_mlp<<<dim3((N_TOT + 63) / 64), b256, 0, stream>>>(agg1b, W1bt, b1, Wcbt, p, N_TOT);

  // t5. tb = S_grid @ p + bc   (96 ch, bf16 reads, fp32 accumulate)
  k_gather96p<<<dim3((N_GRID * 24 + 255) / 256), b256, 0, stream>>>(off, csrc, dinv, p, bc, tb);

  // t6. out = tb^T   (96, N_GRID)
  k_transpose_out<<<dim3((N_GRID + 63) / 64), b256, 0, stream>>>(tb, out);
}

// Round 17
// 239.328 us; speedup vs baseline: 1.4038x; 1.0406x over previous
//
#include <hip/hip_runtime.h>
#include <math.h>

#define N_GRID 65160
#define N_MESH 40962
#define N_TOT  106122
#define NE     521280
#define IN_CH  96
#define HID    256
#define OUT_CH 96

typedef __attribute__((ext_vector_type(8))) short bf16x8;   // 8 bf16 in 4 VGPRs (guide §3)
typedef __attribute__((ext_vector_type(4))) float f32x4;

__device__ __forceinline__ unsigned short f2bf(float f) {   // fp32 -> bf16 RNE
  unsigned u = __float_as_uint(f);
  return (unsigned short)((u + 0x7FFFu + ((u >> 16) & 1u)) >> 16);
}
__device__ __forceinline__ float bf2f(unsigned short s) {
  return __uint_as_float(((unsigned)s) << 16);
}
__device__ __forceinline__ float4 ldbf4(const unsigned short* p) {
  ushort4 u = *(const ushort4*)p;
  return make_float4(bf2f(u.x), bf2f(u.y), bf2f(u.z), bf2f(u.w));
}

// ---------------- concat + transpose: (96,N) fp32 channel-major -> (N,96) bf16 node-major ----------------
__global__ void k_concat_transpose(const float* __restrict__ xg, const float* __restrict__ xm,
                                   unsigned short* __restrict__ h) {
  __shared__ float tile[IN_CH][65];
  int base = blockIdx.x * 64;
  int t = threadIdx.x;
#pragma unroll
  for (int it = 0; it < 24; ++it) {
    int lin = t + it * 256;            // 0..6143 over 96x64
    int c  = lin >> 6;
    int n0 = lin & 63;
    int n = base + n0;
    float v = 0.f;
    if (n < N_TOT) {
      v = (n < N_GRID) ? xg[(size_t)c * N_GRID + n]
                       : xm[(size_t)c * N_MESH + (n - N_GRID)];
    }
    tile[c][n0] = v;
  }
  __syncthreads();
#pragma unroll
  for (int it = 0; it < 24; ++it) {
    int lin = t + it * 256;
    int c  = lin % 96;
    int n0 = lin / 96;
    int n = base + n0;
    if (n < N_TOT) h[(size_t)n * IN_CH + c] = f2bf(tile[c][n0]);
  }
}

// ---------------- final transpose: tb (N_GRID,96) fp32 node-major -> out (96,N_GRID) ----------------
__global__ void k_transpose_out(const float* __restrict__ tb, float* __restrict__ out) {
  __shared__ float tile[IN_CH][65];
  int base = blockIdx.x * 64;
  int t = threadIdx.x;
#pragma unroll
  for (int it = 0; it < 24; ++it) {
    int lin = t + it * 256;
    int c  = lin % 96;
    int n0 = lin / 96;
    int n = base + n0;
    if (n < N_GRID) tile[c][n0] = tb[(size_t)n * 96 + c];
  }
  __syncthreads();
#pragma unroll
  for (int it = 0; it < 24; ++it) {
    int lin = t + it * 256;
    int c  = lin >> 6;
    int n0 = lin & 63;
    int n = base + n0;
    if (n < N_GRID) out[(size_t)c * N_GRID + n] = tile[c][n0];
  }
}

// ---------------- CSR build ----------------
__global__ void k_zeroi(int* __restrict__ p, int n) {
  int i = blockIdx.x * 256 + threadIdx.x;
  if (i < n) p[i] = 0;
}
__global__ void k_seti(int* __restrict__ p, int v) { *p = v; }

__global__ void k_hist(const int* __restrict__ dst, int* __restrict__ deg) {
  int e = blockIdx.x * 256 + threadIdx.x;
  if (e < NE) atomicAdd(&deg[dst[e]], 1);
}

__global__ void k_blocksum(const int* __restrict__ deg, int* __restrict__ bsum, int n) {
  __shared__ int s[256];
  int i = blockIdx.x * 256 + threadIdx.x;
  s[threadIdx.x] = (i < n) ? deg[i] : 0;
  __syncthreads();
  for (int st = 128; st > 0; st >>= 1) {
    if (threadIdx.x < st) s[threadIdx.x] += s[threadIdx.x + st];
    __syncthreads();
  }
  if (threadIdx.x == 0) bsum[blockIdx.x] = s[0];
}

__global__ void k_scanbsum(int* __restrict__ bsum, int nb) {   // single block, 512 thr
  __shared__ int s[512];
  int t = threadIdx.x;
  int v = (t < nb) ? bsum[t] : 0;
  s[t] = v;
  __syncthreads();
  for (int off = 1; off < 512; off <<= 1) {
    int x = (t >= off) ? s[t - off] : 0;
    __syncthreads();
    s[t] += x;
    __syncthreads();
  }
  if (t < nb) bsum[t] = s[t] - v;   // exclusive
}

__global__ void k_offsets(const int* __restrict__ deg, const int* __restrict__ bsum,
                          int* __restrict__ off, int* __restrict__ cur, int n) {
  __shared__ int s[256];
  int i = blockIdx.x * 256 + threadIdx.x;
  int v = (i < n) ? deg[i] : 0;
  s[threadIdx.x] = v;
  __syncthreads();
  for (int o = 1; o < 256; o <<= 1) {
    int x = (threadIdx.x >= o) ? s[threadIdx.x - o] : 0;
    __syncthreads();
    s[threadIdx.x] += x;
    __syncthreads();
  }
  if (i < n) {
    int e = bsum[blockIdx.x] + s[threadIdx.x] - v;
    off[i] = e;
    cur[i] = e;
  }
}

__global__ void k_fillcsr(const int* __restrict__ src, const int* __restrict__ dst,
                          int* __restrict__ cur, int* __restrict__ csrc) {
  int e = blockIdx.x * 256 + threadIdx.x;
  if (e < NE) {
    int p = atomicAdd(&cur[dst[e]], 1);
    csrc[p] = src[e];
  }
}

__global__ void k_dinv(const int* __restrict__ deg, float* __restrict__ dinv, int n) {
  int i = blockIdx.x * 256 + threadIdx.x;
  if (i < n) dinv[i] = rsqrtf(1.0f + (float)deg[i]);
}

// ---------------- gather over bf16 h (4-edge unrolled, fp32 accumulate, bf16 out) ----------------
// Standalone: trivial resource footprint -> near-max waves/CU (round-13 lesson: never fuse me).
__global__ void k_gather96(const int* __restrict__ off, const int* __restrict__ csrc,
                           const float* __restrict__ dinv, const unsigned short* __restrict__ h,
                           unsigned short* __restrict__ agg) {
  int i = blockIdx.x * 256 + threadIdx.x;
  if (i >= N_TOT * 24) return;
  int n = i / 24;
  int c4 = (i % 24) << 2;
  float di = dinv[n];
  float4 v = ldbf4(h + (size_t)n * 96 + c4);
  float w0 = di * di;
  float4 acc = make_float4(v.x * w0, v.y * w0, v.z * w0, v.w * w0);
  int e0 = off[n], e1 = off[n + 1];
  int e = e0;
  for (; e + 3 < e1; e += 4) {
    int s0 = csrc[e], s1 = csrc[e + 1], s2 = csrc[e + 2], s3 = csrc[e + 3];
    float wa = dinv[s0] * di, wb = dinv[s1] * di, wc = dinv[s2] * di, wd = dinv[s3] * di;
    float4 u0 = ldbf4(h + (size_t)s0 * 96 + c4);
    float4 u1 = ldbf4(h + (size_t)s1 * 96 + c4);
    float4 u2 = ldbf4(h + (size_t)s2 * 96 + c4);
    float4 u3 = ldbf4(h + (size_t)s3 * 96 + c4);
    acc.x += u0.x * wa + u1.x * wb + u2.x * wc + u3.x * wd;
    acc.y += u0.y * wa + u1.y * wb + u2.y * wc + u3.y * wd;
    acc.z += u0.z * wa + u1.z * wb + u2.z * wc + u3.z * wd;
    acc.w += u0.w * wa + u1.w * wb + u2.w * wc + u3.w * wd;
  }
  for (; e < e1; ++e) {
    int s = csrc[e];
    float w = dinv[s] * di;
    float4 u = ldbf4(h + (size_t)s * 96 + c4);
    acc.x += u.x * w; acc.y += u.y * w; acc.z += u.z * w; acc.w += u.w * w;
  }
  ushort4 o;
  o.x = f2bf(acc.x); o.y = f2bf(acc.y); o.z = f2bf(acc.z); o.w = f2bf(acc.w);
  *(ushort4*)(agg + (size_t)n * 96 + c4) = o;
}

// gather over p (bf16, 96 ch) for grid nodes only, + combined bias bc, write tb node-major fp32
__global__ void k_gather96p(const int* __restrict__ off, const int* __restrict__ csrc,
                            const float* __restrict__ dinv, const unsigned short* __restrict__ p,
                            const float* __restrict__ bc, float* __restrict__ tb) {
  int i = blockIdx.x * 256 + threadIdx.x;
  if (i >= N_GRID * 24) return;
  int n = i / 24;
  int c4 = (i % 24) << 2;
  float di = dinv[n];
  float4 v = ldbf4(p + (size_t)n * 96 + c4);
  float w0 = di * di;
  float4 acc = make_float4(v.x * w0, v.y * w0, v.z * w0, v.w * w0);
  int e0 = off[n], e1 = off[n + 1];
  int e = e0;
  for (; e + 3 < e1; e += 4) {
    int s0 = csrc[e], s1 = csrc[e + 1], s2 = csrc[e + 2], s3 = csrc[e + 3];
    float wa = dinv[s0] * di, wb = dinv[s1] * di, wc = dinv[s2] * di, wd = dinv[s3] * di;
    float4 u0 = ldbf4(p + (size_t)s0 * 96 + c4);
    float4 u1 = ldbf4(p + (size_t)s1 * 96 + c4);
    float4 u2 = ldbf4(p + (size_t)s2 * 96 + c4);
    float4 u3 = ldbf4(p + (size_t)s3 * 96 + c4);
    acc.x += u0.x * wa + u1.x * wb + u2.x * wc + u3.x * wd;
    acc.y += u0.y * wa + u1.y * wb + u2.y * wc + u3.y * wd;
    acc.z += u0.z * wa + u1.z * wb + u2.z * wc + u3.z * wd;
    acc.w += u0.w * wa + u1.w * wb + u2.w * wc + u3.w * wd;
  }
  for (; e < e1; ++e) {
    int s = csrc[e];
    float w = dinv[s] * di;
    float4 u = ldbf4(p + (size_t)s * 96 + c4);
    acc.x += u.x * w; acc.y += u.y * w; acc.z += u.z * w; acc.w += u.w * w;
  }
  float4 b = *(const float4*)(bc + c4);
  acc.x += b.x; acc.y += b.y; acc.z += b.z; acc.w += b.w;
  *(float4*)(tb + (size_t)n * 96 + c4) = acc;
}

// ---------------- small-matrix weight GEMM: C(Mx96) = [A; bvec](MxK) @ B(Kx96) ----------------
__global__ __launch_bounds__(256, 2) void k_wgemm96(const float* __restrict__ A, const float* __restrict__ bvec,
                                                    const float* __restrict__ B, float* __restrict__ C,
                                                    int M, int K) {
  __shared__ float As[64][33];
  __shared__ float Bs[64][100];
  int t = threadIdx.x;
  int tx = t & 15, ty = t >> 4;
  int bm = blockIdx.x * 32;
  float acc[2][6] = {};
  for (int kc = 0; kc < K; kc += 64) {
#pragma unroll
    for (int it = 0; it < 2; ++it) {
      int idx = t + it * 256;
      int r = idx >> 4, k4 = (idx & 15) << 2;
      int gr = bm + r;
      float4 v = make_float4(0.f, 0.f, 0.f, 0.f);
      if (gr < M) {
        const float* src = (gr < M - 1) ? (A + (size_t)gr * K + kc + k4) : (bvec + kc + k4);
        v = *(const float4*)src;
      }
      As[k4 + 0][r] = v.x;
      As[k4 + 1][r] = v.y;
      As[k4 + 2][r] = v.z;
      As[k4 + 3][r] = v.w;
    }
#pragma unroll
    for (int it = 0; it < 6; ++it) {
      int idx = t + it * 256;
      int k = idx / 24, j4 = (idx % 24) << 2;
      float4 v = *(const float4*)(B + (size_t)(kc + k) * 96 + j4);
      *(float4*)&Bs[k][j4] = v;
    }
    __syncthreads();
#pragma unroll
    for (int k = 0; k < 64; ++k) {
      float a0 = As[k][ty * 2], a1 = As[k][ty * 2 + 1];
      float w[6];
      *(float2*)&w[0] = *(const float2*)&Bs[k][tx * 6];
      *(float2*)&w[2] = *(const float2*)&Bs[k][tx * 6 + 2];
      *(float2*)&w[4] = *(const float2*)&Bs[k][tx * 6 + 4];
#pragma unroll
      for (int j = 0; j < 6; ++j) { acc[0][j] += a0 * w[j]; acc[1][j] += a1 * w[j]; }
    }
    __syncthreads();
  }
#pragma unroll
  for (int i = 0; i < 2; ++i) {
    int gr = bm + ty * 2 + i;
    if (gr >= M) continue;
    float* row = C + (size_t)gr * 96 + tx * 6;
    row[0] = acc[i][0]; row[1] = acc[i][1]; row[2] = acc[i][2];
    row[3] = acc[i][3]; row[4] = acc[i][4]; row[5] = acc[i][5];
  }
}

// bc[j] = P1[256][j] + P2[256][j] + bl2[j]
__global__ void k_bc_final(const float* __restrict__ r1, const float* __restrict__ r2,
                           const float* __restrict__ bl2, float* __restrict__ bc) {
  int j = threadIdx.x;
  if (j < OUT_CH) bc[j] = r1[j] + r2[j] + bl2[j];
}

// ---------------- weight casts (fp32 -> bf16, transposed to col-major) ----------------
__global__ void k_cast_w1t(const float* __restrict__ W1, unsigned short* __restrict__ W1bt) {
  int idx = blockIdx.x * 256 + threadIdx.x;          // over [256 n][96 k]
  if (idx >= 256 * 96) return;
  int n = idx / 96, k = idx % 96;
  W1bt[idx] = f2bf(W1[(size_t)k * 256 + n]);
}
__global__ void k_cast_wct(const float* __restrict__ Wc, unsigned short* __restrict__ Wcbt) {
  int idx = blockIdx.x * 256 + threadIdx.x;          // over [96 n][256 k]
  if (idx >= 96 * 256) return;
  int n = idx / 256, k = idx % 256;
  Wcbt[idx] = f2bf(Wc[(size_t)k * 96 + n]);
}

// ---------------- FUSED MLP v4: swizzled LDS, no As buffer, 48 KB -> 3 blocks/CU ----------------
// Round-16 diagnosis: SQ_LDS_BANK_CONFLICT 3.4M — Hs stride 264 bf16 (132 dw ≡ 4 mod 32) made the
// MFMA A-reads (16 lanes = 16 ROWS at fixed col-group, the G4/T2 pattern) ~8-way conflicted; and
// 60.4 KB LDS capped occupancy at 2 blocks/CU. Fix:
//  * power-of-2 row strides (Hs 256, Ws 128 bf16) + XOR swizzle: group g' = g ^ (row&7)
//    -> 16 rows touch 8 distinct 16B slots = 2-way = free (m136). Same swizzle on write & read.
//  * A-frags load direct from global (3 x bf16x8, once); p stores direct (round-12 pattern).
//    LDS = Hs 32 KB + Ws 16 KB = 48 KB -> 3 blocks/CU.
// Hs remains wave-private (rows wave*16..+15 written and read only by own wave -> no barrier).
#define SWZ(row, g) (((row) << 7) + (((g) ^ ((row) & 7)) << 3))          // Ws: [64][128] bf16
#define SWZH(row, g) (((row) << 8) + (((g) ^ ((row) & 7)) << 3))         // Hs: [64][256] bf16
__global__ __launch_bounds__(256, 2) void k_mlp(const unsigned short* __restrict__ A,
                                                const unsigned short* __restrict__ W1bt,  // [256 n][96 k]
                                                const float* __restrict__ bias1,
                                                const unsigned short* __restrict__ Wcbt,  // [96 n][256 k]
                                                unsigned short* __restrict__ P, int M) {
  __shared__ unsigned short Hs[64 * 256];  // h1 rows (bf16), swizzled, 32 KB
  __shared__ unsigned short Ws[64 * 128];  // weight chunk (bf16), swizzled, 16 KB
  int t = threadIdx.x;
  int wave = t >> 6, lane = t & 63;
  int l15 = lane & 15, lhi = lane >> 4;
  int bm = blockIdx.x * 64;

  // A-frags direct from global (row bm+wave*16+l15, k-groups 0/32/64 + lhi*8)
  int arowl = wave * 16 + l15;
  bool aok = (bm + arowl) < M;
  const unsigned short* ap = A + (size_t)(bm + arowl) * 96 + lhi * 8;
  bf16x8 a0 = aok ? *(const bf16x8*)(ap)      : (bf16x8){0,0,0,0,0,0,0,0};
  bf16x8 a1 = aok ? *(const bf16x8*)(ap + 32) : (bf16x8){0,0,0,0,0,0,0,0};
  bf16x8 a2 = aok ? *(const bf16x8*)(ap + 64) : (bf16x8){0,0,0,0,0,0,0,0};
  int hrow = wave * 16 + lhi * 4;

  // ---- phase B: h1 = gelu(agg @ W1 + b1); 4 chunks of 4 f (64 rows of W1bt each) ----
  for (int c = 0; c < 4; ++c) {
    __syncthreads();                       // Ws free (prev chunk consumed)
#pragma unroll
    for (int it = 0; it < 3; ++it) {       // stage 64 rows x 12 groups, coalesced, swizzled dest
      int idx = t + it * 256;
      int row = idx / 12, g = idx % 12;
      *(uint4*)&Ws[SWZ(row, g)] = *(const uint4*)(W1bt + (size_t)(c * 64 + row) * 96 + g * 8);
    }
    __syncthreads();
#pragma unroll
    for (int fl = 0; fl < 4; ++fl) {
      int f = c * 4 + fl;
      int wrow = fl * 16 + l15;
      bf16x8 w0_ = *(const bf16x8*)&Ws[SWZ(wrow, 0 + lhi)];
      bf16x8 w1_ = *(const bf16x8*)&Ws[SWZ(wrow, 4 + lhi)];
      bf16x8 w2_ = *(const bf16x8*)&Ws[SWZ(wrow, 8 + lhi)];
      f32x4 acc = (f32x4){0.f, 0.f, 0.f, 0.f};
      acc = __builtin_amdgcn_mfma_f32_16x16x32_bf16(a0, w0_, acc, 0, 0, 0);
      acc = __builtin_amdgcn_mfma_f32_16x16x32_bf16(a1, w1_, acc, 0, 0, 0);
      acc = __builtin_amdgcn_mfma_f32_16x16x32_bf16(a2, w2_, acc, 0, 0, 0);
      int col = f * 16 + l15;
      float bv = bias1[col];
#pragma unroll
      for (int r = 0; r < 4; ++r) {
        float x = acc[r] + bv;
        x = 0.5f * x * (1.0f + erff(x * 0.70710678118654752f));
        int row = hrow + r;
        Hs[SWZH(row, col >> 3) + (col & 7)] = f2bf(x);
      }
    }
  }

  // ---- phase C: p = h1 @ Wc; 2 f-triples x 2 K-halves (48 rows x 128 k of Wcbt each) ----
  int orow = wave * 16 + lhi * 4;
  for (int tf = 0; tf < 2; ++tf) {
    f32x4 accC[3];
#pragma unroll
    for (int fl = 0; fl < 3; ++fl) accC[fl] = (f32x4){0.f, 0.f, 0.f, 0.f};
    for (int kh = 0; kh < 2; ++kh) {
      __syncthreads();                     // Ws free
#pragma unroll
      for (int it = 0; it < 3; ++it) {     // stage 48 rows x 16 groups, coalesced, swizzled dest
        int idx = t + it * 256;
        int row = idx >> 4, g = idx & 15;
        *(uint4*)&Ws[SWZ(row, g)] =
            *(const uint4*)(Wcbt + (size_t)(tf * 48 + row) * 256 + kh * 128 + g * 8);
      }
      __syncthreads();
#pragma unroll
      for (int fl = 0; fl < 3; ++fl) {
        int wrow = fl * 16 + l15;
        int harow = wave * 16 + l15;
#pragma unroll
        for (int ks = 0; ks < 4; ++ks) {
          bf16x8 av = *(const bf16x8*)&Hs[SWZH(harow, (kh * 4 + ks) * 4 + lhi)];
          bf16x8 wv = *(const bf16x8*)&Ws[SWZ(wrow, ks * 4 + lhi)];
          accC[fl] = __builtin_amdgcn_mfma_f32_16x16x32_bf16(av, wv, accC[fl], 0, 0, 0);
        }
      }
    }
#pragma unroll
    for (int fl = 0; fl < 3; ++fl) {
      int col = (tf * 3 + fl) * 16 + l15;
#pragma unroll
      for (int r = 0; r < 4; ++r) {
        int row = bm + orow + r;
        if (row < M) P[(size_t)row * 96 + col] = f2bf(accC[fl][r]);
      }
    }
  }
}

extern "C" void kernel_launch(void* const* d_in, const int* in_sizes, int n_in,
                              void* d_out, int out_size, void* d_ws, size_t ws_size,
                              hipStream_t stream) {
  const float* xm  = (const float*)d_in[0];
  const float* xg  = (const float*)d_in[1];
  const int*   ei  = (const int*)d_in[2];
  const float* W1  = (const float*)d_in[3];
  const float* b1  = (const float*)d_in[4];
  const float* W2  = (const float*)d_in[5];
  const float* b2  = (const float*)d_in[6];
  const float* Wl1 = (const float*)d_in[7];
  const float* bl1 = (const float*)d_in[8];
  const float* Wl2 = (const float*)d_in[9];
  const float* bl2 = (const float*)d_in[10];
  float* out = (float*)d_out;

  // ---- workspace layout (float units) ----
  float* W0 = (float*)d_ws;
  const size_t MB = (size_t)N_GRID * 256;          // 16,680,960
  int*   deg  = (int*)(W0 + MB);
  int*   off  = deg + N_TOT;                       // N_TOT+1
  int*   cur  = off + N_TOT + 1;
  int*   bsum = cur + N_TOT;                       // 512
  int*   csrc = bsum + 512;                        // NE
  float* dinv = (float*)(csrc + NE);               // N_TOT
  size_t p1off = ((size_t)(dinv + N_TOT - W0) + 3) & ~(size_t)3;   // 16B align
  float* P1 = W0 + p1off;                          // 257*96: [Wl1;bl1]@Wl2 (rows 0..255 = T1)
  float* P2 = P1 + 257 * 96;                       // 257*96: [W2;b2]@T1  (rows 0..255 = Wc)
  float* bc = P2 + 257 * 96;                       // 96
  size_t wboff = ((size_t)(bc + 96 - W0) + 3) & ~(size_t)3;        // 16B align
  unsigned short* W1bt = (unsigned short*)(W0 + wboff);            // 256x96 bf16
  unsigned short* Wcbt = W1bt + 256 * 96;                          // 96x256 bf16
  size_t RH = (wboff + 24576 + 3) & ~(size_t)3;    // past both bf16 arrays (24576 floats)
  unsigned short* hb = (unsigned short*)(W0 + RH); // N_TOT x 96 bf16 (5.09M fl)
  unsigned short* agg1b = (unsigned short*)W0;     // [0, 5.1M fl) bf16 (t3-t4)
  unsigned short* p = (unsigned short*)(hb + (size_t)N_TOT * 96 + 16);   // bf16, after hb
  p = (unsigned short*)(((size_t)p + 15) & ~(size_t)15);
  float* tb = W0 + (size_t)6 * 1024 * 1024;        // [6M, 12.25M) fl — clear of agg1b and meta

  const int* esrc = ei;
  const int* edst = ei + NE;
  dim3 b256(256);
  const int NB_N = (N_TOT + 255) / 256;

  // t1. node features (N_TOT, 96) bf16
  k_concat_transpose<<<dim3((N_TOT + 63) / 64), b256, 0, stream>>>(xg, xm, hb);

  // t2. CSR by dst + dinv; weight combine + casts (independent of node pipeline)
  k_zeroi<<<dim3(NB_N), b256, 0, stream>>>(deg, N_TOT);
  k_hist<<<dim3((NE + 255) / 256), b256, 0, stream>>>(edst, deg);
  k_blocksum<<<dim3(NB_N), b256, 0, stream>>>(deg, bsum, N_TOT);
  k_scanbsum<<<dim3(1), dim3(512), 0, stream>>>(bsum, NB_N);
  k_offsets<<<dim3(NB_N), b256, 0, stream>>>(deg, bsum, off, cur, N_TOT);
  k_seti<<<dim3(1), dim3(1), 0, stream>>>(off + N_TOT, NE);
  k_fillcsr<<<dim3((NE + 255) / 256), b256, 0, stream>>>(esrc, edst, cur, csrc);
  k_dinv<<<dim3(NB_N), b256, 0, stream>>>(deg, dinv, N_TOT);
  k_cast_w1t<<<dim3(96), b256, 0, stream>>>(W1, W1bt);
  k_wgemm96<<<dim3(9), b256, 0, stream>>>(Wl1, bl1, Wl2, P1, 257, HID);
  k_wgemm96<<<dim3(9), b256, 0, stream>>>(W2, b2, P1, P2, 257, HID);
  k_bc_final<<<dim3(1), dim3(96), 0, stream>>>(P1 + 256 * 96, P2 + 256 * 96, bl2, bc);
  k_cast_wct<<<dim3(96), b256, 0, stream>>>(P2, Wcbt);

  // t3. agg1 = S @ h   (96 ch, gather, bf16) — standalone, high occupancy
  k_gather96<<<dim3((N_TOT * 24 + 255) / 256), b256, 0, stream>>>(off, csrc, dinv, hb, agg1b);

  // t4. p = gelu(agg1@W1+b1)@Wc  — fused MLP v4 (swizzled LDS, 3 blocks/CU), p bf16
  k_mlp<<<dim3((N_TOT + 63) / 64), b256, 0, stream>>>(agg1b, W1bt, b1, Wcbt, p, N_TOT);

  // t5. tb = S_grid @ p + bc   (96 ch, bf16 reads, fp32 accumulate)
  k_gather96p<<<dim3((N_GRID * 24 + 255) / 256), b256, 0, stream>>>(off, csrc, dinv, p, bc, tb);

  // t6. out = tb^T   (96, N_GRID)
  k_transpose_out<<<dim3((N_GRID + 63) / 64), b256, 0, stream>>>(tb, out);
}

// Round 18
// 229.283 us; speedup vs baseline: 1.4653x; 1.0438x over previous
//
#include <hip/hip_runtime.h>
#include <math.h>

#define N_GRID 65160
#define N_MESH 40962
#define N_TOT  106122
#define NE     521280
#define IN_CH  96
#define HID    256
#define OUT_CH 96

typedef __attribute__((ext_vector_type(8))) short bf16x8;   // 8 bf16 in 4 VGPRs (guide §3)
typedef __attribute__((ext_vector_type(4))) float f32x4;

__device__ __forceinline__ unsigned short f2bf(float f) {   // fp32 -> bf16 RNE
  unsigned u = __float_as_uint(f);
  return (unsigned short)((u + 0x7FFFu + ((u >> 16) & 1u)) >> 16);
}
__device__ __forceinline__ float bf2f(unsigned short s) {
  return __uint_as_float(((unsigned)s) << 16);
}
// unpack 8 bf16 (uint4) -> 8 fp32
__device__ __forceinline__ void unp8(uint4 v, float* f) {
  f[0] = __uint_as_float(v.x << 16); f[1] = __uint_as_float(v.x & 0xFFFF0000u);
  f[2] = __uint_as_float(v.y << 16); f[3] = __uint_as_float(v.y & 0xFFFF0000u);
  f[4] = __uint_as_float(v.z << 16); f[5] = __uint_as_float(v.z & 0xFFFF0000u);
  f[6] = __uint_as_float(v.w << 16); f[7] = __uint_as_float(v.w & 0xFFFF0000u);
}

// ---------------- concat + transpose: (96,N) fp32 channel-major -> (N,96) bf16 node-major ----------------
__global__ void k_concat_transpose(const float* __restrict__ xg, const float* __restrict__ xm,
                                   unsigned short* __restrict__ h) {
  __shared__ float tile[IN_CH][65];
  int base = blockIdx.x * 64;
  int t = threadIdx.x;
#pragma unroll
  for (int it = 0; it < 24; ++it) {
    int lin = t + it * 256;            // 0..6143 over 96x64
    int c  = lin >> 6;
    int n0 = lin & 63;
    int n = base + n0;
    float v = 0.f;
    if (n < N_TOT) {
      v = (n < N_GRID) ? xg[(size_t)c * N_GRID + n]
                       : xm[(size_t)c * N_MESH + (n - N_GRID)];
    }
    tile[c][n0] = v;
  }
  __syncthreads();
#pragma unroll
  for (int it = 0; it < 24; ++it) {
    int lin = t + it * 256;
    int c  = lin % 96;
    int n0 = lin / 96;
    int n = base + n0;
    if (n < N_TOT) h[(size_t)n * IN_CH + c] = f2bf(tile[c][n0]);
  }
}

// ---------------- final transpose: tb (N_GRID,96) fp32 node-major -> out (96,N_GRID) ----------------
__global__ void k_transpose_out(const float* __restrict__ tb, float* __restrict__ out) {
  __shared__ float tile[IN_CH][65];
  int base = blockIdx.x * 64;
  int t = threadIdx.x;
#pragma unroll
  for (int it = 0; it < 24; ++it) {
    int lin = t + it * 256;
    int c  = lin % 96;
    int n0 = lin / 96;
    int n = base + n0;
    if (n < N_GRID) tile[c][n0] = tb[(size_t)n * 96 + c];
  }
  __syncthreads();
#pragma unroll
  for (int it = 0; it < 24; ++it) {
    int lin = t + it * 256;
    int c  = lin >> 6;
    int n0 = lin & 63;
    int n = base + n0;
    if (n < N_GRID) out[(size_t)c * N_GRID + n] = tile[c][n0];
  }
}

// ---------------- CSR build ----------------
__global__ void k_zeroi(int* __restrict__ p, int n) {
  int i = blockIdx.x * 256 + threadIdx.x;
  if (i < n) p[i] = 0;
}

__global__ void k_hist(const int* __restrict__ dst, int* __restrict__ deg) {
  int e = blockIdx.x * 256 + threadIdx.x;
  if (e < NE) atomicAdd(&deg[dst[e]], 1);
}

__global__ void k_blocksum(const int* __restrict__ deg, int* __restrict__ bsum, int n) {
  __shared__ int s[256];
  int i = blockIdx.x * 256 + threadIdx.x;
  s[threadIdx.x] = (i < n) ? deg[i] : 0;
  __syncthreads();
  for (int st = 128; st > 0; st >>= 1) {
    if (threadIdx.x < st) s[threadIdx.x] += s[threadIdx.x + st];
    __syncthreads();
  }
  if (threadIdx.x == 0) bsum[blockIdx.x] = s[0];
}

__global__ void k_scanbsum(int* __restrict__ bsum, int nb) {   // single block, 512 thr
  __shared__ int s[512];
  int t = threadIdx.x;
  int v = (t < nb) ? bsum[t] : 0;
  s[t] = v;
  __syncthreads();
  for (int off = 1; off < 512; off <<= 1) {
    int x = (t >= off) ? s[t - off] : 0;
    __syncthreads();
    s[t] += x;
    __syncthreads();
  }
  if (t < nb) bsum[t] = s[t] - v;   // exclusive
}

// offsets + cur init + dinv + off[N_TOT]=NE (k_seti/k_dinv folded in)
__global__ void k_offsets(const int* __restrict__ deg, const int* __restrict__ bsum,
                          int* __restrict__ off, int* __restrict__ cur,
                          float* __restrict__ dinv, int n) {
  __shared__ int s[256];
  int i = blockIdx.x * 256 + threadIdx.x;
  int v = (i < n) ? deg[i] : 0;
  s[threadIdx.x] = v;
  __syncthreads();
  for (int o = 1; o < 256; o <<= 1) {
    int x = (threadIdx.x >= o) ? s[threadIdx.x - o] : 0;
    __syncthreads();
    s[threadIdx.x] += x;
    __syncthreads();
  }
  if (i < n) {
    int e = bsum[blockIdx.x] + s[threadIdx.x] - v;
    off[i] = e;
    cur[i] = e;
    dinv[i] = rsqrtf(1.0f + (float)v);
  }
  if (i == 0) off[n] = NE;
}

__global__ void k_fillcsr(const int* __restrict__ src, const int* __restrict__ dst,
                          int* __restrict__ cur, int* __restrict__ csrc) {
  int e = blockIdx.x * 256 + threadIdx.x;
  if (e < NE) {
    int p = atomicAdd(&cur[dst[e]], 1);
    csrc[p] = src[e];
  }
}

// ---------------- gather over bf16 h, 8 ch/thread (16B loads — G13 sweet spot), 4-edge unroll ----------------
// Standalone: trivial resource footprint -> near-max waves/CU (round-13 lesson: never fuse me).
__global__ void k_gather96(const int* __restrict__ off, const int* __restrict__ csrc,
                           const float* __restrict__ dinv, const unsigned short* __restrict__ h,
                           unsigned short* __restrict__ agg) {
  int i = blockIdx.x * 256 + threadIdx.x;
  if (i >= N_TOT * 12) return;
  int n = i / 12;
  int c8 = (i % 12) << 3;
  float di = dinv[n];
  float acc[8], f[8];
  uint4 v = *(const uint4*)(h + (size_t)n * 96 + c8);
  unp8(v, f);
  float w0 = di * di;
#pragma unroll
  for (int j = 0; j < 8; ++j) acc[j] = f[j] * w0;
  int e0 = off[n], e1 = off[n + 1];
  int e = e0;
  for (; e + 3 < e1; e += 4) {
    int s0 = csrc[e], s1 = csrc[e + 1], s2 = csrc[e + 2], s3 = csrc[e + 3];
    float wa = dinv[s0] * di, wb = dinv[s1] * di, wc = dinv[s2] * di, wd = dinv[s3] * di;
    uint4 u0 = *(const uint4*)(h + (size_t)s0 * 96 + c8);
    uint4 u1 = *(const uint4*)(h + (size_t)s1 * 96 + c8);
    uint4 u2 = *(const uint4*)(h + (size_t)s2 * 96 + c8);
    uint4 u3 = *(const uint4*)(h + (size_t)s3 * 96 + c8);
    float g0[8], g1[8], g2[8], g3[8];
    unp8(u0, g0); unp8(u1, g1); unp8(u2, g2); unp8(u3, g3);
#pragma unroll
    for (int j = 0; j < 8; ++j) acc[j] += g0[j] * wa + g1[j] * wb + g2[j] * wc + g3[j] * wd;
  }
  for (; e < e1; ++e) {
    int s = csrc[e];
    float w = dinv[s] * di;
    uint4 u = *(const uint4*)(h + (size_t)s * 96 + c8);
    unp8(u, f);
#pragma unroll
    for (int j = 0; j < 8; ++j) acc[j] += f[j] * w;
  }
  uint4 o;
  o.x = (unsigned)f2bf(acc[0]) | ((unsigned)f2bf(acc[1]) << 16);
  o.y = (unsigned)f2bf(acc[2]) | ((unsigned)f2bf(acc[3]) << 16);
  o.z = (unsigned)f2bf(acc[4]) | ((unsigned)f2bf(acc[5]) << 16);
  o.w = (unsigned)f2bf(acc[6]) | ((unsigned)f2bf(acc[7]) << 16);
  *(uint4*)(agg + (size_t)n * 96 + c8) = o;
}

// gather over p (bf16), grid nodes only, + bias bc, write tb node-major fp32; 8 ch/thread
__global__ void k_gather96p(const int* __restrict__ off, const int* __restrict__ csrc,
                            const float* __restrict__ dinv, const unsigned short* __restrict__ p,
                            const float* __restrict__ bc, float* __restrict__ tb) {
  int i = blockIdx.x * 256 + threadIdx.x;
  if (i >= N_GRID * 12) return;
  int n = i / 12;
  int c8 = (i % 12) << 3;
  float di = dinv[n];
  float acc[8], f[8];
  uint4 v = *(const uint4*)(p + (size_t)n * 96 + c8);
  unp8(v, f);
  float w0 = di * di;
#pragma unroll
  for (int j = 0; j < 8; ++j) acc[j] = f[j] * w0;
  int e0 = off[n], e1 = off[n + 1];
  int e = e0;
  for (; e + 3 < e1; e += 4) {
    int s0 = csrc[e], s1 = csrc[e + 1], s2 = csrc[e + 2], s3 = csrc[e + 3];
    float wa = dinv[s0] * di, wb = dinv[s1] * di, wc = dinv[s2] * di, wd = dinv[s3] * di;
    uint4 u0 = *(const uint4*)(p + (size_t)s0 * 96 + c8);
    uint4 u1 = *(const uint4*)(p + (size_t)s1 * 96 + c8);
    uint4 u2 = *(const uint4*)(p + (size_t)s2 * 96 + c8);
    uint4 u3 = *(const uint4*)(p + (size_t)s3 * 96 + c8);
    float g0[8], g1[8], g2[8], g3[8];
    unp8(u0, g0); unp8(u1, g1); unp8(u2, g2); unp8(u3, g3);
#pragma unroll
    for (int j = 0; j < 8; ++j) acc[j] += g0[j] * wa + g1[j] * wb + g2[j] * wc + g3[j] * wd;
  }
  for (; e < e1; ++e) {
    int s = csrc[e];
    float w = dinv[s] * di;
    uint4 u = *(const uint4*)(p + (size_t)s * 96 + c8);
    unp8(u, f);
#pragma unroll
    for (int j = 0; j < 8; ++j) acc[j] += f[j] * w;
  }
  float* row = tb + (size_t)n * 96 + c8;
  *(float4*)(row)     = make_float4(acc[0] + bc[c8 + 0], acc[1] + bc[c8 + 1],
                                    acc[2] + bc[c8 + 2], acc[3] + bc[c8 + 3]);
  *(float4*)(row + 4) = make_float4(acc[4] + bc[c8 + 4], acc[5] + bc[c8 + 5],
                                    acc[6] + bc[c8 + 6], acc[7] + bc[c8 + 7]);
}

// ---------------- small-matrix weight GEMM: C(Mx96) = [A; bvec](MxK) @ B(Kx96) ----------------
__global__ __launch_bounds__(256, 2) void k_wgemm96(const float* __restrict__ A, const float* __restrict__ bvec,
                                                    const float* __restrict__ B, float* __restrict__ C,
                                                    int M, int K) {
  __shared__ float As[64][33];
  __shared__ float Bs[64][100];
  int t = threadIdx.x;
  int tx = t & 15, ty = t >> 4;
  int bm = blockIdx.x * 32;
  float acc[2][6] = {};
  for (int kc = 0; kc < K; kc += 64) {
#pragma unroll
    for (int it = 0; it < 2; ++it) {
      int idx = t + it * 256;
      int r = idx >> 4, k4 = (idx & 15) << 2;
      int gr = bm + r;
      float4 v = make_float4(0.f, 0.f, 0.f, 0.f);
      if (gr < M) {
        const float* src = (gr < M - 1) ? (A + (size_t)gr * K + kc + k4) : (bvec + kc + k4);
        v = *(const float4*)src;
      }
      As[k4 + 0][r] = v.x;
      As[k4 + 1][r] = v.y;
      As[k4 + 2][r] = v.z;
      As[k4 + 3][r] = v.w;
    }
#pragma unroll
    for (int it = 0; it < 6; ++it) {
      int idx = t + it * 256;
      int k = idx / 24, j4 = (idx % 24) << 2;
      float4 v = *(const float4*)(B + (size_t)(kc + k) * 96 + j4);
      *(float4*)&Bs[k][j4] = v;
    }
    __syncthreads();
#pragma unroll
    for (int k = 0; k < 64; ++k) {
      float a0 = As[k][ty * 2], a1 = As[k][ty * 2 + 1];
      float w[6];
      *(float2*)&w[0] = *(const float2*)&Bs[k][tx * 6];
      *(float2*)&w[2] = *(const float2*)&Bs[k][tx * 6 + 2];
      *(float2*)&w[4] = *(const float2*)&Bs[k][tx * 6 + 4];
#pragma unroll
      for (int j = 0; j < 6; ++j) { acc[0][j] += a0 * w[j]; acc[1][j] += a1 * w[j]; }
    }
    __syncthreads();
  }
#pragma unroll
  for (int i = 0; i < 2; ++i) {
    int gr = bm + ty * 2 + i;
    if (gr >= M) continue;
    float* row = C + (size_t)gr * 96 + tx * 6;
    row[0] = acc[i][0]; row[1] = acc[i][1]; row[2] = acc[i][2];
    row[3] = acc[i][3]; row[4] = acc[i][4]; row[5] = acc[i][5];
  }
}

// bc[j] = P1[256][j] + P2[256][j] + bl2[j]
__global__ void k_bc_final(const float* __restrict__ r1, const float* __restrict__ r2,
                           const float* __restrict__ bl2, float* __restrict__ bc) {
  int j = threadIdx.x;
  if (j < OUT_CH) bc[j] = r1[j] + r2[j] + bl2[j];
}

// ---------------- weight casts (fp32 -> bf16, transposed to col-major) ----------------
__global__ void k_cast_w1t(const float* __restrict__ W1, unsigned short* __restrict__ W1bt) {
  int idx = blockIdx.x * 256 + threadIdx.x;          // over [256 n][96 k]
  if (idx >= 256 * 96) return;
  int n = idx / 96, k = idx % 96;
  W1bt[idx] = f2bf(W1[(size_t)k * 256 + n]);
}
__global__ void k_cast_wct(const float* __restrict__ Wc, unsigned short* __restrict__ Wcbt) {
  int idx = blockIdx.x * 256 + threadIdx.x;          // over [96 n][256 k]
  if (idx >= 96 * 256) return;
  int n = idx / 256, k = idx % 256;
  Wcbt[idx] = f2bf(Wc[(size_t)k * 96 + n]);
}

// ---------------- FUSED MLP v4.1: swizzled LDS, 48 KB, now 3 blocks/CU requested ----------------
// (256,3): VGPR cap 170 >= measured 68, LDS 3x48=144 <= 160 KB. Round-17 at (256,2) settled at
// 2.4 blocks/CU (22.6% occ); the latency-heavy inner loop wants the 3rd block.
#define SWZ(row, g) (((row) << 7) + (((g) ^ ((row) & 7)) << 3))          // Ws: [64][128] bf16
#define SWZH(row, g) (((row) << 8) + (((g) ^ ((row) & 7)) << 3))         // Hs: [64][256] bf16
__global__ __launch_bounds__(256, 3) void k_mlp(const unsigned short* __restrict__ A,
                                                const unsigned short* __restrict__ W1bt,  // [256 n][96 k]
                                                const float* __restrict__ bias1,
                                                const unsigned short* __restrict__ Wcbt,  // [96 n][256 k]
                                                unsigned short* __restrict__ P, int M) {
  __shared__ unsigned short Hs[64 * 256];  // h1 rows (bf16), swizzled, 32 KB
  __shared__ unsigned short Ws[64 * 128];  // weight chunk (bf16), swizzled, 16 KB
  int t = threadIdx.x;
  int wave = t >> 6, lane = t & 63;
  int l15 = lane & 15, lhi = lane >> 4;
  int bm = blockIdx.x * 64;

  // A-frags direct from global (row bm+wave*16+l15, k-groups 0/32/64 + lhi*8)
  int arowl = wave * 16 + l15;
  bool aok = (bm + arowl) < M;
  const unsigned short* ap = A + (size_t)(bm + arowl) * 96 + lhi * 8;
  bf16x8 a0 = aok ? *(const bf16x8*)(ap)      : (bf16x8){0,0,0,0,0,0,0,0};
  bf16x8 a1 = aok ? *(const bf16x8*)(ap + 32) : (bf16x8){0,0,0,0,0,0,0,0};
  bf16x8 a2 = aok ? *(const bf16x8*)(ap + 64) : (bf16x8){0,0,0,0,0,0,0,0};
  int hrow = wave * 16 + lhi * 4;

  // ---- phase B: h1 = gelu(agg @ W1 + b1); 4 chunks of 4 f (64 rows of W1bt each) ----
  for (int c = 0; c < 4; ++c) {
    __syncthreads();                       // Ws free (prev chunk consumed)
#pragma unroll
    for (int it = 0; it < 3; ++it) {       // stage 64 rows x 12 groups, coalesced, swizzled dest
      int idx = t + it * 256;
      int row = idx / 12, g = idx % 12;
      *(uint4*)&Ws[SWZ(row, g)] = *(const uint4*)(W1bt + (size_t)(c * 64 + row) * 96 + g * 8);
    }
    __syncthreads();
#pragma unroll
    for (int fl = 0; fl < 4; ++fl) {
      int f = c * 4 + fl;
      int wrow = fl * 16 + l15;
      bf16x8 w0_ = *(const bf16x8*)&Ws[SWZ(wrow, 0 + lhi)];
      bf16x8 w1_ = *(const bf16x8*)&Ws[SWZ(wrow, 4 + lhi)];
      bf16x8 w2_ = *(const bf16x8*)&Ws[SWZ(wrow, 8 + lhi)];
      f32x4 acc = (f32x4){0.f, 0.f, 0.f, 0.f};
      acc = __builtin_amdgcn_mfma_f32_16x16x32_bf16(a0, w0_, acc, 0, 0, 0);
      acc = __builtin_amdgcn_mfma_f32_16x16x32_bf16(a1, w1_, acc, 0, 0, 0);
      acc = __builtin_amdgcn_mfma_f32_16x16x32_bf16(a2, w2_, acc, 0, 0, 0);
      int col = f * 16 + l15;
      float bv = bias1[col];
#pragma unroll
      for (int r = 0; r < 4; ++r) {
        float x = acc[r] + bv;
        x = 0.5f * x * (1.0f + erff(x * 0.70710678118654752f));
        int row = hrow + r;
        Hs[SWZH(row, col >> 3) + (col & 7)] = f2bf(x);
      }
    }
  }

  // ---- phase C: p = h1 @ Wc; 2 f-triples x 2 K-halves (48 rows x 128 k of Wcbt each) ----
  int orow = wave * 16 + lhi * 4;
  for (int tf = 0; tf < 2; ++tf) {
    f32x4 accC[3];
#pragma unroll
    for (int fl = 0; fl < 3; ++fl) accC[fl] = (f32x4){0.f, 0.f, 0.f, 0.f};
    for (int kh = 0; kh < 2; ++kh) {
      __syncthreads();                     // Ws free
#pragma unroll
      for (int it = 0; it < 3; ++it) {     // stage 48 rows x 16 groups, coalesced, swizzled dest
        int idx = t + it * 256;
        int row = idx >> 4, g = idx & 15;
        *(uint4*)&Ws[SWZ(row, g)] =
            *(const uint4*)(Wcbt + (size_t)(tf * 48 + row) * 256 + kh * 128 + g * 8);
      }
      __syncthreads();
#pragma unroll
      for (int fl = 0; fl < 3; ++fl) {
        int wrow = fl * 16 + l15;
        int harow = wave * 16 + l15;
#pragma unroll
        for (int ks = 0; ks < 4; ++ks) {
          bf16x8 av = *(const bf16x8*)&Hs[SWZH(harow, (kh * 4 + ks) * 4 + lhi)];
          bf16x8 wv = *(const bf16x8*)&Ws[SWZ(wrow, ks * 4 + lhi)];
          accC[fl] = __builtin_amdgcn_mfma_f32_16x16x32_bf16(av, wv, accC[fl], 0, 0, 0);
        }
      }
    }
#pragma unroll
    for (int fl = 0; fl < 3; ++fl) {
      int col = (tf * 3 + fl) * 16 + l15;
#pragma unroll
      for (int r = 0; r < 4; ++r) {
        int row = bm + orow + r;
        if (row < M) P[(size_t)row * 96 + col] = f2bf(accC[fl][r]);
      }
    }
  }
}

extern "C" void kernel_launch(void* const* d_in, const int* in_sizes, int n_in,
                              void* d_out, int out_size, void* d_ws, size_t ws_size,
                              hipStream_t stream) {
  const float* xm  = (const float*)d_in[0];
  const float* xg  = (const float*)d_in[1];
  const int*   ei  = (const int*)d_in[2];
  const float* W1  = (const float*)d_in[3];
  const float* b1  = (const float*)d_in[4];
  const float* W2  = (const float*)d_in[5];
  const float* b2  = (const float*)d_in[6];
  const float* Wl1 = (const float*)d_in[7];
  const float* bl1 = (const float*)d_in[8];
  const float* Wl2 = (const float*)d_in[9];
  const float* bl2 = (const float*)d_in[10];
  float* out = (float*)d_out;

  // ---- workspace layout (float units) ----
  float* W0 = (float*)d_ws;
  const size_t MB = (size_t)N_GRID * 256;          // 16,680,960
  int*   deg  = (int*)(W0 + MB);
  int*   off  = deg + N_TOT;                       // N_TOT+1
  int*   cur  = off + N_TOT + 1;
  int*   bsum = cur + N_TOT;                       // 512
  int*   csrc = bsum + 512;                        // NE
  float* dinv = (float*)(csrc + NE);               // N_TOT
  size_t p1off = ((size_t)(dinv + N_TOT - W0) + 3) & ~(size_t)3;   // 16B align
  float* P1 = W0 + p1off;                          // 257*96: [Wl1;bl1]@Wl2 (rows 0..255 = T1)
  float* P2 = P1 + 257 * 96;                       // 257*96: [W2;b2]@T1  (rows 0..255 = Wc)
  float* bc = P2 + 257 * 96;                       // 96
  size_t wboff = ((size_t)(bc + 96 - W0) + 3) & ~(size_t)3;        // 16B align
  unsigned short* W1bt = (unsigned short*)(W0 + wboff);            // 256x96 bf16
  unsigned short* Wcbt = W1bt + 256 * 96;                          // 96x256 bf16
  size_t RH = (wboff + 24576 + 3) & ~(size_t)3;    // past both bf16 arrays (24576 floats)
  unsigned short* hb = (unsigned short*)(W0 + RH); // N_TOT x 96 bf16 (5.09M fl)
  unsigned short* agg1b = (unsigned short*)W0;     // [0, 5.1M fl) bf16 (t3-t4)
  unsigned short* p = (unsigned short*)(hb + (size_t)N_TOT * 96 + 16);   // bf16, after hb
  p = (unsigned short*)(((size_t)p + 15) & ~(size_t)15);
  float* tb = W0 + (size_t)6 * 1024 * 1024;        // [6M, 12.25M) fl — clear of agg1b and meta

  const int* esrc = ei;
  const int* edst = ei + NE;
  dim3 b256(256);
  const int NB_N = (N_TOT + 255) / 256;

  // t1. node features (N_TOT, 96) bf16
  k_concat_transpose<<<dim3((N_TOT + 63) / 64), b256, 0, stream>>>(xg, xm, hb);

  // t2. CSR by dst + dinv; weight combine + casts (independent of node pipeline)
  k_zeroi<<<dim3(NB_N), b256, 0, stream>>>(deg, N_TOT);
  k_hist<<<dim3((NE + 255) / 256), b256, 0, stream>>>(edst, deg);
  k_blocksum<<<dim3(NB_N), b256, 0, stream>>>(deg, bsum, N_TOT);
  k_scanbsum<<<dim3(1), dim3(512), 0, stream>>>(bsum, NB_N);
  k_offsets<<<dim3(NB_N), b256, 0, stream>>>(deg, bsum, off, cur, dinv, N_TOT);
  k_fillcsr<<<dim3((NE + 255) / 256), b256, 0, stream>>>(esrc, edst, cur, csrc);
  k_cast_w1t<<<dim3(96), b256, 0, stream>>>(W1, W1bt);
  k_wgemm96<<<dim3(9), b256, 0, stream>>>(Wl1, bl1, Wl2, P1, 257, HID);
  k_wgemm96<<<dim3(9), b256, 0, stream>>>(W2, b2, P1, P2, 257, HID);
  k_bc_final<<<dim3(1), dim3(96), 0, stream>>>(P1 + 256 * 96, P2 + 256 * 96, bl2, bc);
  k_cast_wct<<<dim3(96), b256, 0, stream>>>(P2, Wcbt);

  // t3. agg1 = S @ h   (96 ch, gather, bf16, 16B loads) — standalone, high occupancy
  k_gather96<<<dim3((N_TOT * 12 + 255) / 256), b256, 0, stream>>>(off, csrc, dinv, hb, agg1b);

  // t4. p = gelu(agg1@W1+b1)@Wc  — fused MLP v4.1 (swizzled LDS, 3 blocks/CU), p bf16
  k_mlp<<<dim3((N_TOT + 63) / 64), b256, 0, stream>>>(agg1b, W1bt, b1, Wcbt, p, N_TOT);

  // t5. tb = S_grid @ p + bc   (96 ch, bf16 16B reads, fp32 accumulate)
  k_gather96p<<<dim3((N_GRID * 12 + 255) / 256), b256, 0, stream>>>(off, csrc, dinv, p, bc, tb);

  // t6. out = tb^T   (96, N_GRID)
  k_transpose_out<<<dim3((N_GRID + 63) / 64), b256, 0, stream>>>(tb, out);
}

// Round 19
// 222.791 us; speedup vs baseline: 1.5080x; 1.0291x over previous
//
#include <hip/hip_runtime.h>
#include <math.h>

#define N_GRID 65160
#define N_MESH 40962
#define N_TOT  106122
#define NE     521280
#define IN_CH  96
#define HID    256
#define OUT_CH 96

typedef __attribute__((ext_vector_type(8))) short bf16x8;   // 8 bf16 in 4 VGPRs (guide §3)
typedef __attribute__((ext_vector_type(4))) float f32x4;

__device__ __forceinline__ unsigned short f2bf(float f) {   // fp32 -> bf16 RNE
  unsigned u = __float_as_uint(f);
  return (unsigned short)((u + 0x7FFFu + ((u >> 16) & 1u)) >> 16);
}
__device__ __forceinline__ float bf2f(unsigned short s) {
  return __uint_as_float(((unsigned)s) << 16);
}
// unpack 8 bf16 (uint4) -> 8 fp32
__device__ __forceinline__ void unp8(uint4 v, float* f) {
  f[0] = __uint_as_float(v.x << 16); f[1] = __uint_as_float(v.x & 0xFFFF0000u);
  f[2] = __uint_as_float(v.y << 16); f[3] = __uint_as_float(v.y & 0xFFFF0000u);
  f[4] = __uint_as_float(v.z << 16); f[5] = __uint_as_float(v.z & 0xFFFF0000u);
  f[6] = __uint_as_float(v.w << 16); f[7] = __uint_as_float(v.w & 0xFFFF0000u);
}

// ---------------- concat + transpose: (96,N) fp32 channel-major -> (N,96) bf16 node-major ----------------
__global__ void k_concat_transpose(const float* __restrict__ xg, const float* __restrict__ xm,
                                   unsigned short* __restrict__ h) {
  __shared__ float tile[IN_CH][65];
  int base = blockIdx.x * 64;
  int t = threadIdx.x;
#pragma unroll
  for (int it = 0; it < 24; ++it) {
    int lin = t + it * 256;            // 0..6143 over 96x64
    int c  = lin >> 6;
    int n0 = lin & 63;
    int n = base + n0;
    float v = 0.f;
    if (n < N_TOT) {
      v = (n < N_GRID) ? xg[(size_t)c * N_GRID + n]
                       : xm[(size_t)c * N_MESH + (n - N_GRID)];
    }
    tile[c][n0] = v;
  }
  __syncthreads();
#pragma unroll
  for (int it = 0; it < 24; ++it) {
    int lin = t + it * 256;
    int c  = lin % 96;
    int n0 = lin / 96;
    int n = base + n0;
    if (n < N_TOT) h[(size_t)n * IN_CH + c] = f2bf(tile[c][n0]);
  }
}

// ---------------- final transpose: tb (N_GRID,96) fp32 node-major -> out (96,N_GRID) ----------------
__global__ void k_transpose_out(const float* __restrict__ tb, float* __restrict__ out) {
  __shared__ float tile[IN_CH][65];
  int base = blockIdx.x * 64;
  int t = threadIdx.x;
#pragma unroll
  for (int it = 0; it < 24; ++it) {
    int lin = t + it * 256;
    int c  = lin % 96;
    int n0 = lin / 96;
    int n = base + n0;
    if (n < N_GRID) tile[c][n0] = tb[(size_t)n * 96 + c];
  }
  __syncthreads();
#pragma unroll
  for (int it = 0; it < 24; ++it) {
    int lin = t + it * 256;
    int c  = lin >> 6;
    int n0 = lin & 63;
    int n = base + n0;
    if (n < N_GRID) out[(size_t)c * N_GRID + n] = tile[c][n0];
  }
}

// ---------------- CSR build ----------------
__global__ void k_zeroi(int* __restrict__ p, int n) {
  int i = blockIdx.x * 256 + threadIdx.x;
  if (i < n) p[i] = 0;
}

__global__ void k_hist(const int* __restrict__ dst, int* __restrict__ deg) {
  int e = blockIdx.x * 256 + threadIdx.x;
  if (e < NE) atomicAdd(&deg[dst[e]], 1);
}

__global__ void k_blocksum(const int* __restrict__ deg, int* __restrict__ bsum, int n) {
  __shared__ int s[256];
  int i = blockIdx.x * 256 + threadIdx.x;
  s[threadIdx.x] = (i < n) ? deg[i] : 0;
  __syncthreads();
  for (int st = 128; st > 0; st >>= 1) {
    if (threadIdx.x < st) s[threadIdx.x] += s[threadIdx.x + st];
    __syncthreads();
  }
  if (threadIdx.x == 0) bsum[blockIdx.x] = s[0];
}

__global__ void k_scanbsum(int* __restrict__ bsum, int nb) {   // single block, 512 thr
  __shared__ int s[512];
  int t = threadIdx.x;
  int v = (t < nb) ? bsum[t] : 0;
  s[t] = v;
  __syncthreads();
  for (int off = 1; off < 512; off <<= 1) {
    int x = (t >= off) ? s[t - off] : 0;
    __syncthreads();
    s[t] += x;
    __syncthreads();
  }
  if (t < nb) bsum[t] = s[t] - v;   // exclusive
}

// offsets + cur init + dinv + off[N_TOT]=NE
__global__ void k_offsets(const int* __restrict__ deg, const int* __restrict__ bsum,
                          int* __restrict__ off, int* __restrict__ cur,
                          float* __restrict__ dinv, int n) {
  __shared__ int s[256];
  int i = blockIdx.x * 256 + threadIdx.x;
  int v = (i < n) ? deg[i] : 0;
  s[threadIdx.x] = v;
  __syncthreads();
  for (int o = 1; o < 256; o <<= 1) {
    int x = (threadIdx.x >= o) ? s[threadIdx.x - o] : 0;
    __syncthreads();
    s[threadIdx.x] += x;
    __syncthreads();
  }
  if (i < n) {
    int e = bsum[blockIdx.x] + s[threadIdx.x] - v;
    off[i] = e;
    cur[i] = e;
    dinv[i] = rsqrtf(1.0f + (float)v);
  }
  if (i == 0) off[n] = NE;
}

__global__ void k_fillcsr(const int* __restrict__ src, const int* __restrict__ dst,
                          int* __restrict__ cur, int* __restrict__ csrc) {
  int e = blockIdx.x * 256 + threadIdx.x;
  if (e < NE) {
    int p = atomicAdd(&cur[dst[e]], 1);
    csrc[p] = src[e];
  }
}

// ---------------- gather over bf16 h, 8 ch/thread (16B loads), 4-edge unroll ----------------
__global__ void k_gather96(const int* __restrict__ off, const int* __restrict__ csrc,
                           const float* __restrict__ dinv, const unsigned short* __restrict__ h,
                           unsigned short* __restrict__ agg) {
  int i = blockIdx.x * 256 + threadIdx.x;
  if (i >= N_TOT * 12) return;
  int n = i / 12;
  int c8 = (i % 12) << 3;
  float di = dinv[n];
  float acc[8], f[8];
  uint4 v = *(const uint4*)(h + (size_t)n * 96 + c8);
  unp8(v, f);
  float w0 = di * di;
#pragma unroll
  for (int j = 0; j < 8; ++j) acc[j] = f[j] * w0;
  int e0 = off[n], e1 = off[n + 1];
  int e = e0;
  for (; e + 3 < e1; e += 4) {
    int s0 = csrc[e], s1 = csrc[e + 1], s2 = csrc[e + 2], s3 = csrc[e + 3];
    float wa = dinv[s0] * di, wb = dinv[s1] * di, wc = dinv[s2] * di, wd = dinv[s3] * di;
    uint4 u0 = *(const uint4*)(h + (size_t)s0 * 96 + c8);
    uint4 u1 = *(const uint4*)(h + (size_t)s1 * 96 + c8);
    uint4 u2 = *(const uint4*)(h + (size_t)s2 * 96 + c8);
    uint4 u3 = *(const uint4*)(h + (size_t)s3 * 96 + c8);
    float g0[8], g1[8], g2[8], g3[8];
    unp8(u0, g0); unp8(u1, g1); unp8(u2, g2); unp8(u3, g3);
#pragma unroll
    for (int j = 0; j < 8; ++j) acc[j] += g0[j] * wa + g1[j] * wb + g2[j] * wc + g3[j] * wd;
  }
  for (; e < e1; ++e) {
    int s = csrc[e];
    float w = dinv[s] * di;
    uint4 u = *(const uint4*)(h + (size_t)s * 96 + c8);
    unp8(u, f);
#pragma unroll
    for (int j = 0; j < 8; ++j) acc[j] += f[j] * w;
  }
  uint4 o;
  o.x = (unsigned)f2bf(acc[0]) | ((unsigned)f2bf(acc[1]) << 16);
  o.y = (unsigned)f2bf(acc[2]) | ((unsigned)f2bf(acc[3]) << 16);
  o.z = (unsigned)f2bf(acc[4]) | ((unsigned)f2bf(acc[5]) << 16);
  o.w = (unsigned)f2bf(acc[6]) | ((unsigned)f2bf(acc[7]) << 16);
  *(uint4*)(agg + (size_t)n * 96 + c8) = o;
}

// gather over p (bf16), grid nodes only, + bias bc, write tb node-major fp32; 8 ch/thread
__global__ void k_gather96p(const int* __restrict__ off, const int* __restrict__ csrc,
                            const float* __restrict__ dinv, const unsigned short* __restrict__ p,
                            const float* __restrict__ bc, float* __restrict__ tb) {
  int i = blockIdx.x * 256 + threadIdx.x;
  if (i >= N_GRID * 12) return;
  int n = i / 12;
  int c8 = (i % 12) << 3;
  float di = dinv[n];
  float acc[8], f[8];
  uint4 v = *(const uint4*)(p + (size_t)n * 96 + c8);
  unp8(v, f);
  float w0 = di * di;
#pragma unroll
  for (int j = 0; j < 8; ++j) acc[j] = f[j] * w0;
  int e0 = off[n], e1 = off[n + 1];
  int e = e0;
  for (; e + 3 < e1; e += 4) {
    int s0 = csrc[e], s1 = csrc[e + 1], s2 = csrc[e + 2], s3 = csrc[e + 3];
    float wa = dinv[s0] * di, wb = dinv[s1] * di, wc = dinv[s2] * di, wd = dinv[s3] * di;
    uint4 u0 = *(const uint4*)(p + (size_t)s0 * 96 + c8);
    uint4 u1 = *(const uint4*)(p + (size_t)s1 * 96 + c8);
    uint4 u2 = *(const uint4*)(p + (size_t)s2 * 96 + c8);
    uint4 u3 = *(const uint4*)(p + (size_t)s3 * 96 + c8);
    float g0[8], g1[8], g2[8], g3[8];
    unp8(u0, g0); unp8(u1, g1); unp8(u2, g2); unp8(u3, g3);
#pragma unroll
    for (int j = 0; j < 8; ++j) acc[j] += g0[j] * wa + g1[j] * wb + g2[j] * wc + g3[j] * wd;
  }
  for (; e < e1; ++e) {
    int s = csrc[e];
    float w = dinv[s] * di;
    uint4 u = *(const uint4*)(p + (size_t)s * 96 + c8);
    unp8(u, f);
#pragma unroll
    for (int j = 0; j < 8; ++j) acc[j] += f[j] * w;
  }
  float* row = tb + (size_t)n * 96 + c8;
  *(float4*)(row)     = make_float4(acc[0] + bc[c8 + 0], acc[1] + bc[c8 + 1],
                                    acc[2] + bc[c8 + 2], acc[3] + bc[c8 + 3]);
  *(float4*)(row + 4) = make_float4(acc[4] + bc[c8 + 4], acc[5] + bc[c8 + 5],
                                    acc[6] + bc[c8 + 6], acc[7] + bc[c8 + 7]);
}

// ---------------- small-matrix weight GEMM: C(Mx96) = [A; bvec](MxK) @ B(Kx96) ----------------
__global__ __launch_bounds__(256, 2) void k_wgemm96(const float* __restrict__ A, const float* __restrict__ bvec,
                                                    const float* __restrict__ B, float* __restrict__ C,
                                                    int M, int K) {
  __shared__ float As[64][33];
  __shared__ float Bs[64][100];
  int t = threadIdx.x;
  int tx = t & 15, ty = t >> 4;
  int bm = blockIdx.x * 32;
  float acc[2][6] = {};
  for (int kc = 0; kc < K; kc += 64) {
#pragma unroll
    for (int it = 0; it < 2; ++it) {
      int idx = t + it * 256;
      int r = idx >> 4, k4 = (idx & 15) << 2;
      int gr = bm + r;
      float4 v = make_float4(0.f, 0.f, 0.f, 0.f);
      if (gr < M) {
        const float* src = (gr < M - 1) ? (A + (size_t)gr * K + kc + k4) : (bvec + kc + k4);
        v = *(const float4*)src;
      }
      As[k4 + 0][r] = v.x;
      As[k4 + 1][r] = v.y;
      As[k4 + 2][r] = v.z;
      As[k4 + 3][r] = v.w;
    }
#pragma unroll
    for (int it = 0; it < 6; ++it) {
      int idx = t + it * 256;
      int k = idx / 24, j4 = (idx % 24) << 2;
      float4 v = *(const float4*)(B + (size_t)(kc + k) * 96 + j4);
      *(float4*)&Bs[k][j4] = v;
    }
    __syncthreads();
#pragma unroll
    for (int k = 0; k < 64; ++k) {
      float a0 = As[k][ty * 2], a1 = As[k][ty * 2 + 1];
      float w[6];
      *(float2*)&w[0] = *(const float2*)&Bs[k][tx * 6];
      *(float2*)&w[2] = *(const float2*)&Bs[k][tx * 6 + 2];
      *(float2*)&w[4] = *(const float2*)&Bs[k][tx * 6 + 4];
#pragma unroll
      for (int j = 0; j < 6; ++j) { acc[0][j] += a0 * w[j]; acc[1][j] += a1 * w[j]; }
    }
    __syncthreads();
  }
#pragma unroll
  for (int i = 0; i < 2; ++i) {
    int gr = bm + ty * 2 + i;
    if (gr >= M) continue;
    float* row = C + (size_t)gr * 96 + tx * 6;
    row[0] = acc[i][0]; row[1] = acc[i][1]; row[2] = acc[i][2];
    row[3] = acc[i][3]; row[4] = acc[i][4]; row[5] = acc[i][5];
  }
}

// ---------------- weight casts (fp32 -> bf16, transposed); k_cast_wct also computes bc ----------------
__global__ void k_cast_w1t(const float* __restrict__ W1, unsigned short* __restrict__ W1bt) {
  int idx = blockIdx.x * 256 + threadIdx.x;          // over [256 n][96 k]
  if (idx >= 256 * 96) return;
  int n = idx / 96, k = idx % 96;
  W1bt[idx] = f2bf(W1[(size_t)k * 256 + n]);
}
// Wc = P2 rows 0..255; bc = P1[256] + P2[256] + bl2 (done by block 0)
__global__ void k_cast_wct(const float* __restrict__ P2, const float* __restrict__ r1,
                           const float* __restrict__ bl2, unsigned short* __restrict__ Wcbt,
                           float* __restrict__ bc) {
  int idx = blockIdx.x * 256 + threadIdx.x;          // over [96 n][256 k]
  if (blockIdx.x == 0 && threadIdx.x < OUT_CH)
    bc[threadIdx.x] = r1[threadIdx.x] + P2[256 * 96 + threadIdx.x] + bl2[threadIdx.x];
  if (idx >= 96 * 256) return;
  int n = idx / 256, k = idx % 256;
  Wcbt[idx] = f2bf(P2[(size_t)k * 96 + n]);
}

// ---------------- FUSED MLP v5: halved-phase, 32 KB LDS -> 4 blocks/CU ----------------
// Round-18: (256,3) hint alone didn't raise residency (46 us, 22% occ). v5 halves LDS by
// producing/consuming h1 in two 128-wide K-halves: B-half writes Hs_half (16 KB, wave-private,
// barrier-free), C-half consumes it immediately with accC[6] persisting across halves. Only the
// shared 16 KB Ws chunk buffer needs barriers. LDS 32 KB + ~80 VGPR -> (256,4): 4 blocks/CU.
#define SWZ(row, g) (((row) << 7) + (((g) ^ ((row) & 7)) << 3))          // [64][128] bf16 swizzled
__global__ __launch_bounds__(256, 4) void k_mlp(const unsigned short* __restrict__ A,
                                                const unsigned short* __restrict__ W1bt,  // [256 n][96 k]
                                                const float* __restrict__ bias1,
                                                const unsigned short* __restrict__ Wcbt,  // [96 n][256 k]
                                                unsigned short* __restrict__ P, int M) {
  __shared__ unsigned short Hs[64 * 128];  // h1 half-rows (bf16), swizzled, 16 KB, wave-private
  __shared__ unsigned short Ws[64 * 128];  // weight chunk (bf16), swizzled, 16 KB
  int t = threadIdx.x;
  int wave = t >> 6, lane = t & 63;
  int l15 = lane & 15, lhi = lane >> 4;
  int bm = blockIdx.x * 64;

  // A-frags direct from global (row bm+wave*16+l15, k-groups 0/32/64 + lhi*8)
  int arowl = wave * 16 + l15;
  bool aok = (bm + arowl) < M;
  const unsigned short* ap = A + (size_t)(bm + arowl) * 96 + lhi * 8;
  bf16x8 a0 = aok ? *(const bf16x8*)(ap)      : (bf16x8){0,0,0,0,0,0,0,0};
  bf16x8 a1 = aok ? *(const bf16x8*)(ap + 32) : (bf16x8){0,0,0,0,0,0,0,0};
  bf16x8 a2 = aok ? *(const bf16x8*)(ap + 64) : (bf16x8){0,0,0,0,0,0,0,0};
  int hrow = wave * 16 + lhi * 4;
  int orow = wave * 16 + lhi * 4;

  f32x4 accC[6];
#pragma unroll
  for (int q = 0; q < 6; ++q) accC[q] = (f32x4){0.f, 0.f, 0.f, 0.f};

  for (int hf = 0; hf < 2; ++hf) {
    // ---- phase B-half: h1 cols [hf*128, +128) = 8 f-frags, via 2 W1bt chunks of 64 rows ----
    for (int c = 0; c < 2; ++c) {
      __syncthreads();                     // Ws free (prev chunk consumed)
#pragma unroll
      for (int it = 0; it < 3; ++it) {     // stage 64 rows x 12 groups, coalesced, swizzled dest
        int idx = t + it * 256;
        int row = idx / 12, g = idx % 12;
        *(uint4*)&Ws[SWZ(row, g)] =
            *(const uint4*)(W1bt + (size_t)(hf * 128 + c * 64 + row) * 96 + g * 8);
      }
      __syncthreads();
#pragma unroll
      for (int fl = 0; fl < 4; ++fl) {
        int floc = c * 4 + fl;             // 0..7 within half
        int wrow = fl * 16 + l15;
        bf16x8 w0_ = *(const bf16x8*)&Ws[SWZ(wrow, 0 + lhi)];
        bf16x8 w1_ = *(const bf16x8*)&Ws[SWZ(wrow, 4 + lhi)];
        bf16x8 w2_ = *(const bf16x8*)&Ws[SWZ(wrow, 8 + lhi)];
        f32x4 acc = (f32x4){0.f, 0.f, 0.f, 0.f};
        acc = __builtin_amdgcn_mfma_f32_16x16x32_bf16(a0, w0_, acc, 0, 0, 0);
        acc = __builtin_amdgcn_mfma_f32_16x16x32_bf16(a1, w1_, acc, 0, 0, 0);
        acc = __builtin_amdgcn_mfma_f32_16x16x32_bf16(a2, w2_, acc, 0, 0, 0);
        int col = (hf * 8 + floc) * 16 + l15;        // global h1 col (bias index)
        int colh = floc * 16 + l15;                  // col within half, 0..127
        float bv = bias1[col];
#pragma unroll
        for (int r = 0; r < 4; ++r) {
          float x = acc[r] + bv;
          x = 0.5f * x * (1.0f + erff(x * 0.70710678118654752f));
          int row = hrow + r;
          Hs[SWZ(row, colh >> 3) + (colh & 7)] = f2bf(x);
        }
      }
    }
    // Hs is wave-private: this wave wrote rows wave*16..+15 and reads the same — no barrier.

    // ---- phase C-half: accC += h1[:, hf-half] @ Wc[hf-half, :]; 2 Wcbt chunks of 48 rows ----
    for (int tf = 0; tf < 2; ++tf) {
      __syncthreads();                     // Ws free
#pragma unroll
      for (int it = 0; it < 3; ++it) {     // stage 48 rows x 16 groups (128 k), swizzled dest
        int idx = t + it * 256;
        int row = idx >> 4, g = idx & 15;
        *(uint4*)&Ws[SWZ(row, g)] =
            *(const uint4*)(Wcbt + (size_t)(tf * 48 + row) * 256 + hf * 128 + g * 8);
      }
      __syncthreads();
#pragma unroll
      for (int fl = 0; fl < 3; ++fl) {
        int wrow = fl * 16 + l15;
        int harow = wave * 16 + l15;
#pragma unroll
        for (int ks = 0; ks < 4; ++ks) {
          bf16x8 av = *(const bf16x8*)&Hs[SWZ(harow, ks * 4 + lhi)];
          bf16x8 wv = *(const bf16x8*)&Ws[SWZ(wrow, ks * 4 + lhi)];
          accC[tf * 3 + fl] = __builtin_amdgcn_mfma_f32_16x16x32_bf16(av, wv, accC[tf * 3 + fl], 0, 0, 0);
        }
      }
    }
  }

  // ---- epilogue: p (bf16) direct stores ----
#pragma unroll
  for (int q = 0; q < 6; ++q) {
    int col = (q / 3) * 48 + (q % 3) * 16 + l15;
#pragma unroll
    for (int r = 0; r < 4; ++r) {
      int row = bm + orow + r;
      if (row < M) P[(size_t)row * 96 + col] = f2bf(accC[q][r]);
    }
  }
}

extern "C" void kernel_launch(void* const* d_in, const int* in_sizes, int n_in,
                              void* d_out, int out_size, void* d_ws, size_t ws_size,
                              hipStream_t stream) {
  const float* xm  = (const float*)d_in[0];
  const float* xg  = (const float*)d_in[1];
  const int*   ei  = (const int*)d_in[2];
  const float* W1  = (const float*)d_in[3];
  const float* b1  = (const float*)d_in[4];
  const float* W2  = (const float*)d_in[5];
  const float* b2  = (const float*)d_in[6];
  const float* Wl1 = (const float*)d_in[7];
  const float* bl1 = (const float*)d_in[8];
  const float* Wl2 = (const float*)d_in[9];
  const float* bl2 = (const float*)d_in[10];
  float* out = (float*)d_out;

  // ---- workspace layout (float units) ----
  float* W0 = (float*)d_ws;
  const size_t MB = (size_t)N_GRID * 256;          // 16,680,960
  int*   deg  = (int*)(W0 + MB);
  int*   off  = deg + N_TOT;                       // N_TOT+1
  int*   cur  = off + N_TOT + 1;
  int*   bsum = cur + N_TOT;                       // 512
  int*   csrc = bsum + 512;                        // NE
  float* dinv = (float*)(csrc + NE);               // N_TOT
  size_t p1off = ((size_t)(dinv + N_TOT - W0) + 3) & ~(size_t)3;   // 16B align
  float* P1 = W0 + p1off;                          // 257*96: [Wl1;bl1]@Wl2 (rows 0..255 = T1)
  float* P2 = P1 + 257 * 96;                       // 257*96: [W2;b2]@T1  (rows 0..255 = Wc)
  float* bc = P2 + 257 * 96;                       // 96
  size_t wboff = ((size_t)(bc + 96 - W0) + 3) & ~(size_t)3;        // 16B align
  unsigned short* W1bt = (unsigned short*)(W0 + wboff);            // 256x96 bf16
  unsigned short* Wcbt = W1bt + 256 * 96;                          // 96x256 bf16
  size_t RH = (wboff + 24576 + 3) & ~(size_t)3;    // past both bf16 arrays (24576 floats)
  unsigned short* hb = (unsigned short*)(W0 + RH); // N_TOT x 96 bf16 (5.09M fl)
  unsigned short* agg1b = (unsigned short*)W0;     // [0, 5.1M fl) bf16 (t3-t4)
  unsigned short* p = (unsigned short*)(hb + (size_t)N_TOT * 96 + 16);   // bf16, after hb
  p = (unsigned short*)(((size_t)p + 15) & ~(size_t)15);
  float* tb = W0 + (size_t)6 * 1024 * 1024;        // [6M, 12.25M) fl — clear of agg1b and meta

  const int* esrc = ei;
  const int* edst = ei + NE;
  dim3 b256(256);
  const int NB_N = (N_TOT + 255) / 256;

  // t1. node features (N_TOT, 96) bf16
  k_concat_transpose<<<dim3((N_TOT + 63) / 64), b256, 0, stream>>>(xg, xm, hb);

  // t2. CSR by dst + dinv; weight combine + casts (independent of node pipeline)
  k_zeroi<<<dim3(NB_N), b256, 0, stream>>>(deg, N_TOT);
  k_hist<<<dim3((NE + 255) / 256), b256, 0, stream>>>(edst, deg);
  k_blocksum<<<dim3(NB_N), b256, 0, stream>>>(deg, bsum, N_TOT);
  k_scanbsum<<<dim3(1), dim3(512), 0, stream>>>(bsum, NB_N);
  k_offsets<<<dim3(NB_N), b256, 0, stream>>>(deg, bsum, off, cur, dinv, N_TOT);
  k_fillcsr<<<dim3((NE + 255) / 256), b256, 0, stream>>>(esrc, edst, cur, csrc);
  k_cast_w1t<<<dim3(96), b256, 0, stream>>>(W1, W1bt);
  k_wgemm96<<<dim3(9), b256, 0, stream>>>(Wl1, bl1, Wl2, P1, 257, HID);
  k_wgemm96<<<dim3(9), b256, 0, stream>>>(W2, b2, P1, P2, 257, HID);
  k_cast_wct<<<dim3(96), b256, 0, stream>>>(P2, P1 + 256 * 96, bl2, Wcbt, bc);

  // t3. agg1 = S @ h   (96 ch, gather, bf16, 16B loads) — standalone, high occupancy
  k_gather96<<<dim3((N_TOT * 12 + 255) / 256), b256, 0, stream>>>(off, csrc, dinv, hb, agg1b);

  // t4. p = gelu(agg1@W1+b1)@Wc  — fused MLP v5 (halved phases, 32 KB LDS, 4 blocks/CU), p bf16
  k_mlp<<<dim3((N_TOT + 63) / 64), b256, 0, stream>>>(agg1b, W1bt, b1, Wcbt, p, N_TOT);

  // t5. tb = S_grid @ p + bc   (96 ch, bf16 16B reads, fp32 accumulate)
  k_gather96p<<<dim3((N_GRID * 12 + 255) / 256), b256, 0, stream>>>(off, csrc, dinv, p, bc, tb);

  // t6. out = tb^T   (96, N_GRID)
  k_transpose_out<<<dim3((N_GRID + 63) / 64), b256, 0, stream>>>(tb, out);
}

// Round 20
// 213.226 us; speedup vs baseline: 1.5757x; 1.0449x over previous
//
#include <hip/hip_runtime.h>
#include <math.h>

#define N_GRID 65160
#define N_MESH 40962
#define N_TOT  106122
#define NE     521280
#define IN_CH  96
#define HID    256
#define OUT_CH 96

typedef __attribute__((ext_vector_type(8))) short bf16x8;   // 8 bf16 in 4 VGPRs (guide §3)
typedef __attribute__((ext_vector_type(4))) float f32x4;

__device__ __forceinline__ unsigned short f2bf(float f) {   // fp32 -> bf16 RNE
  unsigned u = __float_as_uint(f);
  return (unsigned short)((u + 0x7FFFu + ((u >> 16) & 1u)) >> 16);
}
__device__ __forceinline__ float bf2f(unsigned short s) {
  return __uint_as_float(((unsigned)s) << 16);
}
// unpack 8 bf16 (uint4) -> 8 fp32
__device__ __forceinline__ void unp8(uint4 v, float* f) {
  f[0] = __uint_as_float(v.x << 16); f[1] = __uint_as_float(v.x & 0xFFFF0000u);
  f[2] = __uint_as_float(v.y << 16); f[3] = __uint_as_float(v.y & 0xFFFF0000u);
  f[4] = __uint_as_float(v.z << 16); f[5] = __uint_as_float(v.z & 0xFFFF0000u);
  f[6] = __uint_as_float(v.w << 16); f[7] = __uint_as_float(v.w & 0xFFFF0000u);
}

// ---------------- concat + transpose: (96,N) fp32 channel-major -> (N,96) bf16 node-major ----------------
__global__ void k_concat_transpose(const float* __restrict__ xg, const float* __restrict__ xm,
                                   unsigned short* __restrict__ h) {
  __shared__ float tile[IN_CH][65];
  int base = blockIdx.x * 64;
  int t = threadIdx.x;
#pragma unroll
  for (int it = 0; it < 24; ++it) {
    int lin = t + it * 256;            // 0..6143 over 96x64
    int c  = lin >> 6;
    int n0 = lin & 63;
    int n = base + n0;
    float v = 0.f;
    if (n < N_TOT) {
      v = (n < N_GRID) ? xg[(size_t)c * N_GRID + n]
                       : xm[(size_t)c * N_MESH + (n - N_GRID)];
    }
    tile[c][n0] = v;
  }
  __syncthreads();
#pragma unroll
  for (int it = 0; it < 24; ++it) {
    int lin = t + it * 256;
    int c  = lin % 96;
    int n0 = lin / 96;
    int n = base + n0;
    if (n < N_TOT) h[(size_t)n * IN_CH + c] = f2bf(tile[c][n0]);
  }
}

// ---------------- CSR build ----------------
__global__ void k_hist(const int* __restrict__ dst, int* __restrict__ deg) {
  int e = blockIdx.x * 256 + threadIdx.x;
  if (e < NE) atomicAdd(&deg[dst[e]], 1);
}

__global__ void k_blocksum(const int* __restrict__ deg, int* __restrict__ bsum, int n) {
  __shared__ int s[256];
  int i = blockIdx.x * 256 + threadIdx.x;
  s[threadIdx.x] = (i < n) ? deg[i] : 0;
  __syncthreads();
  for (int st = 128; st > 0; st >>= 1) {
    if (threadIdx.x < st) s[threadIdx.x] += s[threadIdx.x + st];
    __syncthreads();
  }
  if (threadIdx.x == 0) bsum[blockIdx.x] = s[0];
}

__global__ void k_scanbsum(int* __restrict__ bsum, int nb) {   // single block, 512 thr
  __shared__ int s[512];
  int t = threadIdx.x;
  int v = (t < nb) ? bsum[t] : 0;
  s[t] = v;
  __syncthreads();
  for (int off = 1; off < 512; off <<= 1) {
    int x = (t >= off) ? s[t - off] : 0;
    __syncthreads();
    s[t] += x;
    __syncthreads();
  }
  if (t < nb) bsum[t] = s[t] - v;   // exclusive
}

// offsets + cur init + dinv + off[N_TOT]=NE
__global__ void k_offsets(const int* __restrict__ deg, const int* __restrict__ bsum,
                          int* __restrict__ off, int* __restrict__ cur,
                          float* __restrict__ dinv, int n) {
  __shared__ int s[256];
  int i = blockIdx.x * 256 + threadIdx.x;
  int v = (i < n) ? deg[i] : 0;
  s[threadIdx.x] = v;
  __syncthreads();
  for (int o = 1; o < 256; o <<= 1) {
    int x = (threadIdx.x >= o) ? s[threadIdx.x - o] : 0;
    __syncthreads();
    s[threadIdx.x] += x;
    __syncthreads();
  }
  if (i < n) {
    int e = bsum[blockIdx.x] + s[threadIdx.x] - v;
    off[i] = e;
    cur[i] = e;
    dinv[i] = rsqrtf(1.0f + (float)v);
  }
  if (i == 0) off[n] = NE;
}

__global__ void k_fillcsr(const int* __restrict__ src, const int* __restrict__ dst,
                          int* __restrict__ cur, int* __restrict__ csrc) {
  int e = blockIdx.x * 256 + threadIdx.x;
  if (e < NE) {
    int p = atomicAdd(&cur[dst[e]], 1);
    csrc[p] = src[e];
  }
}

// ---------------- gather over bf16 h, 8 ch/thread (16B loads), 4-edge unroll ----------------
__global__ void k_gather96(const int* __restrict__ off, const int* __restrict__ csrc,
                           const float* __restrict__ dinv, const unsigned short* __restrict__ h,
                           unsigned short* __restrict__ agg) {
  int i = blockIdx.x * 256 + threadIdx.x;
  if (i >= N_TOT * 12) return;
  int n = i / 12;
  int c8 = (i % 12) << 3;
  float di = dinv[n];
  float acc[8], f[8];
  uint4 v = *(const uint4*)(h + (size_t)n * 96 + c8);
  unp8(v, f);
  float w0 = di * di;
#pragma unroll
  for (int j = 0; j < 8; ++j) acc[j] = f[j] * w0;
  int e0 = off[n], e1 = off[n + 1];
  int e = e0;
  for (; e + 3 < e1; e += 4) {
    int s0 = csrc[e], s1 = csrc[e + 1], s2 = csrc[e + 2], s3 = csrc[e + 3];
    float wa = dinv[s0] * di, wb = dinv[s1] * di, wc = dinv[s2] * di, wd = dinv[s3] * di;
    uint4 u0 = *(const uint4*)(h + (size_t)s0 * 96 + c8);
    uint4 u1 = *(const uint4*)(h + (size_t)s1 * 96 + c8);
    uint4 u2 = *(const uint4*)(h + (size_t)s2 * 96 + c8);
    uint4 u3 = *(const uint4*)(h + (size_t)s3 * 96 + c8);
    float g0[8], g1[8], g2[8], g3[8];
    unp8(u0, g0); unp8(u1, g1); unp8(u2, g2); unp8(u3, g3);
#pragma unroll
    for (int j = 0; j < 8; ++j) acc[j] += g0[j] * wa + g1[j] * wb + g2[j] * wc + g3[j] * wd;
  }
  for (; e < e1; ++e) {
    int s = csrc[e];
    float w = dinv[s] * di;
    uint4 u = *(const uint4*)(h + (size_t)s * 96 + c8);
    unp8(u, f);
#pragma unroll
    for (int j = 0; j < 8; ++j) acc[j] += f[j] * w;
  }
  uint4 o;
  o.x = (unsigned)f2bf(acc[0]) | ((unsigned)f2bf(acc[1]) << 16);
  o.y = (unsigned)f2bf(acc[2]) | ((unsigned)f2bf(acc[3]) << 16);
  o.z = (unsigned)f2bf(acc[4]) | ((unsigned)f2bf(acc[5]) << 16);
  o.w = (unsigned)f2bf(acc[6]) | ((unsigned)f2bf(acc[7]) << 16);
  *(uint4*)(agg + (size_t)n * 96 + c8) = o;
}

// ---------------- final gather + bias + transpose: out[c][n] = (S_grid @ p + bc)[n][c] ----------------
// Block = 64 grid nodes. Phase 1: 768 tasks (64 nodes x 12 c8-groups), gather into fp32 LDS tile.
// Phase 2: coalesced channel-major write to out (proven transpose pattern). Eliminates the tb
// buffer (25 MB HBM write + 25 MB read) and one launch vs round-19. LDS 24.4 KB -> occupancy
// stays high for this latency-bound kernel (round-13 lesson: gathers need TLP).
__global__ void k_gather_out(const int* __restrict__ off, const int* __restrict__ csrc,
                             const float* __restrict__ dinv, const unsigned short* __restrict__ p,
                             const float* __restrict__ bc, float* __restrict__ out) {
  __shared__ float tile[IN_CH][65];
  int base = blockIdx.x * 64;
  int t = threadIdx.x;
#pragma unroll
  for (int it = 0; it < 3; ++it) {
    int task = t + it * 256;           // 0..767
    int n0 = task / 12;
    int c8 = (task % 12) << 3;
    int n = base + n0;
    if (n < N_GRID) {
      float di = dinv[n];
      float acc[8], f[8];
      uint4 v = *(const uint4*)(p + (size_t)n * 96 + c8);
      unp8(v, f);
      float w0 = di * di;
#pragma unroll
      for (int j = 0; j < 8; ++j) acc[j] = f[j] * w0;
      int e0 = off[n], e1 = off[n + 1];
      int e = e0;
      for (; e + 3 < e1; e += 4) {
        int s0 = csrc[e], s1 = csrc[e + 1], s2 = csrc[e + 2], s3 = csrc[e + 3];
        float wa = dinv[s0] * di, wb = dinv[s1] * di, wc = dinv[s2] * di, wd = dinv[s3] * di;
        uint4 u0 = *(const uint4*)(p + (size_t)s0 * 96 + c8);
        uint4 u1 = *(const uint4*)(p + (size_t)s1 * 96 + c8);
        uint4 u2 = *(const uint4*)(p + (size_t)s2 * 96 + c8);
        uint4 u3 = *(const uint4*)(p + (size_t)s3 * 96 + c8);
        float g0[8], g1[8], g2[8], g3[8];
        unp8(u0, g0); unp8(u1, g1); unp8(u2, g2); unp8(u3, g3);
#pragma unroll
        for (int j = 0; j < 8; ++j) acc[j] += g0[j] * wa + g1[j] * wb + g2[j] * wc + g3[j] * wd;
      }
      for (; e < e1; ++e) {
        int s = csrc[e];
        float w = dinv[s] * di;
        uint4 u = *(const uint4*)(p + (size_t)s * 96 + c8);
        unp8(u, f);
#pragma unroll
        for (int j = 0; j < 8; ++j) acc[j] += f[j] * w;
      }
#pragma unroll
      for (int j = 0; j < 8; ++j) tile[c8 + j][n0] = acc[j] + bc[c8 + j];
    }
  }
  __syncthreads();
#pragma unroll
  for (int it = 0; it < 24; ++it) {
    int lin = t + it * 256;            // over 96 ch x 64 nodes
    int c  = lin >> 6;
    int n0 = lin & 63;
    int n = base + n0;
    if (n < N_GRID) out[(size_t)c * N_GRID + n] = tile[c][n0];
  }
}

// ---------------- small-matrix weight GEMM: C(Mx96) = [A; bvec](MxK) @ B(Kx96) ----------------
__global__ __launch_bounds__(256, 2) void k_wgemm96(const float* __restrict__ A, const float* __restrict__ bvec,
                                                    const float* __restrict__ B, float* __restrict__ C,
                                                    int M, int K) {
  __shared__ float As[64][33];
  __shared__ float Bs[64][100];
  int t = threadIdx.x;
  int tx = t & 15, ty = t >> 4;
  int bm = blockIdx.x * 32;
  float acc[2][6] = {};
  for (int kc = 0; kc < K; kc += 64) {
#pragma unroll
    for (int it = 0; it < 2; ++it) {
      int idx = t + it * 256;
      int r = idx >> 4, k4 = (idx & 15) << 2;
      int gr = bm + r;
      float4 v = make_float4(0.f, 0.f, 0.f, 0.f);
      if (gr < M) {
        const float* src = (gr < M - 1) ? (A + (size_t)gr * K + kc + k4) : (bvec + kc + k4);
        v = *(const float4*)src;
      }
      As[k4 + 0][r] = v.x;
      As[k4 + 1][r] = v.y;
      As[k4 + 2][r] = v.z;
      As[k4 + 3][r] = v.w;
    }
#pragma unroll
    for (int it = 0; it < 6; ++it) {
      int idx = t + it * 256;
      int k = idx / 24, j4 = (idx % 24) << 2;
      float4 v = *(const float4*)(B + (size_t)(kc + k) * 96 + j4);
      *(float4*)&Bs[k][j4] = v;
    }
    __syncthreads();
#pragma unroll
    for (int k = 0; k < 64; ++k) {
      float a0 = As[k][ty * 2], a1 = As[k][ty * 2 + 1];
      float w[6];
      *(float2*)&w[0] = *(const float2*)&Bs[k][tx * 6];
      *(float2*)&w[2] = *(const float2*)&Bs[k][tx * 6 + 2];
      *(float2*)&w[4] = *(const float2*)&Bs[k][tx * 6 + 4];
#pragma unroll
      for (int j = 0; j < 6; ++j) { acc[0][j] += a0 * w[j]; acc[1][j] += a1 * w[j]; }
    }
    __syncthreads();
  }
#pragma unroll
  for (int i = 0; i < 2; ++i) {
    int gr = bm + ty * 2 + i;
    if (gr >= M) continue;
    float* row = C + (size_t)gr * 96 + tx * 6;
    row[0] = acc[i][0]; row[1] = acc[i][1]; row[2] = acc[i][2];
    row[3] = acc[i][3]; row[4] = acc[i][4]; row[5] = acc[i][5];
  }
}

// ---------------- weight casts (fp32 -> bf16, transposed); k_cast_wct also computes bc ----------------
__global__ void k_cast_w1t(const float* __restrict__ W1, unsigned short* __restrict__ W1bt) {
  int idx = blockIdx.x * 256 + threadIdx.x;          // over [256 n][96 k]
  if (idx >= 256 * 96) return;
  int n = idx / 96, k = idx % 96;
  W1bt[idx] = f2bf(W1[(size_t)k * 256 + n]);
}
// Wc = P2 rows 0..255; bc = P1[256] + P2[256] + bl2 (done by block 0)
__global__ void k_cast_wct(const float* __restrict__ P2, const float* __restrict__ r1,
                           const float* __restrict__ bl2, unsigned short* __restrict__ Wcbt,
                           float* __restrict__ bc) {
  int idx = blockIdx.x * 256 + threadIdx.x;          // over [96 n][256 k]
  if (blockIdx.x == 0 && threadIdx.x < OUT_CH)
    bc[threadIdx.x] = r1[threadIdx.x] + P2[256 * 96 + threadIdx.x] + bl2[threadIdx.x];
  if (idx >= 96 * 256) return;
  int n = idx / 256, k = idx % 256;
  Wcbt[idx] = f2bf(P2[(size_t)k * 96 + n]);
}

// ---------------- FUSED MLP v5: halved-phase, 32 KB LDS, 4 blocks/CU (round-19 proven) ----------------
#define SWZ(row, g) (((row) << 7) + (((g) ^ ((row) & 7)) << 3))          // [64][128] bf16 swizzled
__global__ __launch_bounds__(256, 4) void k_mlp(const unsigned short* __restrict__ A,
                                                const unsigned short* __restrict__ W1bt,  // [256 n][96 k]
                                                const float* __restrict__ bias1,
                                                const unsigned short* __restrict__ Wcbt,  // [96 n][256 k]
                                                unsigned short* __restrict__ P, int M) {
  __shared__ unsigned short Hs[64 * 128];  // h1 half-rows (bf16), swizzled, 16 KB, wave-private
  __shared__ unsigned short Ws[64 * 128];  // weight chunk (bf16), swizzled, 16 KB
  int t = threadIdx.x;
  int wave = t >> 6, lane = t & 63;
  int l15 = lane & 15, lhi = lane >> 4;
  int bm = blockIdx.x * 64;

  int arowl = wave * 16 + l15;
  bool aok = (bm + arowl) < M;
  const unsigned short* ap = A + (size_t)(bm + arowl) * 96 + lhi * 8;
  bf16x8 a0 = aok ? *(const bf16x8*)(ap)      : (bf16x8){0,0,0,0,0,0,0,0};
  bf16x8 a1 = aok ? *(const bf16x8*)(ap + 32) : (bf16x8){0,0,0,0,0,0,0,0};
  bf16x8 a2 = aok ? *(const bf16x8*)(ap + 64) : (bf16x8){0,0,0,0,0,0,0,0};
  int hrow = wave * 16 + lhi * 4;
  int orow = wave * 16 + lhi * 4;

  f32x4 accC[6];
#pragma unroll
  for (int q = 0; q < 6; ++q) accC[q] = (f32x4){0.f, 0.f, 0.f, 0.f};

  for (int hf = 0; hf < 2; ++hf) {
    // phase B-half: h1 cols [hf*128, +128) = 8 f-frags, via 2 W1bt chunks of 64 rows
    for (int c = 0; c < 2; ++c) {
      __syncthreads();
#pragma unroll
      for (int it = 0; it < 3; ++it) {
        int idx = t + it * 256;
        int row = idx / 12, g = idx % 12;
        *(uint4*)&Ws[SWZ(row, g)] =
            *(const uint4*)(W1bt + (size_t)(hf * 128 + c * 64 + row) * 96 + g * 8);
      }
      __syncthreads();
#pragma unroll
      for (int fl = 0; fl < 4; ++fl) {
        int floc = c * 4 + fl;
        int wrow = fl * 16 + l15;
        bf16x8 w0_ = *(const bf16x8*)&Ws[SWZ(wrow, 0 + lhi)];
        bf16x8 w1_ = *(const bf16x8*)&Ws[SWZ(wrow, 4 + lhi)];
        bf16x8 w2_ = *(const bf16x8*)&Ws[SWZ(wrow, 8 + lhi)];
        f32x4 acc = (f32x4){0.f, 0.f, 0.f, 0.f};
        acc = __builtin_amdgcn_mfma_f32_16x16x32_bf16(a0, w0_, acc, 0, 0, 0);
        acc = __builtin_amdgcn_mfma_f32_16x16x32_bf16(a1, w1_, acc, 0, 0, 0);
        acc = __builtin_amdgcn_mfma_f32_16x16x32_bf16(a2, w2_, acc, 0, 0, 0);
        int col = (hf * 8 + floc) * 16 + l15;
        int colh = floc * 16 + l15;
        float bv = bias1[col];
#pragma unroll
        for (int r = 0; r < 4; ++r) {
          float x = acc[r] + bv;
          x = 0.5f * x * (1.0f + erff(x * 0.70710678118654752f));
          int row = hrow + r;
          Hs[SWZ(row, colh >> 3) + (colh & 7)] = f2bf(x);
        }
      }
    }
    // phase C-half: accC += h1[:, hf-half] @ Wc[hf-half, :]; 2 Wcbt chunks of 48 rows
    for (int tf = 0; tf < 2; ++tf) {
      __syncthreads();
#pragma unroll
      for (int it = 0; it < 3; ++it) {
        int idx = t + it * 256;
        int row = idx >> 4, g = idx & 15;
        *(uint4*)&Ws[SWZ(row, g)] =
            *(const uint4*)(Wcbt + (size_t)(tf * 48 + row) * 256 + hf * 128 + g * 8);
      }
      __syncthreads();
#pragma unroll
      for (int fl = 0; fl < 3; ++fl) {
        int wrow = fl * 16 + l15;
        int harow = wave * 16 + l15;
#pragma unroll
        for (int ks = 0; ks < 4; ++ks) {
          bf16x8 av = *(const bf16x8*)&Hs[SWZ(harow, ks * 4 + lhi)];
          bf16x8 wv = *(const bf16x8*)&Ws[SWZ(wrow, ks * 4 + lhi)];
          accC[tf * 3 + fl] = __builtin_amdgcn_mfma_f32_16x16x32_bf16(av, wv, accC[tf * 3 + fl], 0, 0, 0);
        }
      }
    }
  }

#pragma unroll
  for (int q = 0; q < 6; ++q) {
    int col = (q / 3) * 48 + (q % 3) * 16 + l15;
#pragma unroll
    for (int r = 0; r < 4; ++r) {
      int row = bm + orow + r;
      if (row < M) P[(size_t)row * 96 + col] = f2bf(accC[q][r]);
    }
  }
}

extern "C" void kernel_launch(void* const* d_in, const int* in_sizes, int n_in,
                              void* d_out, int out_size, void* d_ws, size_t ws_size,
                              hipStream_t stream) {
  const float* xm  = (const float*)d_in[0];
  const float* xg  = (const float*)d_in[1];
  const int*   ei  = (const int*)d_in[2];
  const float* W1  = (const float*)d_in[3];
  const float* b1  = (const float*)d_in[4];
  const float* W2  = (const float*)d_in[5];
  const float* b2  = (const float*)d_in[6];
  const float* Wl1 = (const float*)d_in[7];
  const float* bl1 = (const float*)d_in[8];
  const float* Wl2 = (const float*)d_in[9];
  const float* bl2 = (const float*)d_in[10];
  float* out = (float*)d_out;

  // ---- workspace layout (float units) ----
  float* W0 = (float*)d_ws;
  const size_t MB = (size_t)N_GRID * 256;          // 16,680,960
  int*   deg  = (int*)(W0 + MB);
  int*   off  = deg + N_TOT;                       // N_TOT+1
  int*   cur  = off + N_TOT + 1;
  int*   bsum = cur + N_TOT;                       // 512
  int*   csrc = bsum + 512;                        // NE
  float* dinv = (float*)(csrc + NE);               // N_TOT
  size_t p1off = ((size_t)(dinv + N_TOT - W0) + 3) & ~(size_t)3;   // 16B align
  float* P1 = W0 + p1off;                          // 257*96: [Wl1;bl1]@Wl2 (rows 0..255 = T1)
  float* P2 = P1 + 257 * 96;                       // 257*96: [W2;b2]@T1  (rows 0..255 = Wc)
  float* bc = P2 + 257 * 96;                       // 96
  size_t wboff = ((size_t)(bc + 96 - W0) + 3) & ~(size_t)3;        // 16B align
  unsigned short* W1bt = (unsigned short*)(W0 + wboff);            // 256x96 bf16
  unsigned short* Wcbt = W1bt + 256 * 96;                          // 96x256 bf16
  size_t RH = (wboff + 24576 + 3) & ~(size_t)3;    // past both bf16 arrays (24576 floats)
  unsigned short* hb = (unsigned short*)(W0 + RH); // N_TOT x 96 bf16 (5.09M fl)
  unsigned short* agg1b = (unsigned short*)W0;     // [0, 5.1M fl) bf16 (t3-t4)
  unsigned short* p = (unsigned short*)(hb + (size_t)N_TOT * 96 + 16);   // bf16, after hb
  p = (unsigned short*)(((size_t)p + 15) & ~(size_t)15);

  const int* esrc = ei;
  const int* edst = ei + NE;
  dim3 b256(256);
  const int NB_N = (N_TOT + 255) / 256;

  // t1. node features (N_TOT, 96) bf16
  k_concat_transpose<<<dim3((N_TOT + 63) / 64), b256, 0, stream>>>(xg, xm, hb);

  // t2. CSR by dst + dinv; weight combine + casts (independent of node pipeline)
  hipMemsetAsync(deg, 0, (size_t)N_TOT * sizeof(int), stream);
  k_hist<<<dim3((NE + 255) / 256), b256, 0, stream>>>(edst, deg);
  k_blocksum<<<dim3(NB_N), b256, 0, stream>>>(deg, bsum, N_TOT);
  k_scanbsum<<<dim3(1), dim3(512), 0, stream>>>(bsum, NB_N);
  k_offsets<<<dim3(NB_N), b256, 0, stream>>>(deg, bsum, off, cur, dinv, N_TOT);
  k_fillcsr<<<dim3((NE + 255) / 256), b256, 0, stream>>>(esrc, edst, cur, csrc);
  k_cast_w1t<<<dim3(96), b256, 0, stream>>>(W1, W1bt);
  k_wgemm96<<<dim3(9), b256, 0, stream>>>(Wl1, bl1, Wl2, P1, 257, HID);
  k_wgemm96<<<dim3(9), b256, 0, stream>>>(W2, b2, P1, P2, 257, HID);
  k_cast_wct<<<dim3(96), b256, 0, stream>>>(P2, P1 + 256 * 96, bl2, Wcbt, bc);

  // t3. agg1 = S @ h   (96 ch, gather, bf16, 16B loads) — standalone, high occupancy
  k_gather96<<<dim3((N_TOT * 12 + 255) / 256), b256, 0, stream>>>(off, csrc, dinv, hb, agg1b);

  // t4. p = gelu(agg1@W1+b1)@Wc  — fused MLP v5, p bf16
  k_mlp<<<dim3((N_TOT + 63) / 64), b256, 0, stream>>>(agg1b, W1bt, b1, Wcbt, p, N_TOT);

  // t5. out = (S_grid @ p + bc)^T  — gather + bias + LDS transpose, direct to out (tb eliminated)
  k_gather_out<<<dim3((N_GRID + 63) / 64), b256, 0, stream>>>(off, csrc, dinv, p, bc, out);
}